// Round 2
// baseline (9758.556 us; speedup 1.0000x reference)
//
#include <hip/hip_runtime.h>
#include <math.h>

#define NB   256
#define NMAX 256
#define CH   512
#define LD2  256
#define LDC  512
#define BS2  (256*256)
#define BSC  (256*512)

#define BM 128
#define BN 128
#define BK 16
#define LSP 132

__device__ __forceinline__ float warp_sum_f(float v) {
#pragma unroll
  for (int m = 32; m >= 1; m >>= 1) v += __shfl_xor(v, m);
  return v;
}

// ---------------- unified fp32 GEMM ----------------
// Y[b] = L[b] @ R[b](^T)  with epilogue:
// flags: 1 = +bias[col], 2 = relu, 4 = *rowscale[b,row]
__global__ __launch_bounds__(256)
void gemm_kernel(const float* __restrict__ Lp, long bsL, int ldl,
                 const float* __restrict__ Rp, long bsR, int ldr,
                 float* __restrict__ Yp, long bsY, int ldy,
                 const float* __restrict__ bias,
                 const float* __restrict__ rowscale,
                 int M, int Ncol, int K, int flags, int transB)
{
  __shared__ float Ls[BK][LSP];
  __shared__ float Rs[BK][LSP];
  const int b   = blockIdx.z;
  const int i0  = blockIdx.y * BM;
  const int n0  = blockIdx.x * BN;
  const int tid = threadIdx.x;
  const int tx = tid & 15, ty = tid >> 4;
  const int row0 = ty * 8, col0 = tx * 8;
  const float* Lb = Lp + (long)b * bsL;
  const float* Rb = Rp + (long)b * bsR;

  float acc[8][8];
#pragma unroll
  for (int r = 0; r < 8; ++r)
#pragma unroll
    for (int c = 0; c < 8; ++c) acc[r][c] = 0.f;

  const bool ldrv = ((ldr & 3) == 0);

  for (int k0 = 0; k0 < K; k0 += BK) {
    // L tile: BM x BK -> Ls[k][row]
#pragma unroll
    for (int rep = 0; rep < 2; ++rep) {
      int idx = rep * 256 + tid;
      int row = idx >> 2, q = (idx & 3) << 2;
      int gr = i0 + row, gk = k0 + q;
      float v[4] = {0.f, 0.f, 0.f, 0.f};
      if (gr < M) {
        if (gk + 3 < K) {
          float4 t = *(const float4*)(Lb + (long)gr * ldl + gk);
          v[0] = t.x; v[1] = t.y; v[2] = t.z; v[3] = t.w;
        } else {
#pragma unroll
          for (int j = 0; j < 4; ++j) if (gk + j < K) v[j] = Lb[(long)gr * ldl + gk + j];
        }
      }
      Ls[q + 0][row] = v[0]; Ls[q + 1][row] = v[1];
      Ls[q + 2][row] = v[2]; Ls[q + 3][row] = v[3];
    }
    if (!transB) {
      // R tile: BK x BN -> Rs[k][col]
#pragma unroll
      for (int rep = 0; rep < 2; ++rep) {
        int idx = rep * 256 + tid;
        int kk = idx >> 5, c4 = (idx & 31) << 2;
        int gk = k0 + kk, gc = n0 + c4;
        float v[4] = {0.f, 0.f, 0.f, 0.f};
        if (gk < K) {
          if (ldrv && gc + 3 < Ncol) {
            float4 t = *(const float4*)(Rb + (long)gk * ldr + gc);
            v[0] = t.x; v[1] = t.y; v[2] = t.z; v[3] = t.w;
          } else {
#pragma unroll
            for (int j = 0; j < 4; ++j) if (gc + j < Ncol) v[j] = Rb[(long)gk * ldr + gc + j];
          }
        }
        *(float4*)&Rs[kk][c4] = *(float4*)v;
      }
    } else {
      // R is [Ncol x K]; output col = R row
#pragma unroll
      for (int rep = 0; rep < 2; ++rep) {
        int idx = rep * 256 + tid;
        int crow = idx >> 2, q = (idx & 3) << 2;
        int gc = n0 + crow, gk = k0 + q;
        float v[4] = {0.f, 0.f, 0.f, 0.f};
        if (gc < Ncol) {
          if (ldrv && gk + 3 < K) {
            float4 t = *(const float4*)(Rb + (long)gc * ldr + gk);
            v[0] = t.x; v[1] = t.y; v[2] = t.z; v[3] = t.w;
          } else {
#pragma unroll
            for (int j = 0; j < 4; ++j) if (gk + j < K) v[j] = Rb[(long)gc * ldr + gk + j];
          }
        }
        Rs[q + 0][crow] = v[0]; Rs[q + 1][crow] = v[1];
        Rs[q + 2][crow] = v[2]; Rs[q + 3][crow] = v[3];
      }
    }
    __syncthreads();
#pragma unroll
    for (int kk = 0; kk < BK; ++kk) {
      float4 a0 = *(const float4*)&Ls[kk][row0];
      float4 a1 = *(const float4*)&Ls[kk][row0 + 4];
      float4 b0 = *(const float4*)&Rs[kk][col0];
      float4 b1 = *(const float4*)&Rs[kk][col0 + 4];
      float av[8] = {a0.x, a0.y, a0.z, a0.w, a1.x, a1.y, a1.z, a1.w};
      float bv[8] = {b0.x, b0.y, b0.z, b0.w, b1.x, b1.y, b1.z, b1.w};
#pragma unroll
      for (int r = 0; r < 8; ++r)
#pragma unroll
        for (int c = 0; c < 8; ++c)
          acc[r][c] = fmaf(av[r], bv[c], acc[r][c]);
    }
    __syncthreads();
  }

  float* Yb = Yp + (long)b * bsY;
  const bool ldyv = ((ldy & 3) == 0);
#pragma unroll
  for (int r = 0; r < 8; ++r) {
    int gr = i0 + row0 + r;
    if (gr >= M) continue;
    float rs = (flags & 4) ? rowscale[b * 256 + gr] : 1.f;
#pragma unroll
    for (int h = 0; h < 2; ++h) {
      int cb = n0 + col0 + h * 4;
      float o[4];
#pragma unroll
      for (int c = 0; c < 4; ++c) {
        float vv = acc[r][h * 4 + c] * rs;
        if (flags & 1) vv += (cb + c < Ncol) ? bias[cb + c] : 0.f;
        if (flags & 2) vv = fmaxf(vv, 0.f);
        o[c] = vv;
      }
      if (ldyv && cb + 3 < Ncol) {
        *(float4*)(Yb + (long)gr * ldy + cb) = *(float4*)o;
      } else {
#pragma unroll
        for (int c = 0; c < 4; ++c) if (cb + c < Ncol) Yb[(long)gr * ldy + cb + c] = o[c];
      }
    }
  }
}

// ---------------- masked neighbor-max "GEMM" ----------------
// Y[b,i,c] = max_j ( (A[b,i,j] > 0 ? 0 : -1e9) + XP[b,j,c] ), acc init -1e9
__global__ __launch_bounds__(256)
void maxgemm_kernel(const float* __restrict__ Ap, const float* __restrict__ Rp,
                    float* __restrict__ Yp, int M, int Ncol, int K)
{
  __shared__ float Ls[BK][LSP];
  __shared__ float Rs[BK][LSP];
  const int b   = blockIdx.z;
  const int i0  = blockIdx.y * BM;
  const int n0  = blockIdx.x * BN;
  const int tid = threadIdx.x;
  const int tx = tid & 15, ty = tid >> 4;
  const int row0 = ty * 8, col0 = tx * 8;
  const float* Lb = Ap + (long)b * BS2;
  const float* Rb = Rp + (long)b * BSC;

  float acc[8][8];
#pragma unroll
  for (int r = 0; r < 8; ++r)
#pragma unroll
    for (int c = 0; c < 8; ++c) acc[r][c] = -1e9f;

  for (int k0 = 0; k0 < K; k0 += BK) {
#pragma unroll
    for (int rep = 0; rep < 2; ++rep) {
      int idx = rep * 256 + tid;
      int row = idx >> 2, q = (idx & 3) << 2;
      int gr = i0 + row, gk = k0 + q;
      float v[4] = {0.f, 0.f, 0.f, 0.f};
      if (gr < M) {
        if (gk + 3 < K) {
          float4 t = *(const float4*)(Lb + (long)gr * LD2 + gk);
          v[0] = t.x; v[1] = t.y; v[2] = t.z; v[3] = t.w;
        } else {
#pragma unroll
          for (int j = 0; j < 4; ++j) if (gk + j < K) v[j] = Lb[(long)gr * LD2 + gk + j];
        }
      }
      Ls[q + 0][row] = (v[0] > 0.f) ? 0.f : -1e9f;
      Ls[q + 1][row] = (v[1] > 0.f) ? 0.f : -1e9f;
      Ls[q + 2][row] = (v[2] > 0.f) ? 0.f : -1e9f;
      Ls[q + 3][row] = (v[3] > 0.f) ? 0.f : -1e9f;
    }
#pragma unroll
    for (int rep = 0; rep < 2; ++rep) {
      int idx = rep * 256 + tid;
      int kk = idx >> 5, c4 = (idx & 31) << 2;
      int gk = k0 + kk, gc = n0 + c4;
      float v[4] = {0.f, 0.f, 0.f, 0.f};
      if (gk < K && gc + 3 < Ncol) {
        float4 t = *(const float4*)(Rb + (long)gk * LDC + gc);
        v[0] = t.x; v[1] = t.y; v[2] = t.z; v[3] = t.w;
      }
      *(float4*)&Rs[kk][c4] = *(float4*)v;
    }
    __syncthreads();
#pragma unroll
    for (int kk = 0; kk < BK; ++kk) {
      float4 a0 = *(const float4*)&Ls[kk][row0];
      float4 a1 = *(const float4*)&Ls[kk][row0 + 4];
      float4 b0 = *(const float4*)&Rs[kk][col0];
      float4 b1 = *(const float4*)&Rs[kk][col0 + 4];
      float av[8] = {a0.x, a0.y, a0.z, a0.w, a1.x, a1.y, a1.z, a1.w};
      float bv[8] = {b0.x, b0.y, b0.z, b0.w, b1.x, b1.y, b1.z, b1.w};
#pragma unroll
      for (int r = 0; r < 8; ++r)
#pragma unroll
        for (int c = 0; c < 8; ++c)
          acc[r][c] = fmaxf(acc[r][c], av[r] + bv[c]);
    }
    __syncthreads();
  }

  float* Yb = Yp + (long)b * BSC;
#pragma unroll
  for (int r = 0; r < 8; ++r) {
    int gr = i0 + row0 + r;
    if (gr >= M) continue;
#pragma unroll
    for (int h = 0; h < 2; ++h) {
      int cb = n0 + col0 + h * 4;
      if (cb + 3 < Ncol) {
        float o[4] = {acc[r][h*4+0], acc[r][h*4+1], acc[r][h*4+2], acc[r][h*4+3]};
        *(float4*)(Yb + (long)gr * LDC + cb) = *(float4*)o;
      }
    }
  }
}

// ---------------- small kernels ----------------
__global__ void build_a_kernel(const float* __restrict__ adj, float* __restrict__ A) {
  int b = blockIdx.y, i = blockIdx.x, j = threadIdx.x;
  float v = adj[(long)b * BS2 + i * 256 + j];
  if (i == j) v = fmaxf(v, 1.f);
  A[(long)b * BS2 + i * 256 + j] = v;
}

__global__ void embed_kernel(const int* __restrict__ ids, const float* __restrict__ emb,
                             float* __restrict__ X) {
  int b = blockIdx.y, i = blockIdx.x, t = threadIdx.x;
  int id = ids[b * NMAX + i];
  float4 v = *(const float4*)(emb + (long)id * CH + t * 4);
  *(float4*)(X + (long)b * BSC + (long)i * LDC + t * 4) = v;
}

// up to 3 simultaneous row-dots on a [B,*,512] buffer; cadd added to o1
__global__ void rowdot_kernel(const float* __restrict__ X,
                              const float* __restrict__ v1, const float* __restrict__ v2,
                              const float* __restrict__ v3,
                              float* __restrict__ o1, float* __restrict__ o2,
                              float* __restrict__ o3,
                              const float* __restrict__ cadd, int nvec) {
  int b = blockIdx.y, i = blockIdx.x, lane = threadIdx.x;
  const float* xr = X + (long)b * BSC + (long)i * LDC;
  float a1 = 0.f, a2 = 0.f, a3 = 0.f;
  for (int c = lane; c < CH; c += 64) {
    float x = xr[c];
    a1 = fmaf(x, v1[c], a1);
    if (nvec > 1) a2 = fmaf(x, v2[c], a2);
    if (nvec > 2) a3 = fmaf(x, v3[c], a3);
  }
  a1 = warp_sum_f(a1);
  if (nvec > 1) a2 = warp_sum_f(a2);
  if (nvec > 2) a3 = warp_sum_f(a3);
  if (lane == 0) {
    o1[b * 256 + i] = a1 + (cadd ? cadd[0] : 0.f);
    if (nvec > 1) o2[b * 256 + i] = a2;
    if (nvec > 2) o3[b * 256 + i] = a3;
  }
}

// v[c] = sum_j qW[c,j]*aw[j] (blocks 0..511); c0 = qb . aw (block 512)
__global__ void vq_kernel(const float* __restrict__ qW, const float* __restrict__ qb,
                          const float* __restrict__ aw, float* __restrict__ v,
                          float* __restrict__ c0) {
  int blk = blockIdx.x, lane = threadIdx.x;
  if (blk < 512) {
    float s = 0.f;
    for (int j = lane; j < CH; j += 64) s = fmaf(qW[(long)blk * CH + j], aw[j], s);
    s = warp_sum_f(s);
    if (lane == 0) v[blk] = s;
  } else {
    float s = 0.f;
    for (int j = lane; j < CH; j += 64) s = fmaf(qb[j], aw[j], s);
    s = warp_sum_f(s);
    if (lane == 0) c0[0] = s;
  }
}

__global__ __launch_bounds__(256)
void softmax_kernel(const float* __restrict__ A, const float* __restrict__ si,
                    const float* __restrict__ sj, const float* __restrict__ attb,
                    float* __restrict__ P, int n) {
  int b = blockIdx.y, i = blockIdx.x, j = threadIdx.x;
  __shared__ float red[256];
  float logit = -1e30f, e = 0.f;
  float siv = si[b * 256 + i];
  if (j < n) {
    float a = A[(long)b * BS2 + i * 256 + j];
    float z = siv + sj[b * 256 + j] + (attb ? attb[0] : 0.f);
    z = (z > 0.f) ? z : 0.2f * z;
    logit = (a > 0.f) ? z : -1e9f;
  }
  red[j] = logit; __syncthreads();
  for (int s = 128; s > 0; s >>= 1) { if (j < s) red[j] = fmaxf(red[j], red[j + s]); __syncthreads(); }
  float mx = red[0]; __syncthreads();
  if (j < n) e = expf(logit - mx);
  red[j] = e; __syncthreads();
  for (int s = 128; s > 0; s >>= 1) { if (j < s) red[j] += red[j + s]; __syncthreads(); }
  float sum = red[0];
  if (j < n) P[(long)b * BS2 + i * 256 + j] = e / sum;
}

__global__ void deg_kernel(const float* __restrict__ A, float* __restrict__ deg,
                           float* __restrict__ dinv, int n) {
  int b = blockIdx.y, i = blockIdx.x, lane = threadIdx.x;
  const float* ar = A + (long)b * BS2 + i * 256;
  float s = 0.f;
  for (int j = lane; j < n; j += 64) s += ar[j];
  s = warp_sum_f(s);
  if (lane == 0) {
    deg[b * 256 + i] = s;
    dinv[b * 256 + i] = (s > 0.f) ? (1.f / sqrtf(s)) : 0.f;
  }
}

__global__ void fit_kernel(const float* __restrict__ A, const float* __restrict__ t1,
                           const float* __restrict__ t2, const float* __restrict__ t3,
                           const float* __restrict__ deg, const float* __restrict__ leb1,
                           float* __restrict__ fit, int n) {
  int b = blockIdx.y, i = blockIdx.x, lane = threadIdx.x;
  const float* ar = A + (long)b * BS2 + i * 256;
  float s = 0.f;
  for (int j = lane; j < n; j += 64) s = fmaf(ar[j], t3[b * 256 + j], s);
  s = warp_sum_f(s);
  if (lane == 0) {
    float z = t1[b * 256 + i] + leb1[0] + t2[b * 256 + i] * deg[b * 256 + i] - s;
    fit[b * 256 + i] = 1.f / (1.f + expf(-z));
  }
}

// bitonic top-k over n<=256 values, descending, tie -> lower index (lax.top_k)
__global__ __launch_bounds__(256)
void topk_kernel(const float* __restrict__ fit, int* __restrict__ perm,
                 float* __restrict__ vals, int n, int k) {
  __shared__ float v[256];
  __shared__ int ix[256];
  int b = blockIdx.x, t = threadIdx.x;
  v[t] = (t < n) ? fit[b * 256 + t] : -1e30f;
  ix[t] = t;
  __syncthreads();
  for (int size = 2; size <= 256; size <<= 1)
    for (int str = size >> 1; str > 0; str >>= 1) {
      int p = t ^ str;
      if (p > t) {
        bool desc = ((t & size) == 0);
        float v1 = v[t], v2 = v[p]; int i1 = ix[t], i2 = ix[p];
        bool inorder = (v1 > v2) || (v1 == v2 && i1 < i2);
        if (inorder != desc) { v[t] = v2; v[p] = v1; ix[t] = i2; ix[p] = i1; }
      }
      __syncthreads();
    }
  if (t < k) { perm[b * 256 + t] = ix[t]; vals[b * 256 + t] = v[t]; }
}

__global__ void gatherx_kernel(const float* __restrict__ Hc, const int* __restrict__ perm,
                               const float* __restrict__ vals, float* __restrict__ X) {
  int b = blockIdx.y, p = blockIdx.x, t = threadIdx.x;
  int src = perm[b * 256 + p];
  float sv = vals[b * 256 + p];
  float4 v = *(const float4*)(Hc + (long)b * BSC + (long)src * LDC + t * 4);
  v.x *= sv; v.y *= sv; v.z *= sv; v.w *= sv;
  *(float4*)(X + (long)b * BSC + (long)p * LDC + t * 4) = v;
}

__global__ void gathersk_kernel(const float* __restrict__ P, const int* __restrict__ perm,
                                float* __restrict__ Sk, int n) {
  int b = blockIdx.y, p = blockIdx.x, j = threadIdx.x;
  int src = perm[b * 256 + p];
  if (j < n) Sk[(long)b * 65536 + p * 256 + j] = P[(long)b * BS2 + src * 256 + j];
}

__global__ void diagfix_kernel(float* __restrict__ A, int k) {
  int b = blockIdx.x, p = threadIdx.x;
  if (p < k) {
    long o = (long)b * BS2 + p * 256 + p;
    float v = A[o];
    if (v <= 0.f) A[o] = v + 1.f;
  }
}

__global__ void readout_kernel(const float* __restrict__ X, float* __restrict__ xs, int k) {
  int b = blockIdx.x, t = threadIdx.x;
#pragma unroll
  for (int rep = 0; rep < 2; ++rep) {
    int c = t + rep * 256;
    float s = 0.f, m = -1e30f;
    for (int p = 0; p < k; ++p) {
      float v = X[(long)b * BSC + (long)p * LDC + c];
      s += v; m = fmaxf(m, v);
    }
    xs[b * 1024 + c] += s / (float)k;
    xs[b * 1024 + 512 + c] += m;
  }
}

// ---------------- host orchestration ----------------
extern "C" void kernel_launch(void* const* d_in, const int* in_sizes, int n_in,
                              void* d_out, int out_size, void* d_ws, size_t ws_size,
                              hipStream_t stream) {
  (void)in_sizes; (void)n_in; (void)out_size;
  const int*   x_ids  = (const int*)  d_in[0];
  const float* adj    = (const float*)d_in[2];
  const float* emb    = (const float*)d_in[3];
  const float* conv_W = (const float*)d_in[4];
  const float* conv_b = (const float*)d_in[5];
  const float* att_src= (const float*)d_in[6];
  const float* att_dst= (const float*)d_in[7];
  const float* q_W    = (const float*)d_in[8];
  const float* q_b    = (const float*)d_in[9];
  const float* att_w  = (const float*)d_in[10];
  const float* att_b  = (const float*)d_in[11];
  const float* gcn_W  = (const float*)d_in[12];
  const float* gcn_b  = (const float*)d_in[13];
  const float* le_W1  = (const float*)d_in[14];
  const float* le_b1  = (const float*)d_in[15];
  const float* le_W2  = (const float*)d_in[16];
  const float* le_W3  = (const float*)d_in[17];
  const float* lin1_W = (const float*)d_in[18];
  const float* lin1_b = (const float*)d_in[19];
  const float* lin2_W = (const float*)d_in[20];
  const float* lin2_b = (const float*)d_in[21];
  float* out = (float*)d_out;

  // ---- adaptive batch chunking to fit ws_size ----
  // per-graph scratch: 3x[256,512]f + 2x[256,256]f + 10x[256] = 2,107,392 B (pre-align)
  // fixed: vvec 3*512f, c0 3f, xs 256*1024f, FH 256*512f
  const size_t per_b  = (size_t)(3 * 131072 + 2 * 65536 + 10 * 256) * 4;
  const size_t fixedb = (size_t)(3 * 512 + 64 + 256 * 1024 + 256 * 512) * 4;
  const size_t slack  = 64 * 256;  // alignment slack for ~20 allocations
  int bc = 4;
  for (int cand = 256; cand >= 4; cand >>= 1) {
    if ((size_t)cand * per_b + fixedb + slack <= ws_size) { bc = cand; break; }
  }
  const int nchunks = NB / bc;

  char* w = (char*)d_ws;
  auto alloc = [&](size_t bytes) { char* p = w; w += (bytes + 255) & ~(size_t)255; return p; };
  // fixed (full-batch) buffers
  float* xs   = (float*)alloc(sizeof(float) * NB * 1024);
  float* FH   = (float*)alloc(sizeof(float) * NB * CH);
  float* vvec = (float*)alloc(sizeof(float) * 3 * CH);
  float* c0   = (float*)alloc(256);
  // chunk-local buffers (reused across chunks)
  float* X    = (float*)alloc(sizeof(float) * bc * NMAX * CH);
  float* H    = (float*)alloc(sizeof(float) * bc * NMAX * CH);
  float* XP   = (float*)alloc(sizeof(float) * bc * NMAX * CH);
  float* P    = (float*)alloc(sizeof(float) * bc * NMAX * NMAX);
  float* A    = (float*)alloc(sizeof(float) * bc * NMAX * NMAX);
  float* si   = (float*)alloc(sizeof(float) * bc * NMAX);
  float* sj   = (float*)alloc(sizeof(float) * bc * NMAX);
  float* deg  = (float*)alloc(sizeof(float) * bc * NMAX);
  float* dinv = (float*)alloc(sizeof(float) * bc * NMAX);
  float* t1   = (float*)alloc(sizeof(float) * bc * NMAX);
  float* t2   = (float*)alloc(sizeof(float) * bc * NMAX);
  float* t3   = (float*)alloc(sizeof(float) * bc * NMAX);
  float* fit  = (float*)alloc(sizeof(float) * bc * NMAX);
  float* vals = (float*)alloc(sizeof(float) * bc * NMAX);
  int*   perm = (int*)  alloc(sizeof(int)   * bc * NMAX);

  hipMemsetAsync(xs, 0, sizeof(float) * NB * 1024, stream);

  // per-layer v = qW @ aw[:C], c0 = qb . aw[:C]  (batch-independent)
  for (int l = 0; l < 3; ++l) {
    vq_kernel<<<513, 64, 0, stream>>>(q_W + (size_t)l * CH * CH, q_b + l * CH,
                                      att_w + (size_t)l * 2 * CH, vvec + l * CH, c0 + l);
  }

  const int ks[3] = {205, 164, 132};

  for (int ch = 0; ch < nchunks; ++ch) {
    const int b0 = ch * bc;
    const int*   ids_c = x_ids + (size_t)b0 * NMAX;
    const float* adj_c = adj + (size_t)b0 * BS2;
    float*       xs_c  = xs + (size_t)b0 * 1024;

    build_a_kernel<<<dim3(NMAX, bc), 256, 0, stream>>>(adj_c, A);
    embed_kernel<<<dim3(NMAX, bc), 128, 0, stream>>>(ids_c, emb, X);

    int n = NMAX;
    for (int l = 0; l < 3; ++l) {
      int kk = ks[l];
      int mt = (n + BM - 1) / BM;
      const float* Wc = conv_W + (size_t)l * CH * CH;
      const float* Wg = gcn_W + (size_t)l * CH * CH;
      const float* aw = att_w + (size_t)l * 2 * CH;

      // ---- GAT ----
      gemm_kernel<<<dim3(CH / BN, mt, bc), 256, 0, stream>>>(
          X, BSC, LDC, Wc, 0, CH, H, BSC, LDC, nullptr, nullptr, n, CH, CH, 0, 0);
      rowdot_kernel<<<dim3(n, bc), 64, 0, stream>>>(
          H, att_dst + l * CH, att_src + l * CH, nullptr, si, sj, nullptr, nullptr, 2);
      softmax_kernel<<<dim3(n, bc), 256, 0, stream>>>(A, si, sj, nullptr, P, n);
      gemm_kernel<<<dim3(CH / BN, mt, bc), 256, 0, stream>>>(
          P, BS2, LD2, H, BSC, LDC, X, BSC, LDC, conv_b + l * CH, nullptr, n, CH, n, 1 | 2, 0);

      // ---- ASAP pool ----
      deg_kernel<<<dim3(n, bc), 64, 0, stream>>>(A, deg, dinv, n);
      gemm_kernel<<<dim3(CH / BN, mt, bc), 256, 0, stream>>>(
          X, BSC, LDC, Wg, 0, CH, H, BSC, LDC, nullptr, dinv, n, CH, CH, 4, 0);
      gemm_kernel<<<dim3(CH / BN, mt, bc), 256, 0, stream>>>(
          A, BS2, LD2, H, BSC, LDC, XP, BSC, LDC, gcn_b + l * CH, dinv, n, CH, n, 1 | 4, 0);
      rowdot_kernel<<<dim3(n, bc), 64, 0, stream>>>(
          XP, aw + CH, nullptr, nullptr, sj, nullptr, nullptr, nullptr, 1);
      maxgemm_kernel<<<dim3(CH / BN, mt, bc), 256, 0, stream>>>(A, XP, H, n, CH, n);
      rowdot_kernel<<<dim3(n, bc), 64, 0, stream>>>(
          H, vvec + l * CH, nullptr, nullptr, si, nullptr, nullptr, c0 + l, 1);
      softmax_kernel<<<dim3(n, bc), 256, 0, stream>>>(A, si, sj, att_b + l, P, n);
      gemm_kernel<<<dim3(CH / BN, mt, bc), 256, 0, stream>>>(
          P, BS2, LD2, X, BSC, LDC, H, BSC, LDC, nullptr, nullptr, n, CH, n, 0, 0);  // xc
      rowdot_kernel<<<dim3(n, bc), 64, 0, stream>>>(
          H, le_W1 + l * CH, le_W2 + l * CH, le_W3 + l * CH, t1, t2, t3, nullptr, 3);
      fit_kernel<<<dim3(n, bc), 64, 0, stream>>>(A, t1, t2, t3, deg, le_b1 + l, fit, n);
      topk_kernel<<<bc, 256, 0, stream>>>(fit, perm, vals, n, kk);
      gatherx_kernel<<<dim3(kk, bc), 128, 0, stream>>>(H, perm, vals, X);
      gathersk_kernel<<<dim3(kk, bc), 256, 0, stream>>>(P, perm, XP, n);
      int mtk = (kk + BM - 1) / BM;
      gemm_kernel<<<dim3((n + BN - 1) / BN, mtk, bc), 256, 0, stream>>>(
          XP, 65536, LD2, A, BS2, LD2, P, BS2, LD2, nullptr, nullptr, kk, n, n, 0, 0);  // SA
      gemm_kernel<<<dim3((kk + BN - 1) / BN, mtk, bc), 256, 0, stream>>>(
          P, BS2, LD2, XP, 65536, LD2, A, BS2, LD2, nullptr, nullptr, kk, kk, n, 0, 1); // A_new
      diagfix_kernel<<<bc, 256, 0, stream>>>(A, kk);
      readout_kernel<<<bc, 256, 0, stream>>>(X, xs_c, kk);
      n = kk;
    }
  }

  // ---- final MLP (full batch) ----
  gemm_kernel<<<dim3(CH / BN, 2, 1), 256, 0, stream>>>(
      xs, 0, 2 * CH, lin1_W, 0, CH, FH, 0, CH, lin1_b, nullptr, NB, CH, 2 * CH, 1 | 2, 0);
  gemm_kernel<<<dim3((511 + BN - 1) / BN, 2, 1), 256, 0, stream>>>(
      FH, 0, CH, lin2_W, 0, 511, out, 0, 511, lin2_b, nullptr, NB, 511, CH, 1, 0);
}

// Round 3
// 7880.543 us; speedup vs baseline: 1.2383x; 1.2383x over previous
//
#include <hip/hip_runtime.h>
#include <math.h>

#define NB   256
#define NMAX 256
#define CH   512
#define LD2  256
#define LDC  512
#define BS2  (256*256)
#define BSC  (256*512)

typedef _Float16 f16;
typedef __attribute__((ext_vector_type(4))) f16 f16x4;
typedef __attribute__((ext_vector_type(8))) f16 f16x8;
typedef __attribute__((ext_vector_type(4))) float f32x4;

__device__ __forceinline__ float warp_sum_f(float v) {
#pragma unroll
  for (int m = 32; m >= 1; m >>= 1) v += __shfl_xor(v, m);
  return v;
}

// split fp32 -> f16 hi + f16 lo where x ~= hi + lo/2048.
// hi forced to 0 below f16-min-normal so MFMA denorm flush can't lose it.
__device__ __forceinline__ void split1(float x, f16& h, f16& l) {
  float xh = (__builtin_fabsf(x) >= 6.103515625e-05f) ? x : 0.f;
  f16 hh = (f16)xh;
  float hf = (float)hh;
  h = hh;
  l = (f16)((x - hf) * 2048.0f);
}

__device__ __forceinline__ void split4(const float* v, f16x4& h, f16x4& l) {
#pragma unroll
  for (int j = 0; j < 4; ++j) { f16 hh, ll; split1(v[j], hh, ll); h[j] = hh; l[j] = ll; }
}

// ---------------- MFMA split-f16 GEMM ----------------
// Y[b] = L[b] @ R(^T) ; mode: 0 = R f32 [K][N], 1 = R f32 [N][K] (transB),
// 2 = R pre-split f16 hi/lo, layout [N][K].
// flags: 1 = +bias[col], 2 = relu, 4 = *rowscale[b,row] (applied before bias)
__global__ __launch_bounds__(256, 2)
void mgemm_kernel(const float* __restrict__ Lp, long bsL, int ldl,
                  const float* __restrict__ Rp, long bsR, int ldr,
                  const f16* __restrict__ Rh, const f16* __restrict__ Rl,
                  float* __restrict__ Yp, long bsY, int ldy,
                  const float* __restrict__ bias,
                  const float* __restrict__ rowscale,
                  int M, int Ncol, int K, int flags, int mode)
{
  __shared__ f16 Ah[128][40];
  __shared__ f16 Al[128][40];
  __shared__ f16 Bh[128][40];
  __shared__ f16 Bl[128][40];
  const int b   = blockIdx.z;
  const int i0  = blockIdx.y * 128;
  const int n0  = blockIdx.x * 128;
  const int tid = threadIdx.x;
  const int w  = tid >> 6, l = tid & 63;
  const int wr = (w >> 1) * 64, wc = (w & 1) * 64;
  const int lr = l & 15, lq = l >> 4;
  const float* Lb = Lp + (long)b * bsL;
  const float* Rb = Rp + (long)b * bsR;

  f32x4 acc1[4][4], acc2[4][4];
#pragma unroll
  for (int mi = 0; mi < 4; ++mi)
#pragma unroll
    for (int ni = 0; ni < 4; ++ni) {
      acc1[mi][ni] = (f32x4){0.f, 0.f, 0.f, 0.f};
      acc2[mi][ni] = (f32x4){0.f, 0.f, 0.f, 0.f};
    }

  for (int k0 = 0; k0 < K; k0 += 32) {
    // ---- stage A (L operand), always f32 [M][K] ----
#pragma unroll
    for (int rep = 0; rep < 4; ++rep) {
      int row = rep * 32 + (tid >> 3);
      int kq  = (tid & 7) * 4;
      int gr = i0 + row, gk = k0 + kq;
      float v[4] = {0.f, 0.f, 0.f, 0.f};
      if (gr < M) {
        if (gk + 3 < K) {
          float4 t = *(const float4*)(Lb + (long)gr * ldl + gk);
          v[0] = t.x; v[1] = t.y; v[2] = t.z; v[3] = t.w;
        } else {
#pragma unroll
          for (int j = 0; j < 4; ++j) if (gk + j < K) v[j] = Lb[(long)gr * ldl + gk + j];
        }
      }
      f16x4 h, lo; split4(v, h, lo);
      *(f16x4*)&Ah[row][kq] = h;
      *(f16x4*)&Al[row][kq] = lo;
    }
    // ---- stage B into Bt[col][k] ----
    if (mode == 0) {
#pragma unroll
      for (int rep = 0; rep < 4; ++rep) {
        int c  = rep * 32 + (tid & 31);
        int kq = (tid >> 5) * 4;
        int gc = n0 + c, gk = k0 + kq;
        float v[4] = {0.f, 0.f, 0.f, 0.f};
        if (gc < Ncol) {
#pragma unroll
          for (int j = 0; j < 4; ++j) if (gk + j < K) v[j] = Rb[(long)(gk + j) * ldr + gc];
        }
        f16x4 h, lo; split4(v, h, lo);
        *(f16x4*)&Bh[c][kq] = h;
        *(f16x4*)&Bl[c][kq] = lo;
      }
    } else if (mode == 1) {
#pragma unroll
      for (int rep = 0; rep < 4; ++rep) {
        int c  = rep * 32 + (tid >> 3);
        int kq = (tid & 7) * 4;
        int gc = n0 + c, gk = k0 + kq;
        float v[4] = {0.f, 0.f, 0.f, 0.f};
        if (gc < Ncol) {
          if (gk + 3 < K) {
            float4 t = *(const float4*)(Rb + (long)gc * ldr + gk);
            v[0] = t.x; v[1] = t.y; v[2] = t.z; v[3] = t.w;
          } else {
#pragma unroll
            for (int j = 0; j < 4; ++j) if (gk + j < K) v[j] = Rb[(long)gc * ldr + gk + j];
          }
        }
        f16x4 h, lo; split4(v, h, lo);
        *(f16x4*)&Bh[c][kq] = h;
        *(f16x4*)&Bl[c][kq] = lo;
      }
    } else {
#pragma unroll
      for (int rep = 0; rep < 4; ++rep) {
        int c  = rep * 32 + (tid >> 3);
        int kq = (tid & 7) * 4;
        int gc = n0 + c, gk = k0 + kq;
        f16x4 h = (f16x4){0, 0, 0, 0}, lo = (f16x4){0, 0, 0, 0};
        if (gc < Ncol) {
          if (gk + 3 < K) {
            h  = *(const f16x4*)(Rh + (long)gc * K + gk);
            lo = *(const f16x4*)(Rl + (long)gc * K + gk);
          } else {
#pragma unroll
            for (int j = 0; j < 4; ++j) if (gk + j < K) {
              h[j]  = Rh[(long)gc * K + gk + j];
              lo[j] = Rl[(long)gc * K + gk + j];
            }
          }
        }
        *(f16x4*)&Bh[c][kq] = h;
        *(f16x4*)&Bl[c][kq] = lo;
      }
    }
    __syncthreads();

    // ---- fragments + MFMA ----
    f16x8 bh[4], bl[4];
#pragma unroll
    for (int ni = 0; ni < 4; ++ni) {
      bh[ni] = *(const f16x8*)&Bh[wc + ni * 16 + lr][lq * 8];
      bl[ni] = *(const f16x8*)&Bl[wc + ni * 16 + lr][lq * 8];
    }
#pragma unroll
    for (int mi = 0; mi < 4; ++mi) {
      f16x8 ah = *(const f16x8*)&Ah[wr + mi * 16 + lr][lq * 8];
      f16x8 al = *(const f16x8*)&Al[wr + mi * 16 + lr][lq * 8];
#pragma unroll
      for (int ni = 0; ni < 4; ++ni) {
        acc1[mi][ni] = __builtin_amdgcn_mfma_f32_16x16x32_f16(ah, bh[ni], acc1[mi][ni], 0, 0, 0);
        acc2[mi][ni] = __builtin_amdgcn_mfma_f32_16x16x32_f16(ah, bl[ni], acc2[mi][ni], 0, 0, 0);
        acc2[mi][ni] = __builtin_amdgcn_mfma_f32_16x16x32_f16(al, bh[ni], acc2[mi][ni], 0, 0, 0);
      }
    }
    __syncthreads();
  }

  // ---- epilogue: C/D layout col = lane&15, row = (lane>>4)*4 + reg ----
  float* Yb = Yp + (long)b * bsY;
  const float inv2048 = 4.8828125e-04f;
#pragma unroll
  for (int mi = 0; mi < 4; ++mi) {
#pragma unroll
    for (int ni = 0; ni < 4; ++ni) {
      int col = n0 + wc + ni * 16 + lr;
      if (col >= Ncol) continue;
      float bv = (flags & 1) ? bias[col] : 0.f;
#pragma unroll
      for (int r = 0; r < 4; ++r) {
        int row = i0 + wr + mi * 16 + lq * 4 + r;
        if (row >= M) continue;
        float vv = acc1[mi][ni][r] + acc2[mi][ni][r] * inv2048;
        if (flags & 4) vv *= rowscale[b * 256 + row];
        vv += bv;
        if (flags & 2) vv = fmaxf(vv, 0.f);
        Yb[(long)row * ldy + col] = vv;
      }
    }
  }
}

// pre-split weights: W [K][N] f32 -> Wt_hi/lo [N][K] f16
__global__ void presplit_kernel(const float* __restrict__ W, f16* __restrict__ Wh,
                                f16* __restrict__ Wl, int K, int N) {
  int n = blockIdx.x;
  for (int k = threadIdx.x; k < K; k += blockDim.x) {
    f16 h, l; split1(W[(long)k * N + n], h, l);
    Wh[(long)n * K + k] = h;
    Wl[(long)n * K + k] = l;
  }
}

// ---------------- neighbor-max replacement ----------------
// per graph: colmax over active rows, dotted with v -> si_full (value for all-true rows)
__global__ __launch_bounds__(256)
void colmax_kernel(const float* __restrict__ XP, const float* __restrict__ v,
                   const float* __restrict__ c0, float* __restrict__ si_full, int n) {
  int b = blockIdx.x, t = threadIdx.x;
  const float* xb = XP + (long)b * BSC;
  float m1 = -1e9f, m2 = -1e9f;
  for (int j = 0; j < n; ++j) {
    m1 = fmaxf(m1, xb[(long)j * LDC + t]);
    m2 = fmaxf(m2, xb[(long)j * LDC + t + 256]);
  }
  __shared__ float red[256];
  red[t] = m1 * v[t] + m2 * v[t + 256];
  __syncthreads();
  for (int s = 128; s > 0; s >>= 1) { if (t < s) red[t] += red[t + s]; __syncthreads(); }
  if (t == 0) si_full[b] = red[0] + c0[0];
}

// per (b,i): exact mask; full rows reuse si_full, sparse rows gather-max over list
__global__ __launch_bounds__(256)
void nbrdot_kernel(const float* __restrict__ A, const float* __restrict__ XP,
                   const float* __restrict__ v, const float* __restrict__ c0,
                   const float* __restrict__ si_full, float* __restrict__ si, int n) {
  int b = blockIdx.y, i = blockIdx.x, t = threadIdx.x;
  __shared__ int list[256];
  __shared__ int cnt, nmiss;
  __shared__ float red[256];
  if (t == 0) { cnt = 0; nmiss = 0; }
  __syncthreads();
  if (t < n) {
    float a = A[(long)b * BS2 + i * 256 + t];
    if (a > 0.f) { int p = atomicAdd(&cnt, 1); list[p] = t; }
    else atomicAdd(&nmiss, 1);
  }
  __syncthreads();
  if (nmiss == 0) {
    if (t == 0) si[b * 256 + i] = si_full[b];
    return;
  }
  int c = cnt;
  const float* xb = XP + (long)b * BSC;
  float m1 = -1e9f, m2 = -1e9f;
  for (int q = 0; q < c; ++q) {
    int j = list[q];
    m1 = fmaxf(m1, xb[(long)j * LDC + t]);
    m2 = fmaxf(m2, xb[(long)j * LDC + t + 256]);
  }
  red[t] = m1 * v[t] + m2 * v[t + 256];
  __syncthreads();
  for (int s = 128; s > 0; s >>= 1) { if (t < s) red[t] += red[t + s]; __syncthreads(); }
  if (t == 0) si[b * 256 + i] = red[0] + c0[0];
}

// ---------------- small kernels (unchanged from round 2) ----------------
__global__ void build_a_kernel(const float* __restrict__ adj, float* __restrict__ A) {
  int b = blockIdx.y, i = blockIdx.x, j = threadIdx.x;
  float v = adj[(long)b * BS2 + i * 256 + j];
  if (i == j) v = fmaxf(v, 1.f);
  A[(long)b * BS2 + i * 256 + j] = v;
}

__global__ void embed_kernel(const int* __restrict__ ids, const float* __restrict__ emb,
                             float* __restrict__ X) {
  int b = blockIdx.y, i = blockIdx.x, t = threadIdx.x;
  int id = ids[b * NMAX + i];
  float4 v = *(const float4*)(emb + (long)id * CH + t * 4);
  *(float4*)(X + (long)b * BSC + (long)i * LDC + t * 4) = v;
}

__global__ void rowdot_kernel(const float* __restrict__ X,
                              const float* __restrict__ v1, const float* __restrict__ v2,
                              const float* __restrict__ v3,
                              float* __restrict__ o1, float* __restrict__ o2,
                              float* __restrict__ o3,
                              const float* __restrict__ cadd, int nvec) {
  int b = blockIdx.y, i = blockIdx.x, lane = threadIdx.x;
  const float* xr = X + (long)b * BSC + (long)i * LDC;
  float a1 = 0.f, a2 = 0.f, a3 = 0.f;
  for (int c = lane; c < CH; c += 64) {
    float x = xr[c];
    a1 = fmaf(x, v1[c], a1);
    if (nvec > 1) a2 = fmaf(x, v2[c], a2);
    if (nvec > 2) a3 = fmaf(x, v3[c], a3);
  }
  a1 = warp_sum_f(a1);
  if (nvec > 1) a2 = warp_sum_f(a2);
  if (nvec > 2) a3 = warp_sum_f(a3);
  if (lane == 0) {
    o1[b * 256 + i] = a1 + (cadd ? cadd[0] : 0.f);
    if (nvec > 1) o2[b * 256 + i] = a2;
    if (nvec > 2) o3[b * 256 + i] = a3;
  }
}

__global__ void vq_kernel(const float* __restrict__ qW, const float* __restrict__ qb,
                          const float* __restrict__ aw, float* __restrict__ v,
                          float* __restrict__ c0) {
  int blk = blockIdx.x, lane = threadIdx.x;
  if (blk < 512) {
    float s = 0.f;
    for (int j = lane; j < CH; j += 64) s = fmaf(qW[(long)blk * CH + j], aw[j], s);
    s = warp_sum_f(s);
    if (lane == 0) v[blk] = s;
  } else {
    float s = 0.f;
    for (int j = lane; j < CH; j += 64) s = fmaf(qb[j], aw[j], s);
    s = warp_sum_f(s);
    if (lane == 0) c0[0] = s;
  }
}

__global__ __launch_bounds__(256)
void softmax_kernel(const float* __restrict__ A, const float* __restrict__ si,
                    const float* __restrict__ sj, const float* __restrict__ attb,
                    float* __restrict__ P, int n) {
  int b = blockIdx.y, i = blockIdx.x, j = threadIdx.x;
  __shared__ float red[256];
  float logit = -1e30f, e = 0.f;
  float siv = si[b * 256 + i];
  if (j < n) {
    float a = A[(long)b * BS2 + i * 256 + j];
    float z = siv + sj[b * 256 + j] + (attb ? attb[0] : 0.f);
    z = (z > 0.f) ? z : 0.2f * z;
    logit = (a > 0.f) ? z : -1e9f;
  }
  red[j] = logit; __syncthreads();
  for (int s = 128; s > 0; s >>= 1) { if (j < s) red[j] = fmaxf(red[j], red[j + s]); __syncthreads(); }
  float mx = red[0]; __syncthreads();
  if (j < n) e = expf(logit - mx);
  red[j] = e; __syncthreads();
  for (int s = 128; s > 0; s >>= 1) { if (j < s) red[j] += red[j + s]; __syncthreads(); }
  float sum = red[0];
  if (j < n) P[(long)b * BS2 + i * 256 + j] = e / sum;
}

__global__ void deg_kernel(const float* __restrict__ A, float* __restrict__ deg,
                           float* __restrict__ dinv, int n) {
  int b = blockIdx.y, i = blockIdx.x, lane = threadIdx.x;
  const float* ar = A + (long)b * BS2 + i * 256;
  float s = 0.f;
  for (int j = lane; j < n; j += 64) s += ar[j];
  s = warp_sum_f(s);
  if (lane == 0) {
    deg[b * 256 + i] = s;
    dinv[b * 256 + i] = (s > 0.f) ? (1.f / sqrtf(s)) : 0.f;
  }
}

__global__ void fit_kernel(const float* __restrict__ A, const float* __restrict__ t1,
                           const float* __restrict__ t2, const float* __restrict__ t3,
                           const float* __restrict__ deg, const float* __restrict__ leb1,
                           float* __restrict__ fit, int n) {
  int b = blockIdx.y, i = blockIdx.x, lane = threadIdx.x;
  const float* ar = A + (long)b * BS2 + i * 256;
  float s = 0.f;
  for (int j = lane; j < n; j += 64) s = fmaf(ar[j], t3[b * 256 + j], s);
  s = warp_sum_f(s);
  if (lane == 0) {
    float z = t1[b * 256 + i] + leb1[0] + t2[b * 256 + i] * deg[b * 256 + i] - s;
    fit[b * 256 + i] = 1.f / (1.f + expf(-z));
  }
}

__global__ __launch_bounds__(256)
void topk_kernel(const float* __restrict__ fit, int* __restrict__ perm,
                 float* __restrict__ vals, int n, int k) {
  __shared__ float v[256];
  __shared__ int ix[256];
  int b = blockIdx.x, t = threadIdx.x;
  v[t] = (t < n) ? fit[b * 256 + t] : -1e30f;
  ix[t] = t;
  __syncthreads();
  for (int size = 2; size <= 256; size <<= 1)
    for (int str = size >> 1; str > 0; str >>= 1) {
      int p = t ^ str;
      if (p > t) {
        bool desc = ((t & size) == 0);
        float v1 = v[t], v2 = v[p]; int i1 = ix[t], i2 = ix[p];
        bool inorder = (v1 > v2) || (v1 == v2 && i1 < i2);
        if (inorder != desc) { v[t] = v2; v[p] = v1; ix[t] = i2; ix[p] = i1; }
      }
      __syncthreads();
    }
  if (t < k) { perm[b * 256 + t] = ix[t]; vals[b * 256 + t] = v[t]; }
}

__global__ void gatherx_kernel(const float* __restrict__ Hc, const int* __restrict__ perm,
                               const float* __restrict__ vals, float* __restrict__ X) {
  int b = blockIdx.y, p = blockIdx.x, t = threadIdx.x;
  int src = perm[b * 256 + p];
  float sv = vals[b * 256 + p];
  float4 v = *(const float4*)(Hc + (long)b * BSC + (long)src * LDC + t * 4);
  v.x *= sv; v.y *= sv; v.z *= sv; v.w *= sv;
  *(float4*)(X + (long)b * BSC + (long)p * LDC + t * 4) = v;
}

__global__ void gathersk_kernel(const float* __restrict__ P, const int* __restrict__ perm,
                                float* __restrict__ Sk, int n) {
  int b = blockIdx.y, p = blockIdx.x, j = threadIdx.x;
  int src = perm[b * 256 + p];
  if (j < n) Sk[(long)b * 65536 + p * 256 + j] = P[(long)b * BS2 + src * 256 + j];
}

__global__ void diagfix_kernel(float* __restrict__ A, int k) {
  int b = blockIdx.x, p = threadIdx.x;
  if (p < k) {
    long o = (long)b * BS2 + p * 256 + p;
    float v = A[o];
    if (v <= 0.f) A[o] = v + 1.f;
  }
}

__global__ void readout_kernel(const float* __restrict__ X, float* __restrict__ xs, int k) {
  int b = blockIdx.x, t = threadIdx.x;
#pragma unroll
  for (int rep = 0; rep < 2; ++rep) {
    int c = t + rep * 256;
    float s = 0.f, m = -1e30f;
    for (int p = 0; p < k; ++p) {
      float v = X[(long)b * BSC + (long)p * LDC + c];
      s += v; m = fmaxf(m, v);
    }
    xs[b * 1024 + c] += s / (float)k;
    xs[b * 1024 + 512 + c] += m;
  }
}

// ---------------- host orchestration ----------------
extern "C" void kernel_launch(void* const* d_in, const int* in_sizes, int n_in,
                              void* d_out, int out_size, void* d_ws, size_t ws_size,
                              hipStream_t stream) {
  (void)in_sizes; (void)n_in; (void)out_size;
  const int*   x_ids  = (const int*)  d_in[0];
  const float* adj    = (const float*)d_in[2];
  const float* emb    = (const float*)d_in[3];
  const float* conv_W = (const float*)d_in[4];
  const float* conv_b = (const float*)d_in[5];
  const float* att_src= (const float*)d_in[6];
  const float* att_dst= (const float*)d_in[7];
  const float* q_W    = (const float*)d_in[8];
  const float* q_b    = (const float*)d_in[9];
  const float* att_w  = (const float*)d_in[10];
  const float* att_b  = (const float*)d_in[11];
  const float* gcn_W  = (const float*)d_in[12];
  const float* gcn_b  = (const float*)d_in[13];
  const float* le_W1  = (const float*)d_in[14];
  const float* le_b1  = (const float*)d_in[15];
  const float* le_W2  = (const float*)d_in[16];
  const float* le_W3  = (const float*)d_in[17];
  const float* lin1_W = (const float*)d_in[18];
  const float* lin1_b = (const float*)d_in[19];
  const float* lin2_W = (const float*)d_in[20];
  const float* lin2_b = (const float*)d_in[21];
  float* out = (float*)d_out;

  // pre-split weight element counts
  const size_t WN_CONV = 3u * CH * CH;         // 786432
  const size_t WN_GCN  = 3u * CH * CH;
  const size_t WN_L1   = (size_t)(2 * CH) * CH; // 524288
  const size_t WN_L2   = (size_t)CH * (512 - 1);
  const size_t WTOT    = WN_CONV + WN_GCN + WN_L1 + WN_L2;

  // adaptive batch chunking
  const size_t per_b  = (size_t)(3 * 131072 + 2 * 65536 + 11 * 256) * 4;
  const size_t fixedb = (size_t)(3 * 512 + 64 + 256 * 1024 + 256 * 512) * 4 + WTOT * 2 * 2;
  const size_t slack  = 64 * 256;
  int bc = 4;
  for (int cand = 256; cand >= 4; cand >>= 1) {
    if ((size_t)cand * per_b + fixedb + slack <= ws_size) { bc = cand; break; }
  }
  const int nchunks = NB / bc;

  char* w = (char*)d_ws;
  auto alloc = [&](size_t bytes) { char* p = w; w += (bytes + 255) & ~(size_t)255; return p; };
  // fixed
  float* xs   = (float*)alloc(sizeof(float) * NB * 1024);
  float* FH   = (float*)alloc(sizeof(float) * NB * CH);
  float* vvec = (float*)alloc(sizeof(float) * 3 * CH);
  float* c0   = (float*)alloc(256);
  f16*   Wh   = (f16*)alloc(WTOT * 2);
  f16*   Wl   = (f16*)alloc(WTOT * 2);
  // chunk-local
  float* X    = (float*)alloc(sizeof(float) * bc * NMAX * CH);
  float* H    = (float*)alloc(sizeof(float) * bc * NMAX * CH);
  float* XP   = (float*)alloc(sizeof(float) * bc * NMAX * CH);
  float* P    = (float*)alloc(sizeof(float) * bc * NMAX * NMAX);
  float* A    = (float*)alloc(sizeof(float) * bc * NMAX * NMAX);
  float* si   = (float*)alloc(sizeof(float) * bc * NMAX);
  float* sj   = (float*)alloc(sizeof(float) * bc * NMAX);
  float* deg  = (float*)alloc(sizeof(float) * bc * NMAX);
  float* dinv = (float*)alloc(sizeof(float) * bc * NMAX);
  float* t1   = (float*)alloc(sizeof(float) * bc * NMAX);
  float* t2   = (float*)alloc(sizeof(float) * bc * NMAX);
  float* t3   = (float*)alloc(sizeof(float) * bc * NMAX);
  float* fit  = (float*)alloc(sizeof(float) * bc * NMAX);
  float* vals = (float*)alloc(sizeof(float) * bc * NMAX);
  int*   perm = (int*)  alloc(sizeof(int)   * bc * NMAX);
  float* sifu = (float*)alloc(sizeof(float) * bc);

  f16* cwh = Wh;                 f16* cwl = Wl;
  f16* gwh = Wh + WN_CONV;       f16* gwl = Wl + WN_CONV;
  f16* l1h = Wh + WN_CONV + WN_GCN;            f16* l1l = Wl + WN_CONV + WN_GCN;
  f16* l2h = l1h + WN_L1;        f16* l2l = l1l + WN_L1;

  hipMemsetAsync(xs, 0, sizeof(float) * NB * 1024, stream);

  // one-time: pre-split weights (transposed), per-layer v/c0
  for (int l = 0; l < 3; ++l) {
    presplit_kernel<<<512, 256, 0, stream>>>(conv_W + (size_t)l * CH * CH,
                                             cwh + (size_t)l * CH * CH,
                                             cwl + (size_t)l * CH * CH, CH, CH);
    presplit_kernel<<<512, 256, 0, stream>>>(gcn_W + (size_t)l * CH * CH,
                                             gwh + (size_t)l * CH * CH,
                                             gwl + (size_t)l * CH * CH, CH, CH);
    vq_kernel<<<513, 64, 0, stream>>>(q_W + (size_t)l * CH * CH, q_b + l * CH,
                                      att_w + (size_t)l * 2 * CH, vvec + l * CH, c0 + l);
  }
  presplit_kernel<<<512, 256, 0, stream>>>(lin1_W, l1h, l1l, 2 * CH, CH);
  presplit_kernel<<<511, 256, 0, stream>>>(lin2_W, l2h, l2l, CH, 511);

  const int ks[3] = {205, 164, 132};

  for (int ch = 0; ch < nchunks; ++ch) {
    const int b0 = ch * bc;
    const int*   ids_c = x_ids + (size_t)b0 * NMAX;
    const float* adj_c = adj + (size_t)b0 * BS2;
    float*       xs_c  = xs + (size_t)b0 * 1024;

    build_a_kernel<<<dim3(NMAX, bc), 256, 0, stream>>>(adj_c, A);
    embed_kernel<<<dim3(NMAX, bc), 128, 0, stream>>>(ids_c, emb, X);

    int n = NMAX;
    for (int l = 0; l < 3; ++l) {
      int kk = ks[l];
      int mt = (n + 127) / 128;
      const float* aw = att_w + (size_t)l * 2 * CH;

      // ---- GAT ----
      mgemm_kernel<<<dim3(4, mt, bc), 256, 0, stream>>>(
          X, BSC, LDC, nullptr, 0, 0, cwh + (size_t)l * CH * CH, cwl + (size_t)l * CH * CH,
          H, BSC, LDC, nullptr, nullptr, n, CH, CH, 0, 2);
      rowdot_kernel<<<dim3(n, bc), 64, 0, stream>>>(
          H, att_dst + l * CH, att_src + l * CH, nullptr, si, sj, nullptr, nullptr, 2);
      softmax_kernel<<<dim3(n, bc), 256, 0, stream>>>(A, si, sj, nullptr, P, n);
      mgemm_kernel<<<dim3(4, mt, bc), 256, 0, stream>>>(
          P, BS2, LD2, H, BSC, LDC, nullptr, nullptr,
          X, BSC, LDC, conv_b + l * CH, nullptr, n, CH, n, 1 | 2, 0);

      // ---- ASAP pool ----
      deg_kernel<<<dim3(n, bc), 64, 0, stream>>>(A, deg, dinv, n);
      mgemm_kernel<<<dim3(4, mt, bc), 256, 0, stream>>>(
          X, BSC, LDC, nullptr, 0, 0, gwh + (size_t)l * CH * CH, gwl + (size_t)l * CH * CH,
          H, BSC, LDC, nullptr, dinv, n, CH, CH, 4, 2);
      mgemm_kernel<<<dim3(4, mt, bc), 256, 0, stream>>>(
          A, BS2, LD2, H, BSC, LDC, nullptr, nullptr,
          XP, BSC, LDC, gcn_b + l * CH, dinv, n, CH, n, 1 | 4, 0);
      rowdot_kernel<<<dim3(n, bc), 64, 0, stream>>>(
          XP, aw + CH, nullptr, nullptr, sj, nullptr, nullptr, nullptr, 1);
      colmax_kernel<<<bc, 256, 0, stream>>>(XP, vvec + l * CH, c0 + l, sifu, n);
      nbrdot_kernel<<<dim3(n, bc), 256, 0, stream>>>(A, XP, vvec + l * CH, c0 + l, sifu, si, n);
      softmax_kernel<<<dim3(n, bc), 256, 0, stream>>>(A, si, sj, att_b + l, P, n);
      mgemm_kernel<<<dim3(4, mt, bc), 256, 0, stream>>>(
          P, BS2, LD2, X, BSC, LDC, nullptr, nullptr,
          H, BSC, LDC, nullptr, nullptr, n, CH, n, 0, 0);  // xc
      rowdot_kernel<<<dim3(n, bc), 64, 0, stream>>>(
          H, le_W1 + l * CH, le_W2 + l * CH, le_W3 + l * CH, t1, t2, t3, nullptr, 3);
      fit_kernel<<<dim3(n, bc), 64, 0, stream>>>(A, t1, t2, t3, deg, le_b1 + l, fit, n);
      topk_kernel<<<bc, 256, 0, stream>>>(fit, perm, vals, n, kk);
      gatherx_kernel<<<dim3(kk, bc), 128, 0, stream>>>(H, perm, vals, X);
      gathersk_kernel<<<dim3(kk, bc), 256, 0, stream>>>(P, perm, XP, n);
      int mtk = (kk + 127) / 128;
      mgemm_kernel<<<dim3((n + 127) / 128, mtk, bc), 256, 0, stream>>>(
          XP, 65536, LD2, A, BS2, LD2, nullptr, nullptr,
          P, BS2, LD2, nullptr, nullptr, kk, n, n, 0, 0);  // SA
      mgemm_kernel<<<dim3(mtk, mtk, bc), 256, 0, stream>>>(
          P, BS2, LD2, XP, 65536, LD2, nullptr, nullptr,
          A, BS2, LD2, nullptr, nullptr, kk, kk, n, 0, 1); // A_new = SA @ Sk^T
      diagfix_kernel<<<bc, 256, 0, stream>>>(A, kk);
      readout_kernel<<<bc, 256, 0, stream>>>(X, xs_c, kk);
      n = kk;
    }
  }

  // ---- final MLP (full batch) ----
  mgemm_kernel<<<dim3(4, 2, 1), 256, 0, stream>>>(
      xs, 0, 2 * CH, nullptr, 0, 0, l1h, l1l,
      FH, 0, CH, lin1_b, nullptr, NB, CH, 2 * CH, 1 | 2, 2);
  mgemm_kernel<<<dim3(4, 2, 1), 256, 0, stream>>>(
      FH, 0, CH, nullptr, 0, 0, l2h, l2l,
      out, 0, 511, lin2_b, nullptr, NB, 511, CH, 1, 2);
}

// Round 4
// 7692.131 us; speedup vs baseline: 1.2686x; 1.0245x over previous
//
#include <hip/hip_runtime.h>
#include <math.h>

#define NB   256
#define NMAX 256
#define CH   512
#define LD2  256
#define LDC  512
#define BS2  (256*256)
#define BSC  (256*512)

typedef _Float16 f16;
typedef __attribute__((ext_vector_type(4))) f16 f16x4;
typedef __attribute__((ext_vector_type(8))) f16 f16x8;
typedef __attribute__((ext_vector_type(4))) float f32x4;

#define INV2048 4.8828125e-04f

__device__ __forceinline__ float warp_sum_f(float v) {
#pragma unroll
  for (int m = 32; m >= 1; m >>= 1) v += __shfl_xor(v, m);
  return v;
}

__device__ __forceinline__ void split1(float x, f16& h, f16& l) {
  float xh = (__builtin_fabsf(x) >= 6.103515625e-05f) ? x : 0.f;
  f16 hh = (f16)xh;
  float hf = (float)hh;
  h = hh;
  l = (f16)((x - hf) * 2048.0f);
}

__device__ __forceinline__ float rc(f16 h, f16 l) {
  return (float)h + (float)l * INV2048;
}

// ---------------- plane GEMM: all operands pre-split f16 hi/lo ----------------
// A: [M][K] planes (lda, bsA elems). B: BMODE 0 -> [N][K] planes (k-contig, ldb);
// BMODE 1 -> [K][N] planes (ldb = N row stride). Y: planes and/or f32.
// flags: 1 bias, 2 relu, 4 rowscale (before bias), 8 write planes, 16 write f32
template <int BMODE>
__global__ __launch_bounds__(256, 2)
void pgemm_kernel(const f16* __restrict__ Ahp, const f16* __restrict__ Alp, long bsA, int lda,
                  const f16* __restrict__ Bhp, const f16* __restrict__ Blp, long bsB, int ldb,
                  f16* __restrict__ Yh, f16* __restrict__ Yl, float* __restrict__ Yf,
                  long bsY, int ldy,
                  const float* __restrict__ bias, const float* __restrict__ rowscale,
                  int M, int Ncol, int K, int flags)
{
  __shared__ f16 Ah[128][40];
  __shared__ f16 Al[128][40];
  __shared__ f16 Bh[128][40];
  __shared__ f16 Bl[128][40];
  const int b   = blockIdx.z;
  const int i0  = blockIdx.y * 128;
  const int n0  = blockIdx.x * 128;
  const int tid = threadIdx.x;
  const int w  = tid >> 6, l = tid & 63;
  const int wr = (w >> 1) * 64, wc = (w & 1) * 64;
  const int lr = l & 15, lq = l >> 4;
  const f16* Abh = Ahp + (long)b * bsA;
  const f16* Abl = Alp + (long)b * bsA;
  const f16* Bbh = Bhp + (long)b * bsB;
  const f16* Bbl = Blp + (long)b * bsB;

  f32x4 acc1[4][4], acc2[4][4];
#pragma unroll
  for (int mi = 0; mi < 4; ++mi)
#pragma unroll
    for (int ni = 0; ni < 4; ++ni) {
      acc1[mi][ni] = (f32x4){0.f, 0.f, 0.f, 0.f};
      acc2[mi][ni] = (f32x4){0.f, 0.f, 0.f, 0.f};
    }

  for (int k0 = 0; k0 < K; k0 += 32) {
    // ---- stage A: [M][K] planes -> Ah/Al[row][k] ----
#pragma unroll
    for (int rep = 0; rep < 4; ++rep) {
      int row = rep * 32 + (tid >> 3);
      int kq  = (tid & 7) * 4;
      int gr = i0 + row, gk = k0 + kq;
      f16x4 h = (f16x4){0, 0, 0, 0}, lo = (f16x4){0, 0, 0, 0};
      if (gr < M) {
        if (gk + 3 < K) {
          h  = *(const f16x4*)(Abh + (long)gr * lda + gk);
          lo = *(const f16x4*)(Abl + (long)gr * lda + gk);
        } else {
#pragma unroll
          for (int j = 0; j < 4; ++j) if (gk + j < K) {
            h[j]  = Abh[(long)gr * lda + gk + j];
            lo[j] = Abl[(long)gr * lda + gk + j];
          }
        }
      }
      *(f16x4*)&Ah[row][kq] = h;
      *(f16x4*)&Al[row][kq] = lo;
    }
    // ---- stage B -> Bh/Bl[col][k] ----
    if (BMODE == 0) {
#pragma unroll
      for (int rep = 0; rep < 4; ++rep) {
        int c  = rep * 32 + (tid >> 3);
        int kq = (tid & 7) * 4;
        int gc = n0 + c, gk = k0 + kq;
        f16x4 h = (f16x4){0, 0, 0, 0}, lo = (f16x4){0, 0, 0, 0};
        if (gc < Ncol) {
          if (gk + 3 < K) {
            h  = *(const f16x4*)(Bbh + (long)gc * ldb + gk);
            lo = *(const f16x4*)(Bbl + (long)gc * ldb + gk);
          } else {
#pragma unroll
            for (int j = 0; j < 4; ++j) if (gk + j < K) {
              h[j]  = Bbh[(long)gc * ldb + gk + j];
              lo[j] = Bbl[(long)gc * ldb + gk + j];
            }
          }
        }
        *(f16x4*)&Bh[c][kq] = h;
        *(f16x4*)&Bl[c][kq] = lo;
      }
    } else {
      // B is [K][N]: transpose-stage. thread: cols c8..c8+7, k-pair (k0p, k0p+1)
      int c8  = (tid & 15) * 8;
      int k0p = (tid >> 4) * 2;
      int gc = n0 + c8;
      f16x8 va = (f16x8){0,0,0,0,0,0,0,0}, vb = va, wa = va, wb = va;
      int gka = k0 + k0p, gkb = gka + 1;
      if (gka < K) { va = *(const f16x8*)(Bbh + (long)gka * ldb + gc);
                     wa = *(const f16x8*)(Bbl + (long)gka * ldb + gc); }
      if (gkb < K) { vb = *(const f16x8*)(Bbh + (long)gkb * ldb + gc);
                     wb = *(const f16x8*)(Bbl + (long)gkb * ldb + gc); }
#pragma unroll
      for (int j = 0; j < 8; ++j) {
        union { f16 f[2]; unsigned u; } ph, pl;
        ph.f[0] = va[j]; ph.f[1] = vb[j];
        pl.f[0] = wa[j]; pl.f[1] = wb[j];
        *(unsigned*)&Bh[c8 + j][k0p] = ph.u;
        *(unsigned*)&Bl[c8 + j][k0p] = pl.u;
      }
    }
    __syncthreads();

    f16x8 bh[4], bl[4];
#pragma unroll
    for (int ni = 0; ni < 4; ++ni) {
      bh[ni] = *(const f16x8*)&Bh[wc + ni * 16 + lr][lq * 8];
      bl[ni] = *(const f16x8*)&Bl[wc + ni * 16 + lr][lq * 8];
    }
#pragma unroll
    for (int mi = 0; mi < 4; ++mi) {
      f16x8 ah = *(const f16x8*)&Ah[wr + mi * 16 + lr][lq * 8];
      f16x8 al = *(const f16x8*)&Al[wr + mi * 16 + lr][lq * 8];
#pragma unroll
      for (int ni = 0; ni < 4; ++ni) {
        acc1[mi][ni] = __builtin_amdgcn_mfma_f32_16x16x32_f16(ah, bh[ni], acc1[mi][ni], 0, 0, 0);
        acc2[mi][ni] = __builtin_amdgcn_mfma_f32_16x16x32_f16(ah, bl[ni], acc2[mi][ni], 0, 0, 0);
        acc2[mi][ni] = __builtin_amdgcn_mfma_f32_16x16x32_f16(al, bh[ni], acc2[mi][ni], 0, 0, 0);
      }
    }
    __syncthreads();
  }

  // epilogue: col = lane&15, row = (lane>>4)*4 + reg
#pragma unroll
  for (int mi = 0; mi < 4; ++mi) {
#pragma unroll
    for (int ni = 0; ni < 4; ++ni) {
      int col = n0 + wc + ni * 16 + lr;
      if (col >= Ncol) continue;
      float bv = (flags & 1) ? bias[col] : 0.f;
#pragma unroll
      for (int r = 0; r < 4; ++r) {
        int row = i0 + wr + mi * 16 + lq * 4 + r;
        if (row >= M) continue;
        float vv = acc1[mi][ni][r] + acc2[mi][ni][r] * INV2048;
        if (flags & 4) vv *= rowscale[b * 256 + row];
        vv += bv;
        if (flags & 2) vv = fmaxf(vv, 0.f);
        long off = (long)b * bsY + (long)row * ldy + col;
        if (flags & 8) { f16 h, lo; split1(vv, h, lo); Yh[off] = h; Yl[off] = lo; }
        if (flags & 16) Yf[off] = vv;
      }
    }
  }
}

// pre-split weights: W [K][N] f32 -> [N][K] f16 planes
__global__ void presplit_kernel(const float* __restrict__ W, f16* __restrict__ Wh,
                                f16* __restrict__ Wl, int K, int N) {
  int n = blockIdx.x;
  for (int k = threadIdx.x; k < K; k += blockDim.x) {
    f16 h, l; split1(W[(long)k * N + n], h, l);
    Wh[(long)n * K + k] = h;
    Wl[(long)n * K + k] = l;
  }
}

// generic f32 [M][cols] -> planes (row-major)
__global__ void splitbuf_kernel(const float* __restrict__ X, f16* __restrict__ Xh,
                                f16* __restrict__ Xl, int cols) {
  int i = blockIdx.x;
  for (int c = threadIdx.x; c < cols; c += blockDim.x) {
    f16 h, l; split1(X[(long)i * cols + c], h, l);
    Xh[(long)i * cols + c] = h;
    Xl[(long)i * cols + c] = l;
  }
}

// ---------------- small kernels on planes ----------------
__global__ void build_a_deg_kernel(const float* __restrict__ adj, f16* __restrict__ AAh,
                                   f16* __restrict__ AAl, float* __restrict__ deg,
                                   float* __restrict__ dinv) {
  int b = blockIdx.y, i = blockIdx.x, j = threadIdx.x;
  __shared__ float red[256];
  float v = adj[(long)b * BS2 + i * 256 + j];
  if (i == j) v = fmaxf(v, 1.f);
  f16 h, l; split1(v, h, l);
  long o = (long)b * BS2 + i * 256 + j;
  AAh[o] = h; AAl[o] = l;
  red[j] = v; __syncthreads();
  for (int s = 128; s > 0; s >>= 1) { if (j < s) red[j] += red[j + s]; __syncthreads(); }
  if (j == 0) {
    float s = red[0];
    deg[b * 256 + i] = s;
    dinv[b * 256 + i] = (s > 0.f) ? (1.f / sqrtf(s)) : 0.f;
  }
}

__global__ void embed_kernel(const int* __restrict__ ids, const float* __restrict__ emb,
                             f16* __restrict__ Xh, f16* __restrict__ Xl) {
  int b = blockIdx.y, i = blockIdx.x, t = threadIdx.x;
  int id = ids[b * NMAX + i];
  float4 v = *(const float4*)(emb + (long)id * CH + t * 4);
  long o = (long)b * BSC + (long)i * LDC + t * 4;
  float vv[4] = {v.x, v.y, v.z, v.w};
#pragma unroll
  for (int j = 0; j < 4; ++j) { f16 h, l; split1(vv[j], h, l); Xh[o + j] = h; Xl[o + j] = l; }
}

// up to 3 row-dots on a [B,*,512] plane buffer
__global__ void rowdot_kernel(const f16* __restrict__ Xh, const f16* __restrict__ Xl,
                              const float* __restrict__ v1, const float* __restrict__ v2,
                              const float* __restrict__ v3,
                              float* __restrict__ o1, float* __restrict__ o2,
                              float* __restrict__ o3,
                              const float* __restrict__ cadd, int nvec) {
  int b = blockIdx.y, i = blockIdx.x, lane = threadIdx.x;
  long base = (long)b * BSC + (long)i * LDC;
  float a1 = 0.f, a2 = 0.f, a3 = 0.f;
  for (int c = lane; c < CH; c += 64) {
    float x = rc(Xh[base + c], Xl[base + c]);
    a1 = fmaf(x, v1[c], a1);
    if (nvec > 1) a2 = fmaf(x, v2[c], a2);
    if (nvec > 2) a3 = fmaf(x, v3[c], a3);
  }
  a1 = warp_sum_f(a1);
  if (nvec > 1) a2 = warp_sum_f(a2);
  if (nvec > 2) a3 = warp_sum_f(a3);
  if (lane == 0) {
    o1[b * 256 + i] = a1 + (cadd ? cadd[0] : 0.f);
    if (nvec > 1) o2[b * 256 + i] = a2;
    if (nvec > 2) o3[b * 256 + i] = a3;
  }
}

__global__ void vq_kernel(const float* __restrict__ qW, const float* __restrict__ qb,
                          const float* __restrict__ aw, float* __restrict__ v,
                          float* __restrict__ c0) {
  int blk = blockIdx.x, lane = threadIdx.x;
  if (blk < 512) {
    float s = 0.f;
    for (int j = lane; j < CH; j += 64) s = fmaf(qW[(long)blk * CH + j], aw[j], s);
    s = warp_sum_f(s);
    if (lane == 0) v[blk] = s;
  } else {
    float s = 0.f;
    for (int j = lane; j < CH; j += 64) s = fmaf(qb[j], aw[j], s);
    s = warp_sum_f(s);
    if (lane == 0) c0[0] = s;
  }
}

__global__ __launch_bounds__(256)
void softmax_kernel(const f16* __restrict__ AAh, const f16* __restrict__ AAl,
                    const float* __restrict__ si, const float* __restrict__ sj,
                    const float* __restrict__ attb,
                    f16* __restrict__ Ph, f16* __restrict__ Pl, int n) {
  int b = blockIdx.y, i = blockIdx.x, j = threadIdx.x;
  __shared__ float red[256];
  float logit = -1e30f, e = 0.f;
  float siv = si[b * 256 + i];
  long ro = (long)b * BS2 + i * 256;
  if (j < n) {
    float a = rc(AAh[ro + j], AAl[ro + j]);
    float z = siv + sj[b * 256 + j] + (attb ? attb[0] : 0.f);
    z = (z > 0.f) ? z : 0.2f * z;
    logit = (a > 0.f) ? z : -1e9f;
  }
  red[j] = logit; __syncthreads();
  for (int s = 128; s > 0; s >>= 1) { if (j < s) red[j] = fmaxf(red[j], red[j + s]); __syncthreads(); }
  float mx = red[0]; __syncthreads();
  if (j < n) e = expf(logit - mx);
  red[j] = e; __syncthreads();
  for (int s = 128; s > 0; s >>= 1) { if (j < s) red[j] += red[j + s]; __syncthreads(); }
  float sum = red[0];
  if (j < n) {
    f16 h, l; split1(e / sum, h, l);
    Ph[ro + j] = h; Pl[ro + j] = l;
  }
}

__global__ __launch_bounds__(256)
void colmax_kernel(const f16* __restrict__ XPh, const f16* __restrict__ XPl,
                   const float* __restrict__ v, const float* __restrict__ c0,
                   float* __restrict__ si_full, int n) {
  int b = blockIdx.x, t = threadIdx.x;
  long base = (long)b * BSC;
  float m1 = -1e9f, m2 = -1e9f;
  for (int j = 0; j < n; ++j) {
    m1 = fmaxf(m1, rc(XPh[base + (long)j * LDC + t], XPl[base + (long)j * LDC + t]));
    m2 = fmaxf(m2, rc(XPh[base + (long)j * LDC + t + 256], XPl[base + (long)j * LDC + t + 256]));
  }
  __shared__ float red[256];
  red[t] = m1 * v[t] + m2 * v[t + 256];
  __syncthreads();
  for (int s = 128; s > 0; s >>= 1) { if (t < s) red[t] += red[t + s]; __syncthreads(); }
  if (t == 0) si_full[b] = red[0] + c0[0];
}

__global__ __launch_bounds__(256)
void nbrdot_kernel(const f16* __restrict__ AAh, const f16* __restrict__ AAl,
                   const f16* __restrict__ XPh, const f16* __restrict__ XPl,
                   const float* __restrict__ v, const float* __restrict__ c0,
                   const float* __restrict__ si_full, float* __restrict__ si, int n) {
  int b = blockIdx.y, i = blockIdx.x, t = threadIdx.x;
  __shared__ int list[256];
  __shared__ int cnt, nmiss;
  __shared__ float red[256];
  if (t == 0) { cnt = 0; nmiss = 0; }
  __syncthreads();
  long ro = (long)b * BS2 + i * 256;
  if (t < n) {
    float a = rc(AAh[ro + t], AAl[ro + t]);
    if (a > 0.f) { int p = atomicAdd(&cnt, 1); list[p] = t; }
    else atomicAdd(&nmiss, 1);
  }
  __syncthreads();
  if (nmiss == 0) {
    if (t == 0) si[b * 256 + i] = si_full[b];
    return;
  }
  int c = cnt;
  long base = (long)b * BSC;
  float m1 = -1e9f, m2 = -1e9f;
  for (int q = 0; q < c; ++q) {
    int j = list[q];
    m1 = fmaxf(m1, rc(XPh[base + (long)j * LDC + t], XPl[base + (long)j * LDC + t]));
    m2 = fmaxf(m2, rc(XPh[base + (long)j * LDC + t + 256], XPl[base + (long)j * LDC + t + 256]));
  }
  red[t] = m1 * v[t] + m2 * v[t + 256];
  __syncthreads();
  for (int s = 128; s > 0; s >>= 1) { if (t < s) red[t] += red[t + s]; __syncthreads(); }
  if (t == 0) si[b * 256 + i] = red[0] + c0[0];
}

__global__ void fit_kernel(const f16* __restrict__ AAh, const f16* __restrict__ AAl,
                           const float* __restrict__ t1, const float* __restrict__ t2,
                           const float* __restrict__ t3,
                           const float* __restrict__ deg, const float* __restrict__ leb1,
                           float* __restrict__ fit, int n) {
  int b = blockIdx.y, i = blockIdx.x, lane = threadIdx.x;
  long ro = (long)b * BS2 + i * 256;
  float s = 0.f;
  for (int j = lane; j < n; j += 64) s = fmaf(rc(AAh[ro + j], AAl[ro + j]), t3[b * 256 + j], s);
  s = warp_sum_f(s);
  if (lane == 0) {
    float z = t1[b * 256 + i] + leb1[0] + t2[b * 256 + i] * deg[b * 256 + i] - s;
    fit[b * 256 + i] = 1.f / (1.f + expf(-z));
  }
}

__global__ __launch_bounds__(256)
void topk_kernel(const float* __restrict__ fit, int* __restrict__ perm,
                 float* __restrict__ vals, int n, int k) {
  __shared__ float v[256];
  __shared__ int ix[256];
  int b = blockIdx.x, t = threadIdx.x;
  v[t] = (t < n) ? fit[b * 256 + t] : -1e30f;
  ix[t] = t;
  __syncthreads();
  for (int size = 2; size <= 256; size <<= 1)
    for (int str = size >> 1; str > 0; str >>= 1) {
      int p = t ^ str;
      if (p > t) {
        bool desc = ((t & size) == 0);
        float v1 = v[t], v2 = v[p]; int i1 = ix[t], i2 = ix[p];
        bool inorder = (v1 > v2) || (v1 == v2 && i1 < i2);
        if (inorder != desc) { v[t] = v2; v[p] = v1; ix[t] = i2; ix[p] = i1; }
      }
      __syncthreads();
    }
  if (t < k) { perm[b * 256 + t] = ix[t]; vals[b * 256 + t] = v[t]; }
}

__global__ void gatherx_kernel(const f16* __restrict__ Hh, const f16* __restrict__ Hl,
                               const int* __restrict__ perm, const float* __restrict__ vals,
                               f16* __restrict__ Xh, f16* __restrict__ Xl) {
  int b = blockIdx.y, p = blockIdx.x, t = threadIdx.x;
  int src = perm[b * 256 + p];
  float sv = vals[b * 256 + p];
  long so = (long)b * BSC + (long)src * LDC + t * 4;
  long dof = (long)b * BSC + (long)p * LDC + t * 4;
#pragma unroll
  for (int j = 0; j < 4; ++j) {
    float x = rc(Hh[so + j], Hl[so + j]) * sv;
    f16 h, l; split1(x, h, l);
    Xh[dof + j] = h; Xl[dof + j] = l;
  }
}

__global__ void gathersk_kernel(const f16* __restrict__ Ph, const f16* __restrict__ Pl,
                                const int* __restrict__ perm,
                                f16* __restrict__ Skh, f16* __restrict__ Skl, int n) {
  int b = blockIdx.y, p = blockIdx.x, j = threadIdx.x;
  int src = perm[b * 256 + p];
  if (j < n) {
    long so = (long)b * BS2 + src * 256 + j;
    long dof = (long)b * BSC + p * 256 + j;  // Sk lives in XP buffer (ld 256)
    Skh[dof] = Ph[so]; Skl[dof] = Pl[so];
  }
}

// diag fix (+1 where diag<=0) then row-sum -> deg/dinv, on AA planes [k][k]
__global__ void degfix_kernel(f16* __restrict__ AAh, f16* __restrict__ AAl,
                              float* __restrict__ deg, float* __restrict__ dinv, int k) {
  int b = blockIdx.y, i = blockIdx.x, j = threadIdx.x;
  __shared__ float red[256];
  long ro = (long)b * BS2 + i * 256;
  float v = 0.f;
  if (j < k) {
    v = rc(AAh[ro + j], AAl[ro + j]);
    if (j == i && v <= 0.f) {
      v += 1.f;
      f16 h, l; split1(v, h, l);
      AAh[ro + j] = h; AAl[ro + j] = l;
    }
  }
  red[j] = v; __syncthreads();
  for (int s = 128; s > 0; s >>= 1) { if (j < s) red[j] += red[j + s]; __syncthreads(); }
  if (j == 0) {
    float s = red[0];
    deg[b * 256 + i] = s;
    dinv[b * 256 + i] = (s > 0.f) ? (1.f / sqrtf(s)) : 0.f;
  }
}

__global__ void readout_kernel(const f16* __restrict__ Xh, const f16* __restrict__ Xl,
                               float* __restrict__ xs, int k) {
  int b = blockIdx.x, t = threadIdx.x;
#pragma unroll
  for (int rep = 0; rep < 2; ++rep) {
    int c = t + rep * 256;
    float s = 0.f, m = -1e30f;
    for (int p = 0; p < k; ++p) {
      float v = rc(Xh[(long)b * BSC + (long)p * LDC + c], Xl[(long)b * BSC + (long)p * LDC + c]);
      s += v; m = fmaxf(m, v);
    }
    xs[b * 1024 + c] += s / (float)k;
    xs[b * 1024 + 512 + c] += m;
  }
}

// ---------------- host orchestration ----------------
extern "C" void kernel_launch(void* const* d_in, const int* in_sizes, int n_in,
                              void* d_out, int out_size, void* d_ws, size_t ws_size,
                              hipStream_t stream) {
  (void)in_sizes; (void)n_in; (void)out_size;
  const int*   x_ids  = (const int*)  d_in[0];
  const float* adj    = (const float*)d_in[2];
  const float* emb    = (const float*)d_in[3];
  const float* conv_W = (const float*)d_in[4];
  const float* conv_b = (const float*)d_in[5];
  const float* att_src= (const float*)d_in[6];
  const float* att_dst= (const float*)d_in[7];
  const float* q_W    = (const float*)d_in[8];
  const float* q_b    = (const float*)d_in[9];
  const float* att_w  = (const float*)d_in[10];
  const float* att_b  = (const float*)d_in[11];
  const float* gcn_W  = (const float*)d_in[12];
  const float* gcn_b  = (const float*)d_in[13];
  const float* le_W1  = (const float*)d_in[14];
  const float* le_b1  = (const float*)d_in[15];
  const float* le_W2  = (const float*)d_in[16];
  const float* le_W3  = (const float*)d_in[17];
  const float* lin1_W = (const float*)d_in[18];
  const float* lin1_b = (const float*)d_in[19];
  const float* lin2_W = (const float*)d_in[20];
  const float* lin2_b = (const float*)d_in[21];
  float* out = (float*)d_out;

  const size_t WN_CONV = 3u * CH * CH;
  const size_t WN_GCN  = 3u * CH * CH;
  const size_t WN_L1   = (size_t)(2 * CH) * CH;
  const size_t WN_L2   = (size_t)CH * 511;
  const size_t WTOT    = WN_CONV + WN_GCN + WN_L1 + WN_L2;

  // per-graph: 3 plane-pairs [256][512] (X,H,XP) + 2 plane-pairs [256][256] (P,AA) + smalls
  const size_t per_b  = (size_t)(3 * BSC * 4 + 2 * BS2 * 4 + 11 * 256 * 4 + 4096);
  const size_t fixedb = (size_t)(3 * 512 + 64 + NB * 1024 + NB * 512) * 4
                      + WTOT * 4 + (size_t)NB * 1024 * 4 + (size_t)NB * 512 * 4;
  const size_t slack  = 64 * 512;
  int bc = 4;
  for (int cand = 256; cand >= 4; cand >>= 1) {
    if ((size_t)cand * per_b + fixedb + slack <= ws_size) { bc = cand; break; }
  }
  const int nchunks = NB / bc;

  char* w = (char*)d_ws;
  auto alloc = [&](size_t bytes) { char* p = w; w += (bytes + 255) & ~(size_t)255; return p; };
  // fixed
  float* xs   = (float*)alloc(sizeof(float) * NB * 1024);
  float* FHd  = (float*)alloc(sizeof(float) * 4);  // unused f32 (placeholder)
  float* vvec = (float*)alloc(sizeof(float) * 3 * CH);
  float* c0   = (float*)alloc(256);
  f16*   Wh   = (f16*)alloc(WTOT * 2);
  f16*   Wl   = (f16*)alloc(WTOT * 2);
  f16*   XSh  = (f16*)alloc((size_t)NB * 1024 * 2);
  f16*   XSl  = (f16*)alloc((size_t)NB * 1024 * 2);
  f16*   FHh  = (f16*)alloc((size_t)NB * 512 * 2);
  f16*   FHl  = (f16*)alloc((size_t)NB * 512 * 2);
  // chunk-local plane pairs
  f16* Xh  = (f16*)alloc((size_t)bc * BSC * 2);
  f16* Xl  = (f16*)alloc((size_t)bc * BSC * 2);
  f16* Hh  = (f16*)alloc((size_t)bc * BSC * 2);
  f16* Hl  = (f16*)alloc((size_t)bc * BSC * 2);
  f16* XPh = (f16*)alloc((size_t)bc * BSC * 2);
  f16* XPl = (f16*)alloc((size_t)bc * BSC * 2);
  f16* Ph  = (f16*)alloc((size_t)bc * BS2 * 2);
  f16* Pl  = (f16*)alloc((size_t)bc * BS2 * 2);
  f16* AAh = (f16*)alloc((size_t)bc * BS2 * 2);
  f16* AAl = (f16*)alloc((size_t)bc * BS2 * 2);
  float* si   = (float*)alloc(sizeof(float) * bc * NMAX);
  float* sj   = (float*)alloc(sizeof(float) * bc * NMAX);
  float* deg  = (float*)alloc(sizeof(float) * bc * NMAX);
  float* dinv = (float*)alloc(sizeof(float) * bc * NMAX);
  float* t1   = (float*)alloc(sizeof(float) * bc * NMAX);
  float* t2   = (float*)alloc(sizeof(float) * bc * NMAX);
  float* t3   = (float*)alloc(sizeof(float) * bc * NMAX);
  float* fit  = (float*)alloc(sizeof(float) * bc * NMAX);
  float* vals = (float*)alloc(sizeof(float) * bc * NMAX);
  int*   perm = (int*)  alloc(sizeof(int)   * bc * NMAX);
  float* sifu = (float*)alloc(sizeof(float) * bc);
  (void)FHd;

  f16* cwh = Wh;                       f16* cwl = Wl;
  f16* gwh = Wh + WN_CONV;             f16* gwl = Wl + WN_CONV;
  f16* l1h = Wh + WN_CONV + WN_GCN;    f16* l1l = Wl + WN_CONV + WN_GCN;
  f16* l2h = l1h + WN_L1;              f16* l2l = l1l + WN_L1;

  hipMemsetAsync(xs, 0, sizeof(float) * NB * 1024, stream);

  for (int l = 0; l < 3; ++l) {
    presplit_kernel<<<512, 256, 0, stream>>>(conv_W + (size_t)l * CH * CH,
                                             cwh + (size_t)l * CH * CH,
                                             cwl + (size_t)l * CH * CH, CH, CH);
    presplit_kernel<<<512, 256, 0, stream>>>(gcn_W + (size_t)l * CH * CH,
                                             gwh + (size_t)l * CH * CH,
                                             gwl + (size_t)l * CH * CH, CH, CH);
    vq_kernel<<<513, 64, 0, stream>>>(q_W + (size_t)l * CH * CH, q_b + l * CH,
                                      att_w + (size_t)l * 2 * CH, vvec + l * CH, c0 + l);
  }
  presplit_kernel<<<512, 256, 0, stream>>>(lin1_W, l1h, l1l, 2 * CH, CH);
  presplit_kernel<<<511, 256, 0, stream>>>(lin2_W, l2h, l2l, CH, 511);

  const int ks[3] = {205, 164, 132};

  for (int ch = 0; ch < nchunks; ++ch) {
    const int b0 = ch * bc;
    const int*   ids_c = x_ids + (size_t)b0 * NMAX;
    const float* adj_c = adj + (size_t)b0 * BS2;
    float*       xs_c  = xs + (size_t)b0 * 1024;

    build_a_deg_kernel<<<dim3(NMAX, bc), 256, 0, stream>>>(adj_c, AAh, AAl, deg, dinv);
    embed_kernel<<<dim3(NMAX, bc), 128, 0, stream>>>(ids_c, emb, Xh, Xl);

    int n = NMAX;
    for (int l = 0; l < 3; ++l) {
      int kk = ks[l];
      int mt = (n + 127) / 128;
      int nt2 = (n + 127) / 128;
      const float* aw = att_w + (size_t)l * 2 * CH;

      // ---- GAT ----
      pgemm_kernel<0><<<dim3(4, mt, bc), 256, 0, stream>>>(
          Xh, Xl, BSC, LDC, cwh + (size_t)l * CH * CH, cwl + (size_t)l * CH * CH, 0, CH,
          Hh, Hl, nullptr, BSC, LDC, nullptr, nullptr, n, CH, CH, 8);
      rowdot_kernel<<<dim3(n, bc), 64, 0, stream>>>(
          Hh, Hl, att_dst + l * CH, att_src + l * CH, nullptr, si, sj, nullptr, nullptr, 2);
      softmax_kernel<<<dim3(n, bc), 256, 0, stream>>>(AAh, AAl, si, sj, nullptr, Ph, Pl, n);
      pgemm_kernel<1><<<dim3(4, mt, bc), 256, 0, stream>>>(
          Ph, Pl, BS2, LD2, Hh, Hl, BSC, LDC,
          Xh, Xl, nullptr, BSC, LDC, conv_b + l * CH, nullptr, n, CH, n, 1 | 2 | 8);

      // ---- ASAP pool ----
      pgemm_kernel<0><<<dim3(4, mt, bc), 256, 0, stream>>>(
          Xh, Xl, BSC, LDC, gwh + (size_t)l * CH * CH, gwl + (size_t)l * CH * CH, 0, CH,
          Hh, Hl, nullptr, BSC, LDC, nullptr, dinv, n, CH, CH, 4 | 8);
      pgemm_kernel<1><<<dim3(4, mt, bc), 256, 0, stream>>>(
          AAh, AAl, BS2, LD2, Hh, Hl, BSC, LDC,
          XPh, XPl, nullptr, BSC, LDC, gcn_b + l * CH, dinv, n, CH, n, 1 | 4 | 8);
      rowdot_kernel<<<dim3(n, bc), 64, 0, stream>>>(
          XPh, XPl, aw + CH, nullptr, nullptr, sj, nullptr, nullptr, nullptr, 1);
      colmax_kernel<<<bc, 256, 0, stream>>>(XPh, XPl, vvec + l * CH, c0 + l, sifu, n);
      nbrdot_kernel<<<dim3(n, bc), 256, 0, stream>>>(AAh, AAl, XPh, XPl,
                                                     vvec + l * CH, c0 + l, sifu, si, n);
      softmax_kernel<<<dim3(n, bc), 256, 0, stream>>>(AAh, AAl, si, sj, att_b + l, Ph, Pl, n);
      pgemm_kernel<1><<<dim3(4, mt, bc), 256, 0, stream>>>(
          Ph, Pl, BS2, LD2, Xh, Xl, BSC, LDC,
          Hh, Hl, nullptr, BSC, LDC, nullptr, nullptr, n, CH, n, 8);  // xc
      rowdot_kernel<<<dim3(n, bc), 64, 0, stream>>>(
          Hh, Hl, le_W1 + l * CH, le_W2 + l * CH, le_W3 + l * CH, t1, t2, t3, nullptr, 3);
      fit_kernel<<<dim3(n, bc), 64, 0, stream>>>(AAh, AAl, t1, t2, t3, deg, le_b1 + l, fit, n);
      topk_kernel<<<bc, 256, 0, stream>>>(fit, perm, vals, n, kk);
      gatherx_kernel<<<dim3(kk, bc), 128, 0, stream>>>(Hh, Hl, perm, vals, Xh, Xl);
      gathersk_kernel<<<dim3(kk, bc), 256, 0, stream>>>(Ph, Pl, perm, XPh, XPl, n);
      int mtk = (kk + 127) / 128;
      // SA = Sk @ A (A symmetric -> B as [N][K] rows of AA)
      pgemm_kernel<0><<<dim3(nt2, mtk, bc), 256, 0, stream>>>(
          XPh, XPl, BSC, LD2, AAh, AAl, BS2, LD2,
          Ph, Pl, nullptr, BS2, LD2, nullptr, nullptr, kk, n, n, 8);
      // A_new = SA @ Sk^T
      pgemm_kernel<0><<<dim3(mtk, mtk, bc), 256, 0, stream>>>(
          Ph, Pl, BS2, LD2, XPh, XPl, BSC, LD2,
          AAh, AAl, nullptr, BS2, LD2, nullptr, nullptr, kk, kk, n, 8);
      degfix_kernel<<<dim3(kk, bc), 256, 0, stream>>>(AAh, AAl, deg, dinv, kk);
      readout_kernel<<<bc, 256, 0, stream>>>(Xh, Xl, xs_c, kk);
      n = kk;
    }
  }

  // ---- final MLP (full batch) ----
  splitbuf_kernel<<<NB, 256, 0, stream>>>(xs, XSh, XSl, 1024);
  pgemm_kernel<0><<<dim3(4, 2, 1), 256, 0, stream>>>(
      XSh, XSl, 0, 1024, l1h, l1l, 0, 1024,
      FHh, FHl, nullptr, 0, CH, lin1_b, nullptr, NB, CH, 2 * CH, 1 | 2 | 8);
  pgemm_kernel<0><<<dim3(4, 2, 1), 256, 0, stream>>>(
      FHh, FHl, 0, CH, l2h, l2l, 0, CH,
      nullptr, nullptr, out, 0, 511, lin2_b, nullptr, NB, 511, CH, 1 | 16);
}

// Round 5
// 5511.438 us; speedup vs baseline: 1.7706x; 1.3957x over previous
//
#include <hip/hip_runtime.h>
#include <math.h>

#define NB   256
#define NMAX 256
#define CH   512
#define LD2  256
#define LDC  512
#define BS2  (256*256)
#define BSC  (256*512)

typedef _Float16 f16;
typedef __attribute__((ext_vector_type(4))) f16 f16x4;
typedef __attribute__((ext_vector_type(8))) f16 f16x8;
typedef __attribute__((ext_vector_type(4))) float f32x4;

#define INV2048 4.8828125e-04f

__device__ __forceinline__ float warp_sum_f(float v) {
#pragma unroll
  for (int m = 32; m >= 1; m >>= 1) v += __shfl_xor(v, m);
  return v;
}

__device__ __forceinline__ void split1(float x, f16& h, f16& l) {
  float xh = (__builtin_fabsf(x) >= 6.103515625e-05f) ? x : 0.f;
  f16 hh = (f16)xh;
  float hf = (float)hh;
  h = hh;
  l = (f16)((x - hf) * 2048.0f);
}

__device__ __forceinline__ float rc(f16 h, f16 l) {
  return (float)h + (float)l * INV2048;
}

// ---------------- plane GEMM with register prefetch ----------------
// A: [M][K] planes. B: BMODE 0 -> [N][K] planes; BMODE 1 -> [K][N] planes.
// flags: 1 bias, 2 relu, 4 rowscale, 8 write planes, 16 write f32
template <int BMODE>
__global__ __launch_bounds__(256, 2)
void pgemm_kernel(const f16* __restrict__ Ahp, const f16* __restrict__ Alp, long bsA, int lda,
                  const f16* __restrict__ Bhp, const f16* __restrict__ Blp, long bsB, int ldb,
                  f16* __restrict__ Yh, f16* __restrict__ Yl, float* __restrict__ Yf,
                  long bsY, int ldy,
                  const float* __restrict__ bias, const float* __restrict__ rowscale,
                  int M, int Ncol, int K, int flags)
{
  __shared__ f16 Ah[128][40];
  __shared__ f16 Al[128][40];
  __shared__ f16 Bh[128][40];
  __shared__ f16 Bl[128][40];
  const int b   = blockIdx.z;
  const int i0  = blockIdx.y * 128;
  const int n0  = blockIdx.x * 128;
  const int tid = threadIdx.x;
  const int w  = tid >> 6, l = tid & 63;
  const int wr = (w >> 1) * 64, wc = (w & 1) * 64;
  const int lr = l & 15, lq = l >> 4;
  const f16* Abh = Ahp + (long)b * bsA;
  const f16* Abl = Alp + (long)b * bsA;
  const f16* Bbh = Bhp + (long)b * bsB;
  const f16* Bbl = Blp + (long)b * bsB;

  f32x4 acc1[4][4], acc2[4][4];
#pragma unroll
  for (int mi = 0; mi < 4; ++mi)
#pragma unroll
    for (int ni = 0; ni < 4; ++ni) {
      acc1[mi][ni] = (f32x4){0.f, 0.f, 0.f, 0.f};
      acc2[mi][ni] = (f32x4){0.f, 0.f, 0.f, 0.f};
    }

  // prefetch registers
  f16x4 rah[4], ral[4];
  f16x4 rbh[4], rbl[4];        // BMODE 0
  f16x8 rva, rvb, rwa, rwb;    // BMODE 1

  auto LOADA = [&](int k0) {
#pragma unroll
    for (int rep = 0; rep < 4; ++rep) {
      int row = rep * 32 + (tid >> 3);
      int kq  = (tid & 7) * 4;
      int gr = i0 + row, gk = k0 + kq;
      f16x4 h = (f16x4){0, 0, 0, 0}, lo = (f16x4){0, 0, 0, 0};
      if (gr < M) {
        if (gk + 3 < K) {
          h  = *(const f16x4*)(Abh + (long)gr * lda + gk);
          lo = *(const f16x4*)(Abl + (long)gr * lda + gk);
        } else {
#pragma unroll
          for (int j = 0; j < 4; ++j) if (gk + j < K) {
            h[j]  = Abh[(long)gr * lda + gk + j];
            lo[j] = Abl[(long)gr * lda + gk + j];
          }
        }
      }
      rah[rep] = h; ral[rep] = lo;
    }
  };
  auto STOREA = [&]() {
#pragma unroll
    for (int rep = 0; rep < 4; ++rep) {
      int row = rep * 32 + (tid >> 3);
      int kq  = (tid & 7) * 4;
      *(f16x4*)&Ah[row][kq] = rah[rep];
      *(f16x4*)&Al[row][kq] = ral[rep];
    }
  };
  auto LOADB = [&](int k0) {
    if (BMODE == 0) {
#pragma unroll
      for (int rep = 0; rep < 4; ++rep) {
        int c  = rep * 32 + (tid >> 3);
        int kq = (tid & 7) * 4;
        int gc = n0 + c, gk = k0 + kq;
        f16x4 h = (f16x4){0, 0, 0, 0}, lo = (f16x4){0, 0, 0, 0};
        if (gc < Ncol) {
          if (gk + 3 < K) {
            h  = *(const f16x4*)(Bbh + (long)gc * ldb + gk);
            lo = *(const f16x4*)(Bbl + (long)gc * ldb + gk);
          } else {
#pragma unroll
            for (int j = 0; j < 4; ++j) if (gk + j < K) {
              h[j]  = Bbh[(long)gc * ldb + gk + j];
              lo[j] = Bbl[(long)gc * ldb + gk + j];
            }
          }
        }
        rbh[rep] = h; rbl[rep] = lo;
      }
    } else {
      int c8  = (tid & 15) * 8;
      int k0p = (tid >> 4) * 2;
      int gc = n0 + c8;
      f16x8 z = (f16x8){0,0,0,0,0,0,0,0};
      rva = z; rvb = z; rwa = z; rwb = z;
      int gka = k0 + k0p, gkb = gka + 1;
      if (gka < K) { rva = *(const f16x8*)(Bbh + (long)gka * ldb + gc);
                     rwa = *(const f16x8*)(Bbl + (long)gka * ldb + gc); }
      if (gkb < K) { rvb = *(const f16x8*)(Bbh + (long)gkb * ldb + gc);
                     rwb = *(const f16x8*)(Bbl + (long)gkb * ldb + gc); }
    }
  };
  auto STOREB = [&]() {
    if (BMODE == 0) {
#pragma unroll
      for (int rep = 0; rep < 4; ++rep) {
        int c  = rep * 32 + (tid >> 3);
        int kq = (tid & 7) * 4;
        *(f16x4*)&Bh[c][kq] = rbh[rep];
        *(f16x4*)&Bl[c][kq] = rbl[rep];
      }
    } else {
      int c8  = (tid & 15) * 8;
      int k0p = (tid >> 4) * 2;
#pragma unroll
      for (int j = 0; j < 8; ++j) {
        union { f16 f[2]; unsigned u; } ph, pl;
        ph.f[0] = rva[j]; ph.f[1] = rvb[j];
        pl.f[0] = rwa[j]; pl.f[1] = rwb[j];
        *(unsigned*)&Bh[c8 + j][k0p] = ph.u;
        *(unsigned*)&Bl[c8 + j][k0p] = pl.u;
      }
    }
  };

  const int nk = (K + 31) / 32;
  LOADA(0); LOADB(0);
  for (int ki = 0; ki < nk; ++ki) {
    STOREA(); STOREB();
    __syncthreads();
    if (ki + 1 < nk) { LOADA((ki + 1) * 32); LOADB((ki + 1) * 32); }

    f16x8 bh[4], bl[4];
#pragma unroll
    for (int ni = 0; ni < 4; ++ni) {
      bh[ni] = *(const f16x8*)&Bh[wc + ni * 16 + lr][lq * 8];
      bl[ni] = *(const f16x8*)&Bl[wc + ni * 16 + lr][lq * 8];
    }
#pragma unroll
    for (int mi = 0; mi < 4; ++mi) {
      f16x8 ah = *(const f16x8*)&Ah[wr + mi * 16 + lr][lq * 8];
      f16x8 al = *(const f16x8*)&Al[wr + mi * 16 + lr][lq * 8];
#pragma unroll
      for (int ni = 0; ni < 4; ++ni) {
        acc1[mi][ni] = __builtin_amdgcn_mfma_f32_16x16x32_f16(ah, bh[ni], acc1[mi][ni], 0, 0, 0);
        acc2[mi][ni] = __builtin_amdgcn_mfma_f32_16x16x32_f16(ah, bl[ni], acc2[mi][ni], 0, 0, 0);
        acc2[mi][ni] = __builtin_amdgcn_mfma_f32_16x16x32_f16(al, bh[ni], acc2[mi][ni], 0, 0, 0);
      }
    }
    __syncthreads();
  }

  // epilogue: col = lane&15, row = (lane>>4)*4 + reg
#pragma unroll
  for (int mi = 0; mi < 4; ++mi) {
#pragma unroll
    for (int ni = 0; ni < 4; ++ni) {
      int col = n0 + wc + ni * 16 + lr;
      if (col >= Ncol) continue;
      float bv = (flags & 1) ? bias[col] : 0.f;
#pragma unroll
      for (int r = 0; r < 4; ++r) {
        int row = i0 + wr + mi * 16 + lq * 4 + r;
        if (row >= M) continue;
        float vv = acc1[mi][ni][r] + acc2[mi][ni][r] * INV2048;
        if (flags & 4) vv *= rowscale[b * 256 + row];
        vv += bv;
        if (flags & 2) vv = fmaxf(vv, 0.f);
        long off = (long)b * bsY + (long)row * ldy + col;
        if (flags & 8) { f16 h, lo; split1(vv, h, lo); Yh[off] = h; Yl[off] = lo; }
        if (flags & 16) Yf[off] = vv;
      }
    }
  }
}

// pre-split weights: W [K][N] f32 -> [N][K] f16 planes
__global__ void presplit_kernel(const float* __restrict__ W, f16* __restrict__ Wh,
                                f16* __restrict__ Wl, int K, int N) {
  int n = blockIdx.x;
  for (int k = threadIdx.x; k < K; k += blockDim.x) {
    f16 h, l; split1(W[(long)k * N + n], h, l);
    Wh[(long)n * K + k] = h;
    Wl[(long)n * K + k] = l;
  }
}

__global__ void splitbuf_kernel(const float* __restrict__ X, f16* __restrict__ Xh,
                                f16* __restrict__ Xl, int cols) {
  int i = blockIdx.x;
  for (int c = threadIdx.x; c < cols; c += blockDim.x) {
    f16 h, l; split1(X[(long)i * cols + c], h, l);
    Xh[(long)i * cols + c] = h;
    Xl[(long)i * cols + c] = l;
  }
}

// ---------------- layer-1 small kernels ----------------
__global__ void build_a_deg_kernel(const float* __restrict__ adj, f16* __restrict__ AAh,
                                   f16* __restrict__ AAl, float* __restrict__ deg,
                                   float* __restrict__ dinv) {
  int b = blockIdx.y, i = blockIdx.x, j = threadIdx.x;
  __shared__ float red[256];
  float v = adj[(long)b * BS2 + i * 256 + j];
  if (i == j) v = fmaxf(v, 1.f);
  f16 h, l; split1(v, h, l);
  long o = (long)b * BS2 + i * 256 + j;
  AAh[o] = h; AAl[o] = l;
  red[j] = v; __syncthreads();
  for (int s = 128; s > 0; s >>= 1) { if (j < s) red[j] += red[j + s]; __syncthreads(); }
  if (j == 0) {
    float s = red[0];
    deg[b * 256 + i] = s;
    dinv[b * 256 + i] = (s > 0.f) ? (1.f / sqrtf(s)) : 0.f;
  }
}

__global__ void embed_kernel(const int* __restrict__ ids, const float* __restrict__ emb,
                             f16* __restrict__ Xh, f16* __restrict__ Xl) {
  int b = blockIdx.y, i = blockIdx.x, t = threadIdx.x;
  int id = ids[b * NMAX + i];
  float4 v = *(const float4*)(emb + (long)id * CH + t * 4);
  long o = (long)b * BSC + (long)i * LDC + t * 4;
  float vv[4] = {v.x, v.y, v.z, v.w};
#pragma unroll
  for (int j = 0; j < 4; ++j) { f16 h, l; split1(vv[j], h, l); Xh[o + j] = h; Xl[o + j] = l; }
}

__global__ void rowdot_kernel(const f16* __restrict__ Xh, const f16* __restrict__ Xl,
                              const float* __restrict__ v1, const float* __restrict__ v2,
                              const float* __restrict__ v3,
                              float* __restrict__ o1, float* __restrict__ o2,
                              float* __restrict__ o3, int nvec) {
  int b = blockIdx.y, i = blockIdx.x, lane = threadIdx.x;
  long base = (long)b * BSC + (long)i * LDC;
  float a1 = 0.f, a2 = 0.f, a3 = 0.f;
  for (int c = lane; c < CH; c += 64) {
    float x = rc(Xh[base + c], Xl[base + c]);
    a1 = fmaf(x, v1[c], a1);
    if (nvec > 1) a2 = fmaf(x, v2[c], a2);
    if (nvec > 2) a3 = fmaf(x, v3[c], a3);
  }
  a1 = warp_sum_f(a1);
  if (nvec > 1) a2 = warp_sum_f(a2);
  if (nvec > 2) a3 = warp_sum_f(a3);
  if (lane == 0) {
    o1[b * 256 + i] = a1;
    if (nvec > 1) o2[b * 256 + i] = a2;
    if (nvec > 2) o3[b * 256 + i] = a3;
  }
}

__global__ void vq_kernel(const float* __restrict__ qW, const float* __restrict__ qb,
                          const float* __restrict__ aw, float* __restrict__ v,
                          float* __restrict__ c0) {
  int blk = blockIdx.x, lane = threadIdx.x;
  if (blk < 512) {
    float s = 0.f;
    for (int j = lane; j < CH; j += 64) s = fmaf(qW[(long)blk * CH + j], aw[j], s);
    s = warp_sum_f(s);
    if (lane == 0) v[blk] = s;
  } else {
    float s = 0.f;
    for (int j = lane; j < CH; j += 64) s = fmaf(qb[j], aw[j], s);
    s = warp_sum_f(s);
    if (lane == 0) c0[0] = s;
  }
}

// masked==1: logit valid only where A>0; masked==0: dense
__global__ __launch_bounds__(256)
void softmax_kernel(const f16* __restrict__ AAh, const f16* __restrict__ AAl,
                    const float* __restrict__ si, const float* __restrict__ sj,
                    const float* __restrict__ attb,
                    f16* __restrict__ Ph, f16* __restrict__ Pl, int n, int masked) {
  int b = blockIdx.y, i = blockIdx.x, j = threadIdx.x;
  __shared__ float red[256];
  float logit = -1e30f, e = 0.f;
  float siv = si[b * 256 + i];
  long ro = (long)b * BS2 + i * 256;
  if (j < n) {
    float z = siv + sj[b * 256 + j] + (attb ? attb[0] : 0.f);
    z = (z > 0.f) ? z : 0.2f * z;
    if (masked) {
      float a = rc(AAh[ro + j], AAl[ro + j]);
      logit = (a > 0.f) ? z : -1e9f;
    } else logit = z;
  }
  red[j] = logit; __syncthreads();
  for (int s = 128; s > 0; s >>= 1) { if (j < s) red[j] = fmaxf(red[j], red[j + s]); __syncthreads(); }
  float mx = red[0]; __syncthreads();
  if (j < n) e = expf(logit - mx);
  red[j] = e; __syncthreads();
  for (int s = 128; s > 0; s >>= 1) { if (j < s) red[j] += red[j + s]; __syncthreads(); }
  float sum = red[0];
  if (j < n) {
    f16 h, l; split1(e / sum, h, l);
    Ph[ro + j] = h; Pl[ro + j] = l;
  }
}

__global__ __launch_bounds__(256)
void colmax_kernel(const f16* __restrict__ XPh, const f16* __restrict__ XPl,
                   const float* __restrict__ v, const float* __restrict__ c0,
                   float* __restrict__ si_full, int n) {
  int b = blockIdx.x, t = threadIdx.x;
  long base = (long)b * BSC;
  float m1 = -1e9f, m2 = -1e9f;
  for (int j = 0; j < n; ++j) {
    m1 = fmaxf(m1, rc(XPh[base + (long)j * LDC + t], XPl[base + (long)j * LDC + t]));
    m2 = fmaxf(m2, rc(XPh[base + (long)j * LDC + t + 256], XPl[base + (long)j * LDC + t + 256]));
  }
  __shared__ float red[256];
  red[t] = m1 * v[t] + m2 * v[t + 256];
  __syncthreads();
  for (int s = 128; s > 0; s >>= 1) { if (t < s) red[t] += red[t + s]; __syncthreads(); }
  if (t == 0) si_full[b] = red[0] + c0[0];
}

__global__ __launch_bounds__(256)
void nbrdot_kernel(const f16* __restrict__ AAh, const f16* __restrict__ AAl,
                   const f16* __restrict__ XPh, const f16* __restrict__ XPl,
                   const float* __restrict__ v, const float* __restrict__ c0,
                   const float* __restrict__ si_full, float* __restrict__ si, int n) {
  int b = blockIdx.y, i = blockIdx.x, t = threadIdx.x;
  __shared__ int list[256];
  __shared__ int cnt, nmiss;
  __shared__ float red[256];
  if (t == 0) { cnt = 0; nmiss = 0; }
  __syncthreads();
  long ro = (long)b * BS2 + i * 256;
  if (t < n) {
    float a = rc(AAh[ro + t], AAl[ro + t]);
    if (a > 0.f) { int p = atomicAdd(&cnt, 1); list[p] = t; }
    else atomicAdd(&nmiss, 1);
  }
  __syncthreads();
  if (nmiss == 0) {
    if (t == 0) si[b * 256 + i] = si_full[b];
    return;
  }
  int c = cnt;
  long base = (long)b * BSC;
  float m1 = -1e9f, m2 = -1e9f;
  for (int q = 0; q < c; ++q) {
    int j = list[q];
    m1 = fmaxf(m1, rc(XPh[base + (long)j * LDC + t], XPl[base + (long)j * LDC + t]));
    m2 = fmaxf(m2, rc(XPh[base + (long)j * LDC + t + 256], XPl[base + (long)j * LDC + t + 256]));
  }
  red[t] = m1 * v[t] + m2 * v[t + 256];
  __syncthreads();
  for (int s = 128; s > 0; s >>= 1) { if (t < s) red[t] += red[t + s]; __syncthreads(); }
  if (t == 0) si[b * 256 + i] = red[0] + c0[0];
}

__global__ void fit_kernel(const f16* __restrict__ AAh, const f16* __restrict__ AAl,
                           const float* __restrict__ t1, const float* __restrict__ t2,
                           const float* __restrict__ t3,
                           const float* __restrict__ deg, const float* __restrict__ leb1,
                           float* __restrict__ fit, int n) {
  int b = blockIdx.y, i = blockIdx.x, lane = threadIdx.x;
  long ro = (long)b * BS2 + i * 256;
  float s = 0.f;
  for (int j = lane; j < n; j += 64) s = fmaf(rc(AAh[ro + j], AAl[ro + j]), t3[b * 256 + j], s);
  s = warp_sum_f(s);
  if (lane == 0) {
    float z = t1[b * 256 + i] + leb1[0] + t2[b * 256 + i] * deg[b * 256 + i] - s;
    fit[b * 256 + i] = 1.f / (1.f + expf(-z));
  }
}

__global__ __launch_bounds__(256)
void topk_kernel(const float* __restrict__ fit, int* __restrict__ perm,
                 float* __restrict__ vals, int n, int k) {
  __shared__ float v[256];
  __shared__ int ix[256];
  int b = blockIdx.x, t = threadIdx.x;
  v[t] = (t < n) ? fit[b * 256 + t] : -1e30f;
  ix[t] = t;
  __syncthreads();
  for (int size = 2; size <= 256; size <<= 1)
    for (int str = size >> 1; str > 0; str >>= 1) {
      int p = t ^ str;
      if (p > t) {
        bool desc = ((t & size) == 0);
        float v1 = v[t], v2 = v[p]; int i1 = ix[t], i2 = ix[p];
        bool inorder = (v1 > v2) || (v1 == v2 && i1 < i2);
        if (inorder != desc) { v[t] = v2; v[p] = v1; ix[t] = i2; ix[p] = i1; }
      }
      __syncthreads();
    }
  if (t < k) { perm[b * 256 + t] = ix[t]; vals[b * 256 + t] = v[t]; }
}

// merged gatherx + gathersk (layer 1)
__global__ __launch_bounds__(256)
void gather_kernel(const f16* __restrict__ Hh, const f16* __restrict__ Hl,
                   const f16* __restrict__ Ph, const f16* __restrict__ Pl,
                   const int* __restrict__ perm, const float* __restrict__ vals,
                   f16* __restrict__ Xh, f16* __restrict__ Xl,
                   f16* __restrict__ Skh, f16* __restrict__ Skl, int n) {
  int b = blockIdx.y, p = blockIdx.x, t = threadIdx.x;
  int src = perm[b * 256 + p];
  float sv = vals[b * 256 + p];
#pragma unroll
  for (int r = 0; r < 2; ++r) {
    int c = t + r * 256;
    long so = (long)b * BSC + (long)src * LDC + c;
    long dof = (long)b * BSC + (long)p * LDC + c;
    float x = rc(Hh[so], Hl[so]) * sv;
    f16 h, l; split1(x, h, l);
    Xh[dof] = h; Xl[dof] = l;
  }
  if (t < n) {
    long so = (long)b * BS2 + src * 256 + t;
    long dof = (long)b * BSC + p * 256 + t;
    Skh[dof] = Ph[so]; Skl[dof] = Pl[so];
  }
}

__global__ void degfix_kernel(f16* __restrict__ AAh, f16* __restrict__ AAl,
                              float* __restrict__ deg, float* __restrict__ dinv, int k) {
  int b = blockIdx.y, i = blockIdx.x, j = threadIdx.x;
  __shared__ float red[256];
  long ro = (long)b * BS2 + i * 256;
  float v = 0.f;
  if (j < k) {
    v = rc(AAh[ro + j], AAl[ro + j]);
    if (j == i && v <= 0.f) {
      v += 1.f;
      f16 h, l; split1(v, h, l);
      AAh[ro + j] = h; AAl[ro + j] = l;
    }
  }
  red[j] = v; __syncthreads();
  for (int s = 128; s > 0; s >>= 1) { if (j < s) red[j] += red[j + s]; __syncthreads(); }
  if (j == 0) {
    float s = red[0];
    deg[b * 256 + i] = s;
    dinv[b * 256 + i] = (s > 0.f) ? (1.f / sqrtf(s)) : 0.f;
  }
}

__global__ void readout_kernel(const f16* __restrict__ Xh, const f16* __restrict__ Xl,
                               float* __restrict__ xs, int k) {
  int b = blockIdx.x, t = threadIdx.x;
#pragma unroll
  for (int rep = 0; rep < 2; ++rep) {
    int c = t + rep * 256;
    float s = 0.f, m = -1e30f;
    for (int p = 0; p < k; ++p) {
      float v = rc(Xh[(long)b * BSC + (long)p * LDC + c], Xl[(long)b * BSC + (long)p * LDC + c]);
      s += v; m = fmaxf(m, v);
    }
    xs[b * 1024 + c] += s / (float)k;
    xs[b * 1024 + 512 + c] += m;
  }
}

// ---------------- collapsed-pool kernels (layers 2/3) ----------------
// p[j] = softmax_j(leaky(siF + sj[j] + ab))
__global__ __launch_bounds__(256)
void prow_kernel(const float* __restrict__ sj, const float* __restrict__ sifu,
                 const float* __restrict__ attb, float* __restrict__ pv, int n) {
  int b = blockIdx.x, j = threadIdx.x;
  __shared__ float red[256];
  float z = -1e30f, e = 0.f;
  float siv = sifu[b];
  if (j < n) {
    float zz = siv + sj[b * 256 + j] + attb[0];
    z = (zz > 0.f) ? zz : 0.2f * zz;
  }
  red[j] = z; __syncthreads();
  for (int s = 128; s > 0; s >>= 1) { if (j < s) red[j] = fmaxf(red[j], red[j + s]); __syncthreads(); }
  float mx = red[0]; __syncthreads();
  if (j < n) e = expf(z - mx);
  red[j] = e; __syncthreads();
  for (int s = 128; s > 0; s >>= 1) { if (j < s) red[j] += red[j + s]; __syncthreads(); }
  if (j < n) pv[b * 256 + j] = e / red[0];
}

// out[b][c] = sum_{j<n} w_j * X[j][c]; w = pv or 1. mode1: out = d*(al*(d*out)) + bias
__global__ void wsumrows_kernel(const f16* __restrict__ Xh, const f16* __restrict__ Xl,
                                const float* __restrict__ pv, const float* __restrict__ sc,
                                const float* __restrict__ bias,
                                float* __restrict__ out, int n, int mode) {
  int b = blockIdx.y, c = blockIdx.x * 256 + threadIdx.x;
  long base = (long)b * BSC;
  float s = 0.f;
  for (int j = 0; j < n; ++j) {
    float x = rc(Xh[base + (long)j * LDC + c], Xl[base + (long)j * LDC + c]);
    s = fmaf(pv ? pv[b * 256 + j] : 1.f, x, s);
  }
  if (mode) {
    float d = sc[b * 16 + 4], al = sc[b * 16 + 2];
    s = d * (al * (d * s)) + bias[c];
  }
  out[b * 512 + c] = s;
}

// alpha = p (A p); deg3 = n3*alpha; dinv3
__global__ __launch_bounds__(256)
void alpha_kernel(const f16* __restrict__ AAh, const f16* __restrict__ AAl,
                  const float* __restrict__ pv, float* __restrict__ sc, int n, int n3) {
  int b = blockIdx.x, t = threadIdx.x;
  __shared__ float red[256];
  long base = (long)b * BS2;
  float qm = 0.f;
  if (t < n)
    for (int j = 0; j < n; ++j)
      qm = fmaf(pv[b * 256 + j], rc(AAh[base + (long)j * 256 + t], AAl[base + (long)j * 256 + t]), qm);
  red[t] = (t < n) ? qm * pv[b * 256 + t] : 0.f;
  __syncthreads();
  for (int s = 128; s > 0; s >>= 1) { if (t < s) red[t] += red[t + s]; __syncthreads(); }
  if (t == 0) {
    float a = red[0];
    float d3 = a * (float)n3;
    sc[b * 16 + 2] = a;
    sc[b * 16 + 3] = d3;
    sc[b * 16 + 4] = (d3 > 0.f) ? (1.f / sqrtf(d3)) : 0.f;
  }
}

// t-scalars from xcrow, broadcast into t1/t2/t3 arrays
__global__ void tscal_kernel(const float* __restrict__ xcr, const float* __restrict__ w1,
                             const float* __restrict__ w2, const float* __restrict__ w3,
                             float* __restrict__ t1, float* __restrict__ t2,
                             float* __restrict__ t3, int n) {
  int b = blockIdx.x, lane = threadIdx.x;
  float a1 = 0.f, a2 = 0.f, a3 = 0.f;
  for (int c = lane; c < CH; c += 64) {
    float x = xcr[b * 512 + c];
    a1 = fmaf(x, w1[c], a1); a2 = fmaf(x, w2[c], a2); a3 = fmaf(x, w3[c], a3);
  }
  a1 = warp_sum_f(a1); a2 = warp_sum_f(a2); a3 = warp_sum_f(a3);
  for (int i = lane; i < n; i += 64) {
    t1[b * 256 + i] = a1; t2[b * 256 + i] = a2; t3[b * 256 + i] = a3;
  }
}

// y[b][c] = sum_d x[b][d] * W[d][c]   (W f32 [D][512])
__global__ __launch_bounds__(256)
void matvec512_kernel(const float* __restrict__ x, const float* __restrict__ W,
                      float* __restrict__ y, int D) {
  int b = blockIdx.x;
  __shared__ float xsd[1024];
  for (int d = threadIdx.x; d < D; d += 256) xsd[d] = x[(long)b * D + d];
  __syncthreads();
  for (int c = threadIdx.x; c < 512; c += 256) {
    float s = 0.f;
    for (int d = 0; d < D; ++d) s = fmaf(xsd[d], W[(long)d * 512 + c], s);
    y[b * 512 + c] = s;
  }
}

__global__ void gat3scal_kernel(const float* __restrict__ h, const float* __restrict__ adst,
                                const float* __restrict__ asrc, float* __restrict__ sc) {
  int b = blockIdx.x, lane = threadIdx.x;
  float a1 = 0.f, a2 = 0.f;
  for (int c = lane; c < CH; c += 64) {
    float x = h[b * 512 + c];
    a1 = fmaf(x, adst[c], a1); a2 = fmaf(x, asrc[c], a2);
  }
  a1 = warp_sum_f(a1); a2 = warp_sum_f(a2);
  if (lane == 0) { sc[b * 16 + 0] = a1; sc[b * 16 + 1] = a2; }
}

// w[i] = sum_j softmax_j(leaky(vals_i*hd + vals_j*hs)) * vals_j
__global__ __launch_bounds__(256)
void gatw_kernel(const float* __restrict__ vals, const float* __restrict__ sc,
                 float* __restrict__ wv, int n) {
  int b = blockIdx.y, i = blockIdx.x, t = threadIdx.x;
  __shared__ float red[256];
  __shared__ float red2[256];
  float hd = sc[b * 16 + 0], hs = sc[b * 16 + 1];
  float si = vals[b * 256 + i] * hd;
  float z = -1e30f, vj = 0.f;
  if (t < n) {
    vj = vals[b * 256 + t];
    float zz = si + vj * hs;
    z = (zz > 0.f) ? zz : 0.2f * zz;
  }
  red[t] = z; __syncthreads();
  for (int s = 128; s > 0; s >>= 1) { if (t < s) red[t] = fmaxf(red[t], red[t + s]); __syncthreads(); }
  float mx = red[0]; __syncthreads();
  float e = (t < n) ? expf(z - mx) : 0.f;
  red[t] = e; red2[t] = e * vj; __syncthreads();
  for (int s = 128; s > 0; s >>= 1) {
    if (t < s) { red[t] += red[t + s]; red2[t] += red2[t + s]; }
    __syncthreads();
  }
  if (t == 0) wv[b * 256 + i] = red2[0] / red[0];
}

// X[i][c] = relu(w_i*h_c + cb_c) -> planes
__global__ void xgat_kernel(const float* __restrict__ wv, const float* __restrict__ h,
                            const float* __restrict__ cb, f16* __restrict__ Xh,
                            f16* __restrict__ Xl) {
  int b = blockIdx.y, i = blockIdx.x, t = threadIdx.x;
  float w_ = wv[b * 256 + i];
#pragma unroll
  for (int r = 0; r < 2; ++r) {
    int c = t + r * 256;
    float v = fmaxf(w_ * h[b * 512 + c] + cb[c], 0.f);
    f16 hh, ll; split1(v, hh, ll);
    long o = (long)b * BSC + (long)i * LDC + c;
    Xh[o] = hh; Xl[o] = ll;
  }
}

// sifu = xpr.vvec + c0 ; sj broadcast = xpr.awC
__global__ void pool3pre_kernel(const float* __restrict__ xpr, const float* __restrict__ vvec3,
                                const float* __restrict__ c03, const float* __restrict__ aw3C,
                                float* __restrict__ sifu, float* __restrict__ sj, int n3) {
  int b = blockIdx.x, lane = threadIdx.x;
  float a1 = 0.f, a2 = 0.f;
  for (int c = lane; c < CH; c += 64) {
    float x = xpr[b * 512 + c];
    a1 = fmaf(x, vvec3[c], a1); a2 = fmaf(x, aw3C[c], a2);
  }
  a1 = warp_sum_f(a1); a2 = warp_sum_f(a2);
  if (lane == 0) sifu[b] = a1 + c03[0];
  for (int j = lane; j < n3; j += 64) sj[b * 256 + j] = a2;
}

// layer-3 fit (all-equal): vals broadcast
__global__ void fit3_kernel(const float* __restrict__ xcr, const float* __restrict__ w1,
                            const float* __restrict__ w2, const float* __restrict__ w3,
                            const float* __restrict__ leb1, const float* __restrict__ sc,
                            float* __restrict__ vals, int n3, int kk3) {
  int b = blockIdx.x, lane = threadIdx.x;
  float a1 = 0.f, a2 = 0.f, a3 = 0.f;
  for (int c = lane; c < CH; c += 64) {
    float x = xcr[b * 512 + c];
    a1 = fmaf(x, w1[c], a1); a2 = fmaf(x, w2[c], a2); a3 = fmaf(x, w3[c], a3);
  }
  a1 = warp_sum_f(a1); a2 = warp_sum_f(a2); a3 = warp_sum_f(a3);
  float alpha = sc[b * 16 + 2], deg3 = sc[b * 16 + 3];
  float sub = 0.f;
  for (int j = 0; j < n3; ++j) sub += alpha * a3;
  float z = a1 + leb1[0] + a2 * deg3 - sub;
  float fv = 1.f / (1.f + expf(-z));
  for (int p = lane; p < kk3; p += 64) vals[b * 256 + p] = fv;
}

// readout of rank-1 X' = vals (x) xcr: mean and max per column
__global__ __launch_bounds__(256)
void readout_rank1_kernel(const float* __restrict__ vals, const float* __restrict__ xcr,
                          float* __restrict__ xs, int k) {
  int b = blockIdx.x, t = threadIdx.x;
  __shared__ float red[256];
  red[t] = (t < k) ? vals[b * 256 + t] : 0.f;
  __syncthreads();
  for (int s = 128; s > 0; s >>= 1) { if (t < s) red[t] += red[t + s]; __syncthreads(); }
  float sv = red[0] / (float)k;
  float vmax = vals[b * 256], vmin = vals[b * 256 + k - 1];
#pragma unroll
  for (int r = 0; r < 2; ++r) {
    int c = t + r * 256;
    float x = xcr[b * 512 + c];
    xs[b * 1024 + c] += sv * x;
    xs[b * 1024 + 512 + c] += (x >= 0.f ? vmax : vmin) * x;
  }
}

// ---------------- host orchestration ----------------
extern "C" void kernel_launch(void* const* d_in, const int* in_sizes, int n_in,
                              void* d_out, int out_size, void* d_ws, size_t ws_size,
                              hipStream_t stream) {
  (void)in_sizes; (void)n_in; (void)out_size;
  const int*   x_ids  = (const int*)  d_in[0];
  const float* adj    = (const float*)d_in[2];
  const float* emb    = (const float*)d_in[3];
  const float* conv_W = (const float*)d_in[4];
  const float* conv_b = (const float*)d_in[5];
  const float* att_src= (const float*)d_in[6];
  const float* att_dst= (const float*)d_in[7];
  const float* q_W    = (const float*)d_in[8];
  const float* q_b    = (const float*)d_in[9];
  const float* att_w  = (const float*)d_in[10];
  const float* att_b  = (const float*)d_in[11];
  const float* gcn_W  = (const float*)d_in[12];
  const float* gcn_b  = (const float*)d_in[13];
  const float* le_W1  = (const float*)d_in[14];
  const float* le_b1  = (const float*)d_in[15];
  const float* le_W2  = (const float*)d_in[16];
  const float* le_W3  = (const float*)d_in[17];
  const float* lin1_W = (const float*)d_in[18];
  const float* lin1_b = (const float*)d_in[19];
  const float* lin2_W = (const float*)d_in[20];
  const float* lin2_b = (const float*)d_in[21];
  float* out = (float*)d_out;

  const size_t WN_CONV = 3u * CH * CH;
  const size_t WN_GCN  = 3u * CH * CH;
  const size_t WN_L1   = (size_t)(2 * CH) * CH;
  const size_t WN_L2   = (size_t)CH * 511;
  const size_t WTOT    = WN_CONV + WN_GCN + WN_L1 + WN_L2;

  const size_t per_b  = (size_t)(3 * BSC * 4 + 2 * BS2 * 4 + 11 * 256 * 4
                                 + (4 * 512 + 2 * 256 + 16) * 4 + 4096);
  const size_t fixedb = (size_t)(3 * 512 + 64 + NB * 1024 + NB * 512) * 4
                      + WTOT * 4 + (size_t)NB * 1024 * 4 + (size_t)NB * 512 * 4;
  const size_t slack  = 64 * 512;
  int bc = 4;
  for (int cand = 256; cand >= 4; cand >>= 1) {
    if ((size_t)cand * per_b + fixedb + slack <= ws_size) { bc = cand; break; }
  }
  const int nchunks = NB / bc;

  char* w = (char*)d_ws;
  auto alloc = [&](size_t bytes) { char* p = w; w += (bytes + 255) & ~(size_t)255; return p; };
  // fixed
  float* xs   = (float*)alloc(sizeof(float) * NB * 1024);
  float* vvec = (float*)alloc(sizeof(float) * 3 * CH);
  float* c0   = (float*)alloc(256);
  f16*   Wh   = (f16*)alloc(WTOT * 2);
  f16*   Wl   = (f16*)alloc(WTOT * 2);
  f16*   XSh  = (f16*)alloc((size_t)NB * 1024 * 2);
  f16*   XSl  = (f16*)alloc((size_t)NB * 1024 * 2);
  f16*   FHh  = (f16*)alloc((size_t)NB * 512 * 2);
  f16*   FHl  = (f16*)alloc((size_t)NB * 512 * 2);
  // chunk-local
  f16* Xh  = (f16*)alloc((size_t)bc * BSC * 2);
  f16* Xl  = (f16*)alloc((size_t)bc * BSC * 2);
  f16* Hh  = (f16*)alloc((size_t)bc * BSC * 2);
  f16* Hl  = (f16*)alloc((size_t)bc * BSC * 2);
  f16* XPh = (f16*)alloc((size_t)bc * BSC * 2);
  f16* XPl = (f16*)alloc((size_t)bc * BSC * 2);
  f16* Ph  = (f16*)alloc((size_t)bc * BS2 * 2);
  f16* Pl  = (f16*)alloc((size_t)bc * BS2 * 2);
  f16* AAh = (f16*)alloc((size_t)bc * BS2 * 2);
  f16* AAl = (f16*)alloc((size_t)bc * BS2 * 2);
  float* si   = (float*)alloc(sizeof(float) * bc * NMAX);
  float* sj   = (float*)alloc(sizeof(float) * bc * NMAX);
  float* deg  = (float*)alloc(sizeof(float) * bc * NMAX);
  float* dinv = (float*)alloc(sizeof(float) * bc * NMAX);
  float* t1   = (float*)alloc(sizeof(float) * bc * NMAX);
  float* t2   = (float*)alloc(sizeof(float) * bc * NMAX);
  float* t3   = (float*)alloc(sizeof(float) * bc * NMAX);
  float* fit  = (float*)alloc(sizeof(float) * bc * NMAX);
  float* vals = (float*)alloc(sizeof(float) * bc * NMAX);
  int*   perm = (int*)  alloc(sizeof(int)   * bc * NMAX);
  float* sifu = (float*)alloc(sizeof(float) * bc);
  float* pv   = (float*)alloc(sizeof(float) * bc * 256);
  float* wv   = (float*)alloc(sizeof(float) * bc * 256);
  float* xcr  = (float*)alloc(sizeof(float) * bc * 512);
  float* xcr2 = (float*)alloc(sizeof(float) * bc * 512);
  float* h3   = (float*)alloc(sizeof(float) * bc * 512);
  float* xpr  = (float*)alloc(sizeof(float) * bc * 512);
  float* sc   = (float*)alloc(sizeof(float) * bc * 16);

  f16* cwh = Wh;                       f16* cwl = Wl;
  f16* gwh = Wh + WN_CONV;             f16* gwl = Wl + WN_CONV;
  f16* l1h = Wh + WN_CONV + WN_GCN;    f16* l1l = Wl + WN_CONV + WN_GCN;
  f16* l2h = l1h + WN_L1;              f16* l2l = l1l + WN_L1;

  hipMemsetAsync(xs, 0, sizeof(float) * NB * 1024, stream);

  for (int l = 0; l < 3; ++l) {
    presplit_kernel<<<512, 256, 0, stream>>>(conv_W + (size_t)l * CH * CH,
                                             cwh + (size_t)l * CH * CH,
                                             cwl + (size_t)l * CH * CH, CH, CH);
    presplit_kernel<<<512, 256, 0, stream>>>(gcn_W + (size_t)l * CH * CH,
                                             gwh + (size_t)l * CH * CH,
                                             gwl + (size_t)l * CH * CH, CH, CH);
    vq_kernel<<<513, 64, 0, stream>>>(q_W + (size_t)l * CH * CH, q_b + l * CH,
                                      att_w + (size_t)l * 2 * CH, vvec + l * CH, c0 + l);
  }
  presplit_kernel<<<512, 256, 0, stream>>>(lin1_W, l1h, l1l, 2 * CH, CH);
  presplit_kernel<<<511, 256, 0, stream>>>(lin2_W, l2h, l2l, CH, 511);

  for (int ch = 0; ch < nchunks; ++ch) {
    const int b0 = ch * bc;
    const int*   ids_c = x_ids + (size_t)b0 * NMAX;
    const float* adj_c = adj + (size_t)b0 * BS2;
    float*       xs_c  = xs + (size_t)b0 * 1024;

    build_a_deg_kernel<<<dim3(NMAX, bc), 256, 0, stream>>>(adj_c, AAh, AAl, deg, dinv);
    embed_kernel<<<dim3(NMAX, bc), 128, 0, stream>>>(ids_c, emb, Xh, Xl);

    // ================= layer 1 (full, masked) =================
    {
      const int n = 256, kk = 205, mt = 2;
      const float* aw = att_w;
      pgemm_kernel<0><<<dim3(4, mt, bc), 256, 0, stream>>>(
          Xh, Xl, BSC, LDC, cwh, cwl, 0, CH,
          Hh, Hl, nullptr, BSC, LDC, nullptr, nullptr, n, CH, CH, 8);
      rowdot_kernel<<<dim3(n, bc), 64, 0, stream>>>(
          Hh, Hl, att_dst, att_src, nullptr, si, sj, nullptr, 2);
      softmax_kernel<<<dim3(n, bc), 256, 0, stream>>>(AAh, AAl, si, sj, nullptr, Ph, Pl, n, 1);
      pgemm_kernel<1><<<dim3(4, mt, bc), 256, 0, stream>>>(
          Ph, Pl, BS2, LD2, Hh, Hl, BSC, LDC,
          Xh, Xl, nullptr, BSC, LDC, conv_b, nullptr, n, CH, n, 1 | 2 | 8);
      pgemm_kernel<0><<<dim3(4, mt, bc), 256, 0, stream>>>(
          Xh, Xl, BSC, LDC, gwh, gwl, 0, CH,
          Hh, Hl, nullptr, BSC, LDC, nullptr, dinv, n, CH, CH, 4 | 8);
      pgemm_kernel<1><<<dim3(4, mt, bc), 256, 0, stream>>>(
          AAh, AAl, BS2, LD2, Hh, Hl, BSC, LDC,
          XPh, XPl, nullptr, BSC, LDC, gcn_b, dinv, n, CH, n, 1 | 4 | 8);
      rowdot_kernel<<<dim3(n, bc), 64, 0, stream>>>(
          XPh, XPl, aw + CH, nullptr, nullptr, sj, nullptr, nullptr, 1);
      colmax_kernel<<<bc, 256, 0, stream>>>(XPh, XPl, vvec, c0, sifu, n);
      nbrdot_kernel<<<dim3(n, bc), 256, 0, stream>>>(AAh, AAl, XPh, XPl, vvec, c0, sifu, si, n);
      softmax_kernel<<<dim3(n, bc), 256, 0, stream>>>(AAh, AAl, si, sj, att_b, Ph, Pl, n, 1);
      pgemm_kernel<1><<<dim3(4, mt, bc), 256, 0, stream>>>(
          Ph, Pl, BS2, LD2, Xh, Xl, BSC, LDC,
          Hh, Hl, nullptr, BSC, LDC, nullptr, nullptr, n, CH, n, 8);  // xc
      rowdot_kernel<<<dim3(n, bc), 64, 0, stream>>>(
          Hh, Hl, le_W1, le_W2, le_W3, t1, t2, t3, 3);
      fit_kernel<<<dim3(n, bc), 64, 0, stream>>>(AAh, AAl, t1, t2, t3, deg, le_b1, fit, n);
      topk_kernel<<<bc, 256, 0, stream>>>(fit, perm, vals, n, kk);
      gather_kernel<<<dim3(kk, bc), 256, 0, stream>>>(Hh, Hl, Ph, Pl, perm, vals,
                                                      Xh, Xl, XPh, XPl, n);
      int mtk = 2;
      pgemm_kernel<0><<<dim3(2, mtk, bc), 256, 0, stream>>>(
          XPh, XPl, BSC, LD2, AAh, AAl, BS2, LD2,
          Ph, Pl, nullptr, BS2, LD2, nullptr, nullptr, kk, n, n, 8);          // SA
      pgemm_kernel<0><<<dim3(mtk, mtk, bc), 256, 0, stream>>>(
          Ph, Pl, BS2, LD2, XPh, XPl, BSC, LD2,
          AAh, AAl, nullptr, BS2, LD2, nullptr, nullptr, kk, kk, n, 8);       // A_new
      degfix_kernel<<<dim3(kk, bc), 256, 0, stream>>>(AAh, AAl, deg, dinv, kk);
      readout_kernel<<<bc, 256, 0, stream>>>(Xh, Xl, xs_c, kk);
    }

    // ================= layer 2 (dense mask; pool collapsed) =================
    {
      const int n = 205, kk = 164, mt = 2;
      const float* aw = att_w + (size_t)2 * CH;
      // GAT (full, unmasked)
      pgemm_kernel<0><<<dim3(4, mt, bc), 256, 0, stream>>>(
          Xh, Xl, BSC, LDC, cwh + (size_t)CH * CH, cwl + (size_t)CH * CH, 0, CH,
          Hh, Hl, nullptr, BSC, LDC, nullptr, nullptr, n, CH, CH, 8);
      rowdot_kernel<<<dim3(n, bc), 64, 0, stream>>>(
          Hh, Hl, att_dst + CH, att_src + CH, nullptr, si, sj, nullptr, 2);
      softmax_kernel<<<dim3(n, bc), 256, 0, stream>>>(AAh, AAl, si, sj, nullptr, Ph, Pl, n, 0);
      pgemm_kernel<1><<<dim3(4, mt, bc), 256, 0, stream>>>(
          Ph, Pl, BS2, LD2, Hh, Hl, BSC, LDC,
          Xh, Xl, nullptr, BSC, LDC, conv_b + CH, nullptr, n, CH, n, 1 | 2 | 8);
      // GCN (full)
      pgemm_kernel<0><<<dim3(4, mt, bc), 256, 0, stream>>>(
          Xh, Xl, BSC, LDC, gwh + (size_t)CH * CH, gwl + (size_t)CH * CH, 0, CH,
          Hh, Hl, nullptr, BSC, LDC, nullptr, dinv, n, CH, CH, 4 | 8);
      pgemm_kernel<1><<<dim3(4, mt, bc), 256, 0, stream>>>(
          AAh, AAl, BS2, LD2, Hh, Hl, BSC, LDC,
          XPh, XPl, nullptr, BSC, LDC, gcn_b + CH, dinv, n, CH, n, 1 | 4 | 8);
      // collapsed pool
      rowdot_kernel<<<dim3(n, bc), 64, 0, stream>>>(
          XPh, XPl, aw + CH, nullptr, nullptr, sj, nullptr, nullptr, 1);
      colmax_kernel<<<bc, 256, 0, stream>>>(XPh, XPl, vvec + CH, c0 + 1, sifu, n);
      prow_kernel<<<bc, 256, 0, stream>>>(sj, sifu, att_b + 1, pv, n);
      wsumrows_kernel<<<dim3(2, bc), 256, 0, stream>>>(Xh, Xl, pv, nullptr, nullptr, xcr, n, 0);
      tscal_kernel<<<bc, 64, 0, stream>>>(xcr, le_W1 + CH, le_W2 + CH, le_W3 + CH, t1, t2, t3, n);
      fit_kernel<<<dim3(n, bc), 64, 0, stream>>>(AAh, AAl, t1, t2, t3, deg, le_b1 + 1, fit, n);
      topk_kernel<<<bc, 256, 0, stream>>>(fit, perm, vals, n, kk);
      alpha_kernel<<<bc, 256, 0, stream>>>(AAh, AAl, pv, sc, n, kk);
      readout_rank1_kernel<<<bc, 256, 0, stream>>>(vals, xcr, xs_c, kk);
    }

    // ================= layer 3 (rank-1 X; everything collapsed) =================
    {
      const int n = 164, kk = 132, mt = 2;
      const float* aw = att_w + (size_t)4 * CH;
      // GAT rank-1
      matvec512_kernel<<<bc, 256, 0, stream>>>(xcr, conv_W + (size_t)2 * CH * CH, h3, 512);
      gat3scal_kernel<<<bc, 64, 0, stream>>>(h3, att_dst + 2 * CH, att_src + 2 * CH, sc);
      gatw_kernel<<<dim3(n, bc), 256, 0, stream>>>(vals, sc, wv, n);
      xgat_kernel<<<dim3(n, bc), 256, 0, stream>>>(wv, h3, conv_b + 2 * CH, Xh, Xl);
      // GCN: one GEMM + collapsed A (= alpha * ones)
      pgemm_kernel<0><<<dim3(4, mt, bc), 256, 0, stream>>>(
          Xh, Xl, BSC, LDC, gwh + (size_t)2 * CH * CH, gwl + (size_t)2 * CH * CH, 0, CH,
          Hh, Hl, nullptr, BSC, LDC, nullptr, nullptr, n, CH, CH, 8);
      wsumrows_kernel<<<dim3(2, bc), 256, 0, stream>>>(Hh, Hl, nullptr, sc, gcn_b + 2 * CH,
                                                       xpr, n, 1);
      // collapsed pool
      pool3pre_kernel<<<bc, 64, 0, stream>>>(xpr, vvec + 2 * CH, c0 + 2, aw + CH, sifu, sj, n);
      prow_kernel<<<bc, 256, 0, stream>>>(sj, sifu, att_b + 2, pv, n);
      wsumrows_kernel<<<dim3(2, bc), 256, 0, stream>>>(Xh, Xl, pv, nullptr, nullptr, xcr2, n, 0);
      fit3_kernel<<<bc, 64, 0, stream>>>(xcr2, le_W1 + 2 * CH, le_W2 + 2 * CH, le_W3 + 2 * CH,
                                         le_b1 + 2, sc, vals, n, kk);
      readout_rank1_kernel<<<bc, 256, 0, stream>>>(vals, xcr2, xs_c, kk);
    }
  }

  // ---- final MLP (full batch) ----
  splitbuf_kernel<<<NB, 256, 0, stream>>>(xs, XSh, XSl, 1024);
  pgemm_kernel<0><<<dim3(4, 2, 1), 256, 0, stream>>>(
      XSh, XSl, 0, 1024, l1h, l1l, 0, 1024,
      FHh, FHl, nullptr, 0, CH, lin1_b, nullptr, NB, CH, 2 * CH, 1 | 2 | 8);
  pgemm_kernel<0><<<dim3(4, 2, 1), 256, 0, stream>>>(
      FHh, FHl, 0, CH, l2h, l2l, 0, CH,
      nullptr, nullptr, out, 0, 511, lin2_b, nullptr, NB, 511, CH, 1 | 16);
}

// Round 6
// 3824.209 us; speedup vs baseline: 2.5518x; 1.4412x over previous
//
#include <hip/hip_runtime.h>
#include <math.h>

#define NB   256
#define NMAX 256
#define CH   512
#define LD2  256
#define LDC  512
#define BS2  (256*256)
#define BSC  (256*512)

typedef _Float16 f16;
typedef __attribute__((ext_vector_type(4))) f16 f16x4;
typedef __attribute__((ext_vector_type(8))) f16 f16x8;
typedef __attribute__((ext_vector_type(4))) float f32x4;

#define INV2048 4.8828125e-04f

__device__ __forceinline__ float warp_sum_f(float v) {
#pragma unroll
  for (int m = 32; m >= 1; m >>= 1) v += __shfl_xor(v, m);
  return v;
}

__device__ __forceinline__ void split1(float x, f16& h, f16& l) {
  float xh = (__builtin_fabsf(x) >= 6.103515625e-05f) ? x : 0.f;
  f16 hh = (f16)xh;
  float hf = (float)hh;
  h = hh;
  l = (f16)((x - hf) * 2048.0f);
}

__device__ __forceinline__ float rc(f16 h, f16 l) {
  return (float)h + (float)l * INV2048;
}

__device__ __forceinline__ float rc8q(const f16x8& h, const f16x8& l, int q) {
  return (float)h[q] + (float)l[q] * INV2048;
}

// ---------------- plane GEMM with register prefetch (unchanged from r5) ----------------
template <int BMODE>
__global__ __launch_bounds__(256, 2)
void pgemm_kernel(const f16* __restrict__ Ahp, const f16* __restrict__ Alp, long bsA, int lda,
                  const f16* __restrict__ Bhp, const f16* __restrict__ Blp, long bsB, int ldb,
                  f16* __restrict__ Yh, f16* __restrict__ Yl, float* __restrict__ Yf,
                  long bsY, int ldy,
                  const float* __restrict__ bias, const float* __restrict__ rowscale,
                  int M, int Ncol, int K, int flags)
{
  __shared__ f16 Ah[128][40];
  __shared__ f16 Al[128][40];
  __shared__ f16 Bh[128][40];
  __shared__ f16 Bl[128][40];
  const int b   = blockIdx.z;
  const int i0  = blockIdx.y * 128;
  const int n0  = blockIdx.x * 128;
  const int tid = threadIdx.x;
  const int w  = tid >> 6, l = tid & 63;
  const int wr = (w >> 1) * 64, wc = (w & 1) * 64;
  const int lr = l & 15, lq = l >> 4;
  const f16* Abh = Ahp + (long)b * bsA;
  const f16* Abl = Alp + (long)b * bsA;
  const f16* Bbh = Bhp + (long)b * bsB;
  const f16* Bbl = Blp + (long)b * bsB;

  f32x4 acc1[4][4], acc2[4][4];
#pragma unroll
  for (int mi = 0; mi < 4; ++mi)
#pragma unroll
    for (int ni = 0; ni < 4; ++ni) {
      acc1[mi][ni] = (f32x4){0.f, 0.f, 0.f, 0.f};
      acc2[mi][ni] = (f32x4){0.f, 0.f, 0.f, 0.f};
    }

  f16x4 rah[4], ral[4];
  f16x4 rbh[4], rbl[4];
  f16x8 rva, rvb, rwa, rwb;

  auto LOADA = [&](int k0) {
#pragma unroll
    for (int rep = 0; rep < 4; ++rep) {
      int row = rep * 32 + (tid >> 3);
      int kq  = (tid & 7) * 4;
      int gr = i0 + row, gk = k0 + kq;
      f16x4 h = (f16x4){0, 0, 0, 0}, lo = (f16x4){0, 0, 0, 0};
      if (gr < M) {
        if (gk + 3 < K) {
          h  = *(const f16x4*)(Abh + (long)gr * lda + gk);
          lo = *(const f16x4*)(Abl + (long)gr * lda + gk);
        } else {
#pragma unroll
          for (int j = 0; j < 4; ++j) if (gk + j < K) {
            h[j]  = Abh[(long)gr * lda + gk + j];
            lo[j] = Abl[(long)gr * lda + gk + j];
          }
        }
      }
      rah[rep] = h; ral[rep] = lo;
    }
  };
  auto STOREA = [&]() {
#pragma unroll
    for (int rep = 0; rep < 4; ++rep) {
      int row = rep * 32 + (tid >> 3);
      int kq  = (tid & 7) * 4;
      *(f16x4*)&Ah[row][kq] = rah[rep];
      *(f16x4*)&Al[row][kq] = ral[rep];
    }
  };
  auto LOADB = [&](int k0) {
    if (BMODE == 0) {
#pragma unroll
      for (int rep = 0; rep < 4; ++rep) {
        int c  = rep * 32 + (tid >> 3);
        int kq = (tid & 7) * 4;
        int gc = n0 + c, gk = k0 + kq;
        f16x4 h = (f16x4){0, 0, 0, 0}, lo = (f16x4){0, 0, 0, 0};
        if (gc < Ncol) {
          if (gk + 3 < K) {
            h  = *(const f16x4*)(Bbh + (long)gc * ldb + gk);
            lo = *(const f16x4*)(Bbl + (long)gc * ldb + gk);
          } else {
#pragma unroll
            for (int j = 0; j < 4; ++j) if (gk + j < K) {
              h[j]  = Bbh[(long)gc * ldb + gk + j];
              lo[j] = Bbl[(long)gc * ldb + gk + j];
            }
          }
        }
        rbh[rep] = h; rbl[rep] = lo;
      }
    } else {
      int c8  = (tid & 15) * 8;
      int k0p = (tid >> 4) * 2;
      int gc = n0 + c8;
      f16x8 z = (f16x8){0,0,0,0,0,0,0,0};
      rva = z; rvb = z; rwa = z; rwb = z;
      int gka = k0 + k0p, gkb = gka + 1;
      if (gka < K) { rva = *(const f16x8*)(Bbh + (long)gka * ldb + gc);
                     rwa = *(const f16x8*)(Bbl + (long)gka * ldb + gc); }
      if (gkb < K) { rvb = *(const f16x8*)(Bbh + (long)gkb * ldb + gc);
                     rwb = *(const f16x8*)(Bbl + (long)gkb * ldb + gc); }
    }
  };
  auto STOREB = [&]() {
    if (BMODE == 0) {
#pragma unroll
      for (int rep = 0; rep < 4; ++rep) {
        int c  = rep * 32 + (tid >> 3);
        int kq = (tid & 7) * 4;
        *(f16x4*)&Bh[c][kq] = rbh[rep];
        *(f16x4*)&Bl[c][kq] = rbl[rep];
      }
    } else {
      int c8  = (tid & 15) * 8;
      int k0p = (tid >> 4) * 2;
#pragma unroll
      for (int j = 0; j < 8; ++j) {
        union { f16 f[2]; unsigned u; } ph, pl;
        ph.f[0] = rva[j]; ph.f[1] = rvb[j];
        pl.f[0] = rwa[j]; pl.f[1] = rwb[j];
        *(unsigned*)&Bh[c8 + j][k0p] = ph.u;
        *(unsigned*)&Bl[c8 + j][k0p] = pl.u;
      }
    }
  };

  const int nk = (K + 31) / 32;
  LOADA(0); LOADB(0);
  for (int ki = 0; ki < nk; ++ki) {
    STOREA(); STOREB();
    __syncthreads();
    if (ki + 1 < nk) { LOADA((ki + 1) * 32); LOADB((ki + 1) * 32); }

    f16x8 bh[4], bl[4];
#pragma unroll
    for (int ni = 0; ni < 4; ++ni) {
      bh[ni] = *(const f16x8*)&Bh[wc + ni * 16 + lr][lq * 8];
      bl[ni] = *(const f16x8*)&Bl[wc + ni * 16 + lr][lq * 8];
    }
#pragma unroll
    for (int mi = 0; mi < 4; ++mi) {
      f16x8 ah = *(const f16x8*)&Ah[wr + mi * 16 + lr][lq * 8];
      f16x8 al = *(const f16x8*)&Al[wr + mi * 16 + lr][lq * 8];
#pragma unroll
      for (int ni = 0; ni < 4; ++ni) {
        acc1[mi][ni] = __builtin_amdgcn_mfma_f32_16x16x32_f16(ah, bh[ni], acc1[mi][ni], 0, 0, 0);
        acc2[mi][ni] = __builtin_amdgcn_mfma_f32_16x16x32_f16(ah, bl[ni], acc2[mi][ni], 0, 0, 0);
        acc2[mi][ni] = __builtin_amdgcn_mfma_f32_16x16x32_f16(al, bh[ni], acc2[mi][ni], 0, 0, 0);
      }
    }
    __syncthreads();
  }

#pragma unroll
  for (int mi = 0; mi < 4; ++mi) {
#pragma unroll
    for (int ni = 0; ni < 4; ++ni) {
      int col = n0 + wc + ni * 16 + lr;
      if (col >= Ncol) continue;
      float bv = (flags & 1) ? bias[col] : 0.f;
#pragma unroll
      for (int r = 0; r < 4; ++r) {
        int row = i0 + wr + mi * 16 + lq * 4 + r;
        if (row >= M) continue;
        float vv = acc1[mi][ni][r] + acc2[mi][ni][r] * INV2048;
        if (flags & 4) vv *= rowscale[b * 256 + row];
        vv += bv;
        if (flags & 2) vv = fmaxf(vv, 0.f);
        long off = (long)b * bsY + (long)row * ldy + col;
        if (flags & 8) { f16 h, lo; split1(vv, h, lo); Yh[off] = h; Yl[off] = lo; }
        if (flags & 16) Yf[off] = vv;
      }
    }
  }
}

__global__ void presplit_kernel(const float* __restrict__ W, f16* __restrict__ Wh,
                                f16* __restrict__ Wl, int K, int N) {
  int n = blockIdx.x;
  for (int k = threadIdx.x; k < K; k += blockDim.x) {
    f16 h, l; split1(W[(long)k * N + n], h, l);
    Wh[(long)n * K + k] = h;
    Wl[(long)n * K + k] = l;
  }
}

__global__ void splitbuf_kernel(const float* __restrict__ X, f16* __restrict__ Xh,
                                f16* __restrict__ Xl, int cols) {
  int i = blockIdx.x;
  for (int c = threadIdx.x; c < cols; c += blockDim.x) {
    f16 h, l; split1(X[(long)i * cols + c], h, l);
    Xh[(long)i * cols + c] = h;
    Xl[(long)i * cols + c] = l;
  }
}

// ---------------- layer-1 small kernels ----------------
__global__ void build_a_deg_kernel(const float* __restrict__ adj, f16* __restrict__ AAh,
                                   f16* __restrict__ AAl, float* __restrict__ deg,
                                   float* __restrict__ dinv) {
  int b = blockIdx.y, i = blockIdx.x, j = threadIdx.x;
  __shared__ float red[256];
  float v = adj[(long)b * BS2 + i * 256 + j];
  if (i == j) v = fmaxf(v, 1.f);
  f16 h, l; split1(v, h, l);
  long o = (long)b * BS2 + i * 256 + j;
  AAh[o] = h; AAl[o] = l;
  red[j] = v; __syncthreads();
  for (int s = 128; s > 0; s >>= 1) { if (j < s) red[j] += red[j + s]; __syncthreads(); }
  if (j == 0) {
    float s = red[0];
    deg[b * 256 + i] = s;
    dinv[b * 256 + i] = (s > 0.f) ? (1.f / sqrtf(s)) : 0.f;
  }
}

__global__ void embed_kernel(const int* __restrict__ ids, const float* __restrict__ emb,
                             f16* __restrict__ Xh, f16* __restrict__ Xl) {
  int b = blockIdx.y, i = blockIdx.x, t = threadIdx.x;
  int id = ids[b * NMAX + i];
  float4 v = *(const float4*)(emb + (long)id * CH + t * 4);
  long o = (long)b * BSC + (long)i * LDC + t * 4;
  float vv[4] = {v.x, v.y, v.z, v.w};
#pragma unroll
  for (int j = 0; j < 4; ++j) { f16 h, l; split1(vv[j], h, l); Xh[o + j] = h; Xl[o + j] = l; }
}

__global__ void rowdot_kernel(const f16* __restrict__ Xh, const f16* __restrict__ Xl,
                              const float* __restrict__ v1, const float* __restrict__ v2,
                              float* __restrict__ o1, float* __restrict__ o2, int nvec) {
  int b = blockIdx.y, i = blockIdx.x, lane = threadIdx.x;
  long base = (long)b * BSC + (long)i * LDC;
  float a1 = 0.f, a2 = 0.f;
  for (int c = lane; c < CH; c += 64) {
    float x = rc(Xh[base + c], Xl[base + c]);
    a1 = fmaf(x, v1[c], a1);
    if (nvec > 1) a2 = fmaf(x, v2[c], a2);
  }
  a1 = warp_sum_f(a1);
  if (nvec > 1) a2 = warp_sum_f(a2);
  if (lane == 0) {
    o1[b * 256 + i] = a1;
    if (nvec > 1) o2[b * 256 + i] = a2;
  }
}

__global__ void vq_kernel(const float* __restrict__ qW, const float* __restrict__ qb,
                          const float* __restrict__ aw, float* __restrict__ v,
                          float* __restrict__ c0) {
  int blk = blockIdx.x, lane = threadIdx.x;
  if (blk < 512) {
    float s = 0.f;
    for (int j = lane; j < CH; j += 64) s = fmaf(qW[(long)blk * CH + j], aw[j], s);
    s = warp_sum_f(s);
    if (lane == 0) v[blk] = s;
  } else {
    float s = 0.f;
    for (int j = lane; j < CH; j += 64) s = fmaf(qb[j], aw[j], s);
    s = warp_sum_f(s);
    if (lane == 0) c0[0] = s;
  }
}

__global__ __launch_bounds__(256)
void softmax_kernel(const f16* __restrict__ AAh, const f16* __restrict__ AAl,
                    const float* __restrict__ si, const float* __restrict__ sj,
                    const float* __restrict__ attb,
                    f16* __restrict__ Ph, f16* __restrict__ Pl, int n, int masked) {
  int b = blockIdx.y, i = blockIdx.x, j = threadIdx.x;
  __shared__ float red[256];
  float logit = -1e30f, e = 0.f;
  float siv = si[b * 256 + i];
  long ro = (long)b * BS2 + i * 256;
  if (j < n) {
    float z = siv + sj[b * 256 + j] + (attb ? attb[0] : 0.f);
    z = (z > 0.f) ? z : 0.2f * z;
    if (masked) {
      float a = rc(AAh[ro + j], AAl[ro + j]);
      logit = (a > 0.f) ? z : -1e9f;
    } else logit = z;
  }
  red[j] = logit; __syncthreads();
  for (int s = 128; s > 0; s >>= 1) { if (j < s) red[j] = fmaxf(red[j], red[j + s]); __syncthreads(); }
  float mx = red[0]; __syncthreads();
  if (j < n) e = expf(logit - mx);
  red[j] = e; __syncthreads();
  for (int s = 128; s > 0; s >>= 1) { if (j < s) red[j] += red[j + s]; __syncthreads(); }
  float sum = red[0];
  if (j < n) {
    f16 h, l; split1(e / sum, h, l);
    Ph[ro + j] = h; Pl[ro + j] = l;
  }
}

// ---- colmax v2: grid (bc), block 512; 8 row-lanes x 64 col-groups x f16x8 ----
__global__ __launch_bounds__(512)
void colmax_kernel(const f16* __restrict__ XPh, const f16* __restrict__ XPl,
                   const float* __restrict__ v, const float* __restrict__ c0,
                   float* __restrict__ si_full, int n) {
  int b = blockIdx.x, t = threadIdx.x;
  int cg = t >> 3, rl = t & 7, c0c = cg * 8;
  long base = (long)b * BSC;
  __shared__ float red[64];
  float m[8];
#pragma unroll
  for (int q = 0; q < 8; ++q) m[q] = -1e9f;
  for (int j = rl; j < n; j += 8) {
    f16x8 h = *(const f16x8*)(XPh + base + (long)j * LDC + c0c);
    f16x8 l = *(const f16x8*)(XPl + base + (long)j * LDC + c0c);
#pragma unroll
    for (int q = 0; q < 8; ++q) m[q] = fmaxf(m[q], rc8q(h, l, q));
  }
#pragma unroll
  for (int d = 1; d < 8; d <<= 1)
#pragma unroll
    for (int q = 0; q < 8; ++q) m[q] = fmaxf(m[q], __shfl_xor(m[q], d));
  if (rl == 0) {
    float p = 0.f;
#pragma unroll
    for (int q = 0; q < 8; ++q) p = fmaf(m[q], v[c0c + q], p);
    red[cg] = p;
  }
  __syncthreads();
  for (int s = 32; s > 0; s >>= 1) { if (t < s) red[t] += red[t + s]; __syncthreads(); }
  if (t == 0) si_full[b] = red[0] + c0[0];
}

__global__ __launch_bounds__(256)
void nbrdot_kernel(const f16* __restrict__ AAh, const f16* __restrict__ AAl,
                   const f16* __restrict__ XPh, const f16* __restrict__ XPl,
                   const float* __restrict__ v, const float* __restrict__ c0,
                   const float* __restrict__ si_full, float* __restrict__ si, int n) {
  int b = blockIdx.y, i = blockIdx.x, t = threadIdx.x;
  __shared__ int list[256];
  __shared__ int cnt, nmiss;
  __shared__ float red[256];
  if (t == 0) { cnt = 0; nmiss = 0; }
  __syncthreads();
  long ro = (long)b * BS2 + i * 256;
  if (t < n) {
    float a = rc(AAh[ro + t], AAl[ro + t]);
    if (a > 0.f) { int p = atomicAdd(&cnt, 1); list[p] = t; }
    else atomicAdd(&nmiss, 1);
  }
  __syncthreads();
  if (nmiss == 0) {
    if (t == 0) si[b * 256 + i] = si_full[b];
    return;
  }
  int c = cnt;
  long base = (long)b * BSC;
  float m1 = -1e9f, m2 = -1e9f;
  for (int q = 0; q < c; ++q) {
    int j = list[q];
    m1 = fmaxf(m1, rc(XPh[base + (long)j * LDC + t], XPl[base + (long)j * LDC + t]));
    m2 = fmaxf(m2, rc(XPh[base + (long)j * LDC + t + 256], XPl[base + (long)j * LDC + t + 256]));
  }
  red[t] = m1 * v[t] + m2 * v[t + 256];
  __syncthreads();
  for (int s = 128; s > 0; s >>= 1) { if (t < s) red[t] += red[t + s]; __syncthreads(); }
  if (t == 0) si[b * 256 + i] = red[0] + c0[0];
}

__global__ void fit_kernel(const f16* __restrict__ AAh, const f16* __restrict__ AAl,
                           const float* __restrict__ t1, const float* __restrict__ t2,
                           const float* __restrict__ t3,
                           const float* __restrict__ deg, const float* __restrict__ leb1,
                           float* __restrict__ fit, int n) {
  int b = blockIdx.y, i = blockIdx.x, lane = threadIdx.x;
  long ro = (long)b * BS2 + i * 256;
  float s = 0.f;
  for (int j = lane; j < n; j += 64) s = fmaf(rc(AAh[ro + j], AAl[ro + j]), t3[b * 256 + j], s);
  s = warp_sum_f(s);
  if (lane == 0) {
    float z = t1[b * 256 + i] + leb1[0] + t2[b * 256 + i] * deg[b * 256 + i] - s;
    fit[b * 256 + i] = 1.f / (1.f + expf(-z));
  }
}

__global__ __launch_bounds__(256)
void topk_kernel(const float* __restrict__ fit, int* __restrict__ perm,
                 float* __restrict__ vals, int n, int k) {
  __shared__ float v[256];
  __shared__ int ix[256];
  int b = blockIdx.x, t = threadIdx.x;
  v[t] = (t < n) ? fit[b * 256 + t] : -1e30f;
  ix[t] = t;
  __syncthreads();
  for (int size = 2; size <= 256; size <<= 1)
    for (int str = size >> 1; str > 0; str >>= 1) {
      int p = t ^ str;
      if (p > t) {
        bool desc = ((t & size) == 0);
        float v1 = v[t], v2 = v[p]; int i1 = ix[t], i2 = ix[p];
        bool inorder = (v1 > v2) || (v1 == v2 && i1 < i2);
        if (inorder != desc) { v[t] = v2; v[p] = v1; ix[t] = i2; ix[p] = i1; }
      }
      __syncthreads();
    }
  if (t < k) { perm[b * 256 + t] = ix[t]; vals[b * 256 + t] = v[t]; }
}

__global__ __launch_bounds__(256)
void gather_kernel(const f16* __restrict__ Hh, const f16* __restrict__ Hl,
                   const f16* __restrict__ Ph, const f16* __restrict__ Pl,
                   const int* __restrict__ perm, const float* __restrict__ vals,
                   f16* __restrict__ Xh, f16* __restrict__ Xl,
                   f16* __restrict__ Skh, f16* __restrict__ Skl, int n) {
  int b = blockIdx.y, p = blockIdx.x, t = threadIdx.x;
  int src = perm[b * 256 + p];
  float sv = vals[b * 256 + p];
#pragma unroll
  for (int r = 0; r < 2; ++r) {
    int c = t + r * 256;
    long so = (long)b * BSC + (long)src * LDC + c;
    long dof = (long)b * BSC + (long)p * LDC + c;
    float x = rc(Hh[so], Hl[so]) * sv;
    f16 h, l; split1(x, h, l);
    Xh[dof] = h; Xl[dof] = l;
  }
  if (t < n) {
    long so = (long)b * BS2 + src * 256 + t;
    long dof = (long)b * BSC + p * 256 + t;
    Skh[dof] = Ph[so]; Skl[dof] = Pl[so];
  }
}

__global__ void degfix_kernel(f16* __restrict__ AAh, f16* __restrict__ AAl,
                              float* __restrict__ deg, float* __restrict__ dinv, int k) {
  int b = blockIdx.y, i = blockIdx.x, j = threadIdx.x;
  __shared__ float red[256];
  long ro = (long)b * BS2 + i * 256;
  float v = 0.f;
  if (j < k) {
    v = rc(AAh[ro + j], AAl[ro + j]);
    if (j == i && v <= 0.f) {
      v += 1.f;
      f16 h, l; split1(v, h, l);
      AAh[ro + j] = h; AAl[ro + j] = l;
    }
  }
  red[j] = v; __syncthreads();
  for (int s = 128; s > 0; s >>= 1) { if (j < s) red[j] += red[j + s]; __syncthreads(); }
  if (j == 0) {
    float s = red[0];
    deg[b * 256 + i] = s;
    dinv[b * 256 + i] = (s > 0.f) ? (1.f / sqrtf(s)) : 0.f;
  }
}

// ---- readout v2: grid (2,bc), block 256; vectorized + row-split ----
__global__ __launch_bounds__(256)
void readout_kernel(const f16* __restrict__ Xh, const f16* __restrict__ Xl,
                    float* __restrict__ xs, int k) {
  int b = blockIdx.y, t = threadIdx.x;
  int cg = t >> 3, rl = t & 7;
  int c0c = blockIdx.x * 256 + cg * 8;
  long base = (long)b * BSC;
  float s[8], m[8];
#pragma unroll
  for (int q = 0; q < 8; ++q) { s[q] = 0.f; m[q] = -1e30f; }
  for (int p = rl; p < k; p += 8) {
    f16x8 h = *(const f16x8*)(Xh + base + (long)p * LDC + c0c);
    f16x8 l = *(const f16x8*)(Xl + base + (long)p * LDC + c0c);
#pragma unroll
    for (int q = 0; q < 8; ++q) {
      float v = rc8q(h, l, q);
      s[q] += v; m[q] = fmaxf(m[q], v);
    }
  }
#pragma unroll
  for (int d = 1; d < 8; d <<= 1)
#pragma unroll
    for (int q = 0; q < 8; ++q) {
      s[q] += __shfl_xor(s[q], d);
      m[q] = fmaxf(m[q], __shfl_xor(m[q], d));
    }
  if (rl == 0) {
#pragma unroll
    for (int q = 0; q < 8; ++q) {
      xs[b * 1024 + c0c + q] += s[q] / (float)k;
      xs[b * 1024 + 512 + c0c + q] += m[q];
    }
  }
}

// ---- fused layer-2 pool: colmax + prow + wsum(xcr) + tscal + alpha ----
__global__ __launch_bounds__(512)
void pool2_kernel(const f16* __restrict__ XPh, const f16* __restrict__ XPl,
                  const f16* __restrict__ Xh, const f16* __restrict__ Xl,
                  const f16* __restrict__ AAh, const f16* __restrict__ AAl,
                  const float* __restrict__ sj,
                  const float* __restrict__ v, const float* __restrict__ c0,
                  const float* __restrict__ attb,
                  const float* __restrict__ w1, const float* __restrict__ w2,
                  const float* __restrict__ w3,
                  float* __restrict__ xcr, f16* __restrict__ xcrh, f16* __restrict__ xcrl,
                  float* __restrict__ t1, float* __restrict__ t2, float* __restrict__ t3,
                  float* __restrict__ sc, int n, int n3) {
  int b = blockIdx.x, t = threadIdx.x;
  int cg = t >> 3, rl = t & 7, c0c = cg * 8;
  long baseC = (long)b * BSC;
  __shared__ float red[512];
  __shared__ float pvs[256];
  __shared__ float xcs[512];

  // phase 1: colmax(XP) . v -> sifu
  float m[8];
#pragma unroll
  for (int q = 0; q < 8; ++q) m[q] = -1e9f;
  for (int j = rl; j < n; j += 8) {
    f16x8 h = *(const f16x8*)(XPh + baseC + (long)j * LDC + c0c);
    f16x8 l = *(const f16x8*)(XPl + baseC + (long)j * LDC + c0c);
#pragma unroll
    for (int q = 0; q < 8; ++q) m[q] = fmaxf(m[q], rc8q(h, l, q));
  }
#pragma unroll
  for (int d = 1; d < 8; d <<= 1)
#pragma unroll
    for (int q = 0; q < 8; ++q) m[q] = fmaxf(m[q], __shfl_xor(m[q], d));
  if (rl == 0) {
    float p = 0.f;
#pragma unroll
    for (int q = 0; q < 8; ++q) p = fmaf(m[q], v[c0c + q], p);
    red[cg] = p;
  }
  __syncthreads();
  for (int s2 = 32; s2 > 0; s2 >>= 1) { if (t < s2) red[t] += red[t + s2]; __syncthreads(); }
  float sifu = red[0] + c0[0];
  __syncthreads();

  // phase 2: pv = softmax_j(leaky(sifu + sj[j] + ab))
  float z = -1e30f;
  if (t < n) {
    float zz = sifu + sj[b * 256 + t] + attb[0];
    z = (zz > 0.f) ? zz : 0.2f * zz;
  }
  red[t] = z; __syncthreads();
  for (int s2 = 256; s2 > 0; s2 >>= 1) { if (t < s2) red[t] = fmaxf(red[t], red[t + s2]); __syncthreads(); }
  float mx = red[0]; __syncthreads();
  float e = (t < n) ? expf(z - mx) : 0.f;
  red[t] = e; __syncthreads();
  for (int s2 = 256; s2 > 0; s2 >>= 1) { if (t < s2) red[t] += red[t + s2]; __syncthreads(); }
  float psum = red[0];
  __syncthreads();
  if (t < 256) pvs[t] = (t < n) ? e / psum : 0.f;
  __syncthreads();

  // phase 3: xcr = sum_j pv[j] * X[j][:]
  float s8[8];
#pragma unroll
  for (int q = 0; q < 8; ++q) s8[q] = 0.f;
  for (int j = rl; j < n; j += 8) {
    float w_ = pvs[j];
    f16x8 h = *(const f16x8*)(Xh + baseC + (long)j * LDC + c0c);
    f16x8 l = *(const f16x8*)(Xl + baseC + (long)j * LDC + c0c);
#pragma unroll
    for (int q = 0; q < 8; ++q) s8[q] = fmaf(w_, rc8q(h, l, q), s8[q]);
  }
#pragma unroll
  for (int d = 1; d < 8; d <<= 1)
#pragma unroll
    for (int q = 0; q < 8; ++q) s8[q] += __shfl_xor(s8[q], d);
  if (rl == 0) {
#pragma unroll
    for (int q = 0; q < 8; ++q) {
      float vv = s8[q];
      xcs[c0c + q] = vv;
      xcr[b * 512 + c0c + q] = vv;
      f16 hh, ll; split1(vv, hh, ll);
      xcrh[b * 512 + c0c + q] = hh;
      xcrl[b * 512 + c0c + q] = ll;
    }
  }
  __syncthreads();

  // phase 4: tscal -> t1,t2,t3 broadcast
  float x_ = xcs[t];
  red[t] = x_ * w1[t]; __syncthreads();
  for (int s2 = 256; s2 > 0; s2 >>= 1) { if (t < s2) red[t] += red[t + s2]; __syncthreads(); }
  float a1 = red[0]; __syncthreads();
  red[t] = x_ * w2[t]; __syncthreads();
  for (int s2 = 256; s2 > 0; s2 >>= 1) { if (t < s2) red[t] += red[t + s2]; __syncthreads(); }
  float a2 = red[0]; __syncthreads();
  red[t] = x_ * w3[t]; __syncthreads();
  for (int s2 = 256; s2 > 0; s2 >>= 1) { if (t < s2) red[t] += red[t + s2]; __syncthreads(); }
  float a3 = red[0]; __syncthreads();
  if (t < n) { t1[b * 256 + t] = a1; t2[b * 256 + t] = a2; t3[b * 256 + t] = a3; }

  // phase 5: alpha = pv^T A pv (A symmetric -> row reads)
  float qm = 0.f;
  if (t < n) {
    long ro = (long)b * BS2 + (long)t * 256;
    int j = 0;
    for (; j + 8 <= n; j += 8) {
      f16x8 h = *(const f16x8*)(AAh + ro + j);
      f16x8 l = *(const f16x8*)(AAl + ro + j);
#pragma unroll
      for (int q = 0; q < 8; ++q) qm = fmaf(pvs[j + q], rc8q(h, l, q), qm);
    }
    for (; j < n; ++j) qm = fmaf(pvs[j], rc(AAh[ro + j], AAl[ro + j]), qm);
  }
  red[t] = (t < n) ? qm * pvs[t] : 0.f;
  __syncthreads();
  for (int s2 = 256; s2 > 0; s2 >>= 1) { if (t < s2) red[t] += red[t + s2]; __syncthreads(); }
  if (t == 0) {
    float a = red[0];
    float d3 = a * (float)n3;
    sc[b * 16 + 2] = a;
    sc[b * 16 + 3] = d3;
    sc[b * 16 + 4] = (d3 > 0.f) ? (1.f / sqrtf(d3)) : 0.f;
  }
}

__global__ __launch_bounds__(256)
void readout_rank1_kernel(const float* __restrict__ vals, const float* __restrict__ xcr,
                          float* __restrict__ xs, int k) {
  int b = blockIdx.x, t = threadIdx.x;
  __shared__ float red[256];
  red[t] = (t < k) ? vals[b * 256 + t] : 0.f;
  __syncthreads();
  for (int s = 128; s > 0; s >>= 1) { if (t < s) red[t] += red[t + s]; __syncthreads(); }
  float sv = red[0] / (float)k;
  float vmax = vals[b * 256], vmin = vals[b * 256 + k - 1];
#pragma unroll
  for (int r = 0; r < 2; ++r) {
    int c = t + r * 256;
    float x = xcr[b * 512 + c];
    xs[b * 1024 + c] += sv * x;
    xs[b * 1024 + 512 + c] += (x >= 0.f ? vmax : vmin) * x;
  }
}

__global__ void gat3scal_kernel(const float* __restrict__ h, const float* __restrict__ adst,
                                const float* __restrict__ asrc, float* __restrict__ sc) {
  int b = blockIdx.x, lane = threadIdx.x;
  float a1 = 0.f, a2 = 0.f;
  for (int c = lane; c < CH; c += 64) {
    float x = h[b * 512 + c];
    a1 = fmaf(x, adst[c], a1); a2 = fmaf(x, asrc[c], a2);
  }
  a1 = warp_sum_f(a1); a2 = warp_sum_f(a2);
  if (lane == 0) { sc[b * 16 + 0] = a1; sc[b * 16 + 1] = a2; }
}

__global__ __launch_bounds__(256)
void gatw_kernel(const float* __restrict__ vals, const float* __restrict__ sc,
                 float* __restrict__ wv, int n) {
  int b = blockIdx.y, i = blockIdx.x, t = threadIdx.x;
  __shared__ float red[256];
  __shared__ float red2[256];
  float hd = sc[b * 16 + 0], hs = sc[b * 16 + 1];
  float si = vals[b * 256 + i] * hd;
  float z = -1e30f, vj = 0.f;
  if (t < n) {
    vj = vals[b * 256 + t];
    float zz = si + vj * hs;
    z = (zz > 0.f) ? zz : 0.2f * zz;
  }
  red[t] = z; __syncthreads();
  for (int s = 128; s > 0; s >>= 1) { if (t < s) red[t] = fmaxf(red[t], red[t + s]); __syncthreads(); }
  float mx = red[0]; __syncthreads();
  float e = (t < n) ? expf(z - mx) : 0.f;
  red[t] = e; red2[t] = e * vj; __syncthreads();
  for (int s = 128; s > 0; s >>= 1) {
    if (t < s) { red[t] += red[t + s]; red2[t] += red2[t + s]; }
    __syncthreads();
  }
  if (t == 0) wv[b * 256 + i] = red2[0] / red[0];
}

__global__ void xgat_kernel(const float* __restrict__ wv, const float* __restrict__ h,
                            const float* __restrict__ cb, f16* __restrict__ Xh,
                            f16* __restrict__ Xl) {
  int b = blockIdx.y, i = blockIdx.x, t = threadIdx.x;
  float w_ = wv[b * 256 + i];
#pragma unroll
  for (int r = 0; r < 2; ++r) {
    int c = t + r * 256;
    float v = fmaxf(w_ * h[b * 512 + c] + cb[c], 0.f);
    f16 hh, ll; split1(v, hh, ll);
    long o = (long)b * BSC + (long)i * LDC + c;
    Xh[o] = hh; Xl[o] = ll;
  }
}

// ---- fused layer-3 pool: colsum(H)->xpr, pv=1/n, colmean(X)->xc2, fit3, readout ----
__global__ __launch_bounds__(512)
void pool3_kernel(const f16* __restrict__ Hh, const f16* __restrict__ Hl,
                  const f16* __restrict__ Xh, const f16* __restrict__ Xl,
                  const float* __restrict__ sc, const float* __restrict__ gb,
                  const float* __restrict__ w1, const float* __restrict__ w2,
                  const float* __restrict__ w3, const float* __restrict__ leb1,
                  float* __restrict__ xs, int n) {
  int b = blockIdx.x, t = threadIdx.x;
  int cg = t >> 3, rl = t & 7, c0c = cg * 8;
  long baseC = (long)b * BSC;
  __shared__ float red[512];
  __shared__ float xc2[512];

  // colmean of X (pool softmax logits are identical -> pv = 1/n exactly)
  float s8[8];
#pragma unroll
  for (int q = 0; q < 8; ++q) s8[q] = 0.f;
  for (int j = rl; j < n; j += 8) {
    f16x8 h = *(const f16x8*)(Xh + baseC + (long)j * LDC + c0c);
    f16x8 l = *(const f16x8*)(Xl + baseC + (long)j * LDC + c0c);
#pragma unroll
    for (int q = 0; q < 8; ++q) s8[q] += rc8q(h, l, q);
  }
#pragma unroll
  for (int d = 1; d < 8; d <<= 1)
#pragma unroll
    for (int q = 0; q < 8; ++q) s8[q] += __shfl_xor(s8[q], d);
  float invn = 1.f / (float)n;
  if (rl == 0) {
#pragma unroll
    for (int q = 0; q < 8; ++q) xc2[c0c + q] = s8[q] * invn;
  }
  __syncthreads();

  // fit3 dots on xc2
  float x2 = xc2[t];
  red[t] = x2 * w1[t]; __syncthreads();
  for (int s2 = 256; s2 > 0; s2 >>= 1) { if (t < s2) red[t] += red[t + s2]; __syncthreads(); }
  float a1 = red[0]; __syncthreads();
  red[t] = x2 * w2[t]; __syncthreads();
  for (int s2 = 256; s2 > 0; s2 >>= 1) { if (t < s2) red[t] += red[t + s2]; __syncthreads(); }
  float a2 = red[0]; __syncthreads();
  red[t] = x2 * w3[t]; __syncthreads();
  for (int s2 = 256; s2 > 0; s2 >>= 1) { if (t < s2) red[t] += red[t + s2]; __syncthreads(); }
  float a3 = red[0]; __syncthreads();

  float alpha = sc[b * 16 + 2], deg3 = sc[b * 16 + 3];
  float sub = 0.f;
  for (int j = 0; j < n; ++j) sub += alpha * a3;
  float z = a1 + leb1[0] + a2 * deg3 - sub;
  float fv = 1.f / (1.f + expf(-z));
  // readout (all rows identical = fv * xc2)
  xs[b * 1024 + t] += fv * x2;
  xs[b * 1024 + 512 + t] += fv * x2;
  (void)Hh; (void)Hl; (void)gb;
}

// xpr = d*(al*(d*colsum(H))) + gcn_b; then only feeds the (uniform) pool -> unused;
// BUT sc (alpha/deg3) is needed by fit3, computed in pool2. H colsum feeds nothing else.
// (kept minimal: pool3 above doesn't need H at all since pv is uniform and xpr only fed pv.)

// ---------------- host orchestration ----------------
extern "C" void kernel_launch(void* const* d_in, const int* in_sizes, int n_in,
                              void* d_out, int out_size, void* d_ws, size_t ws_size,
                              hipStream_t stream) {
  (void)in_sizes; (void)n_in; (void)out_size;
  const int*   x_ids  = (const int*)  d_in[0];
  const float* adj    = (const float*)d_in[2];
  const float* emb    = (const float*)d_in[3];
  const float* conv_W = (const float*)d_in[4];
  const float* conv_b = (const float*)d_in[5];
  const float* att_src= (const float*)d_in[6];
  const float* att_dst= (const float*)d_in[7];
  const float* q_W    = (const float*)d_in[8];
  const float* q_b    = (const float*)d_in[9];
  const float* att_w  = (const float*)d_in[10];
  const float* att_b  = (const float*)d_in[11];
  const float* gcn_W  = (const float*)d_in[12];
  const float* gcn_b  = (const float*)d_in[13];
  const float* le_W1  = (const float*)d_in[14];
  const float* le_b1  = (const float*)d_in[15];
  const float* le_W2  = (const float*)d_in[16];
  const float* le_W3  = (const float*)d_in[17];
  const float* lin1_W = (const float*)d_in[18];
  const float* lin1_b = (const float*)d_in[19];
  const float* lin2_W = (const float*)d_in[20];
  const float* lin2_b = (const float*)d_in[21];
  float* out = (float*)d_out;

  const size_t WN_CONV = 3u * CH * CH;
  const size_t WN_GCN  = 3u * CH * CH;
  const size_t WN_L1   = (size_t)(2 * CH) * CH;
  const size_t WN_L2   = (size_t)CH * 511;
  const size_t WTOT    = WN_CONV + WN_GCN + WN_L1 + WN_L2;

  const size_t per_b  = (size_t)(3 * BSC * 4 + 2 * BS2 * 4 + 11 * 256 * 4
                                 + (4 * 512 + 2 * 256 + 16) * 4 + 4096);
  const size_t fixedb = (size_t)(3 * 512 + 64 + NB * 1024 + NB * 512) * 4
                      + WTOT * 4 + (size_t)NB * 1024 * 4 + (size_t)NB * 512 * 4;
  const size_t slack  = 64 * 512;
  int bc = 4;
  for (int cand = 256; cand >= 4; cand >>= 1) {
    if ((size_t)cand * per_b + fixedb + slack <= ws_size) { bc = cand; break; }
  }
  const int nchunks = NB / bc;

  char* w = (char*)d_ws;
  auto alloc = [&](size_t bytes) { char* p = w; w += (bytes + 255) & ~(size_t)255; return p; };
  // fixed
  float* xs   = (float*)alloc(sizeof(float) * NB * 1024);
  float* vvec = (float*)alloc(sizeof(float) * 3 * CH);
  float* c0   = (float*)alloc(256);
  f16*   Wh   = (f16*)alloc(WTOT * 2);
  f16*   Wl   = (f16*)alloc(WTOT * 2);
  f16*   XSh  = (f16*)alloc((size_t)NB * 1024 * 2);
  f16*   XSl  = (f16*)alloc((size_t)NB * 1024 * 2);
  f16*   FHh  = (f16*)alloc((size_t)NB * 512 * 2);
  f16*   FHl  = (f16*)alloc((size_t)NB * 512 * 2);
  // chunk-local
  f16* Xh  = (f16*)alloc((size_t)bc * BSC * 2);
  f16* Xl  = (f16*)alloc((size_t)bc * BSC * 2);
  f16* Hh  = (f16*)alloc((size_t)bc * BSC * 2);
  f16* Hl  = (f16*)alloc((size_t)bc * BSC * 2);
  f16* XPh = (f16*)alloc((size_t)bc * BSC * 2);
  f16* XPl = (f16*)alloc((size_t)bc * BSC * 2);
  f16* Ph  = (f16*)alloc((size_t)bc * BS2 * 2);
  f16* Pl  = (f16*)alloc((size_t)bc * BS2 * 2);
  f16* AAh = (f16*)alloc((size_t)bc * BS2 * 2);
  f16* AAl = (f16*)alloc((size_t)bc * BS2 * 2);
  float* si   = (float*)alloc(sizeof(float) * bc * NMAX);
  float* sj   = (float*)alloc(sizeof(float) * bc * NMAX);
  float* deg  = (float*)alloc(sizeof(float) * bc * NMAX);
  float* dinv = (float*)alloc(sizeof(float) * bc * NMAX);
  float* t1   = (float*)alloc(sizeof(float) * bc * NMAX);
  float* t2   = (float*)alloc(sizeof(float) * bc * NMAX);
  float* t3   = (float*)alloc(sizeof(float) * bc * NMAX);
  float* fit  = (float*)alloc(sizeof(float) * bc * NMAX);
  float* vals = (float*)alloc(sizeof(float) * bc * NMAX);
  int*   perm = (int*)  alloc(sizeof(int)   * bc * NMAX);
  float* sifu = (float*)alloc(sizeof(float) * bc);
  float* wv   = (float*)alloc(sizeof(float) * bc * 256);
  float* xcr  = (float*)alloc(sizeof(float) * bc * 512);
  float* h3   = (float*)alloc(sizeof(float) * bc * 512);
  float* sc   = (float*)alloc(sizeof(float) * bc * 16);
  f16* xcrh   = (f16*)alloc((size_t)bc * 512 * 2);
  f16* xcrl   = (f16*)alloc((size_t)bc * 512 * 2);

  f16* cwh = Wh;                       f16* cwl = Wl;
  f16* gwh = Wh + WN_CONV;             f16* gwl = Wl + WN_CONV;
  f16* l1h = Wh + WN_CONV + WN_GCN;    f16* l1l = Wl + WN_CONV + WN_GCN;
  f16* l2h = l1h + WN_L1;              f16* l2l = l1l + WN_L1;

  hipMemsetAsync(xs, 0, sizeof(float) * NB * 1024, stream);

  for (int l = 0; l < 3; ++l) {
    presplit_kernel<<<512, 256, 0, stream>>>(conv_W + (size_t)l * CH * CH,
                                             cwh + (size_t)l * CH * CH,
                                             cwl + (size_t)l * CH * CH, CH, CH);
    presplit_kernel<<<512, 256, 0, stream>>>(gcn_W + (size_t)l * CH * CH,
                                             gwh + (size_t)l * CH * CH,
                                             gwl + (size_t)l * CH * CH, CH, CH);
    vq_kernel<<<513, 64, 0, stream>>>(q_W + (size_t)l * CH * CH, q_b + l * CH,
                                      att_w + (size_t)l * 2 * CH, vvec + l * CH, c0 + l);
  }
  presplit_kernel<<<512, 256, 0, stream>>>(lin1_W, l1h, l1l, 2 * CH, CH);
  presplit_kernel<<<511, 256, 0, stream>>>(lin2_W, l2h, l2l, CH, 511);

  for (int ch = 0; ch < nchunks; ++ch) {
    const int b0 = ch * bc;
    const int*   ids_c = x_ids + (size_t)b0 * NMAX;
    const float* adj_c = adj + (size_t)b0 * BS2;
    float*       xs_c  = xs + (size_t)b0 * 1024;

    build_a_deg_kernel<<<dim3(NMAX, bc), 256, 0, stream>>>(adj_c, AAh, AAl, deg, dinv);
    embed_kernel<<<dim3(NMAX, bc), 128, 0, stream>>>(ids_c, emb, Xh, Xl);

    // ================= layer 1 (full, masked) =================
    {
      const int n = 256, kk = 205, mt = 2;
      const float* aw = att_w;
      pgemm_kernel<0><<<dim3(4, mt, bc), 256, 0, stream>>>(
          Xh, Xl, BSC, LDC, cwh, cwl, 0, CH,
          Hh, Hl, nullptr, BSC, LDC, nullptr, nullptr, n, CH, CH, 8);
      rowdot_kernel<<<dim3(n, bc), 64, 0, stream>>>(Hh, Hl, att_dst, att_src, si, sj, 2);
      softmax_kernel<<<dim3(n, bc), 256, 0, stream>>>(AAh, AAl, si, sj, nullptr, Ph, Pl, n, 1);
      pgemm_kernel<1><<<dim3(4, mt, bc), 256, 0, stream>>>(
          Ph, Pl, BS2, LD2, Hh, Hl, BSC, LDC,
          Xh, Xl, nullptr, BSC, LDC, conv_b, nullptr, n, CH, n, 1 | 2 | 8);
      pgemm_kernel<0><<<dim3(4, mt, bc), 256, 0, stream>>>(
          Xh, Xl, BSC, LDC, gwh, gwl, 0, CH,
          Hh, Hl, nullptr, BSC, LDC, nullptr, dinv, n, CH, CH, 4 | 8);
      pgemm_kernel<1><<<dim3(4, mt, bc), 256, 0, stream>>>(
          AAh, AAl, BS2, LD2, Hh, Hl, BSC, LDC,
          XPh, XPl, nullptr, BSC, LDC, gcn_b, dinv, n, CH, n, 1 | 4 | 8);
      rowdot_kernel<<<dim3(n, bc), 64, 0, stream>>>(XPh, XPl, aw + CH, nullptr, sj, nullptr, 1);
      colmax_kernel<<<bc, 512, 0, stream>>>(XPh, XPl, vvec, c0, sifu, n);
      nbrdot_kernel<<<dim3(n, bc), 256, 0, stream>>>(AAh, AAl, XPh, XPl, vvec, c0, sifu, si, n);
      softmax_kernel<<<dim3(n, bc), 256, 0, stream>>>(AAh, AAl, si, sj, att_b, Ph, Pl, n, 1);
      pgemm_kernel<1><<<dim3(4, mt, bc), 256, 0, stream>>>(
          Ph, Pl, BS2, LD2, Xh, Xl, BSC, LDC,
          Hh, Hl, nullptr, BSC, LDC, nullptr, nullptr, n, CH, n, 8);  // xc
      rowdot_kernel<<<dim3(n, bc), 64, 0, stream>>>(Hh, Hl, le_W1, le_W2, t1, t2, 2);
      rowdot_kernel<<<dim3(n, bc), 64, 0, stream>>>(Hh, Hl, le_W3, nullptr, t3, nullptr, 1);
      fit_kernel<<<dim3(n, bc), 64, 0, stream>>>(AAh, AAl, t1, t2, t3, deg, le_b1, fit, n);
      topk_kernel<<<bc, 256, 0, stream>>>(fit, perm, vals, n, kk);
      gather_kernel<<<dim3(kk, bc), 256, 0, stream>>>(Hh, Hl, Ph, Pl, perm, vals,
                                                      Xh, Xl, XPh, XPl, n);
      pgemm_kernel<0><<<dim3(2, 2, bc), 256, 0, stream>>>(
          XPh, XPl, BSC, LD2, AAh, AAl, BS2, LD2,
          Ph, Pl, nullptr, BS2, LD2, nullptr, nullptr, kk, n, n, 8);          // SA
      pgemm_kernel<0><<<dim3(2, 2, bc), 256, 0, stream>>>(
          Ph, Pl, BS2, LD2, XPh, XPl, BSC, LD2,
          AAh, AAl, nullptr, BS2, LD2, nullptr, nullptr, kk, kk, n, 8);       // A_new
      degfix_kernel<<<dim3(kk, bc), 256, 0, stream>>>(AAh, AAl, deg, dinv, kk);
      readout_kernel<<<dim3(2, bc), 256, 0, stream>>>(Xh, Xl, xs_c, kk);
    }

    // ================= layer 2 (dense mask; pool collapsed+fused) =================
    {
      const int n = 205, kk = 164, mt = 2;
      const float* aw = att_w + (size_t)2 * CH;
      pgemm_kernel<0><<<dim3(4, mt, bc), 256, 0, stream>>>(
          Xh, Xl, BSC, LDC, cwh + (size_t)CH * CH, cwl + (size_t)CH * CH, 0, CH,
          Hh, Hl, nullptr, BSC, LDC, nullptr, nullptr, n, CH, CH, 8);
      rowdot_kernel<<<dim3(n, bc), 64, 0, stream>>>(Hh, Hl, att_dst + CH, att_src + CH, si, sj, 2);
      softmax_kernel<<<dim3(n, bc), 256, 0, stream>>>(AAh, AAl, si, sj, nullptr, Ph, Pl, n, 0);
      pgemm_kernel<1><<<dim3(4, mt, bc), 256, 0, stream>>>(
          Ph, Pl, BS2, LD2, Hh, Hl, BSC, LDC,
          Xh, Xl, nullptr, BSC, LDC, conv_b + CH, nullptr, n, CH, n, 1 | 2 | 8);
      pgemm_kernel<0><<<dim3(4, mt, bc), 256, 0, stream>>>(
          Xh, Xl, BSC, LDC, gwh + (size_t)CH * CH, gwl + (size_t)CH * CH, 0, CH,
          Hh, Hl, nullptr, BSC, LDC, nullptr, dinv, n, CH, CH, 4 | 8);
      pgemm_kernel<1><<<dim3(4, mt, bc), 256, 0, stream>>>(
          AAh, AAl, BS2, LD2, Hh, Hl, BSC, LDC,
          XPh, XPl, nullptr, BSC, LDC, gcn_b + CH, dinv, n, CH, n, 1 | 4 | 8);
      rowdot_kernel<<<dim3(n, bc), 64, 0, stream>>>(XPh, XPl, aw + CH, nullptr, sj, nullptr, 1);
      pool2_kernel<<<bc, 512, 0, stream>>>(
          XPh, XPl, Xh, Xl, AAh, AAl, sj, vvec + CH, c0 + 1, att_b + 1,
          le_W1 + CH, le_W2 + CH, le_W3 + CH, xcr, xcrh, xcrl, t1, t2, t3, sc, n, kk);
      fit_kernel<<<dim3(n, bc), 64, 0, stream>>>(AAh, AAl, t1, t2, t3, deg, le_b1 + 1, fit, n);
      topk_kernel<<<bc, 256, 0, stream>>>(fit, perm, vals, n, kk);
      readout_rank1_kernel<<<bc, 256, 0, stream>>>(vals, xcr, xs_c, kk);
    }

    // ================= layer 3 (rank-1 X; fused) =================
    {
      const int n = 164, mt = 2;
      // h3 = xcr @ Wc3 (single small GEMM over all bc graphs)
      pgemm_kernel<0><<<dim3(4, 1, 1), 256, 0, stream>>>(
          xcrh, xcrl, 0, 512, cwh + (size_t)2 * CH * CH, cwl + (size_t)2 * CH * CH, 0, CH,
          nullptr, nullptr, h3, 0, 512, nullptr, nullptr, bc, CH, CH, 16);
      gat3scal_kernel<<<bc, 64, 0, stream>>>(h3, att_dst + 2 * CH, att_src + 2 * CH, sc);
      gatw_kernel<<<dim3(n, bc), 256, 0, stream>>>(vals, sc, wv, n);
      xgat_kernel<<<dim3(n, bc), 256, 0, stream>>>(wv, h3, conv_b + 2 * CH, Xh, Xl);
      pool3_kernel<<<bc, 512, 0, stream>>>(
          Hh, Hl, Xh, Xl, sc, gcn_b + 2 * CH,
          le_W1 + 2 * CH, le_W2 + 2 * CH, le_W3 + 2 * CH, le_b1 + 2, xs_c, n);
      (void)mt;
    }
  }

  // ---- final MLP (full batch) ----
  splitbuf_kernel<<<NB, 256, 0, stream>>>(xs, XSh, XSl, 1024);
  pgemm_kernel<0><<<dim3(4, 2, 1), 256, 0, stream>>>(
      XSh, XSl, 0, 1024, l1h, l1l, 0, 1024,
      FHh, FHl, nullptr, 0, CH, lin1_b, nullptr, NB, CH, 2 * CH, 1 | 2 | 8);
  pgemm_kernel<0><<<dim3(4, 2, 1), 256, 0, stream>>>(
      FHh, FHl, 0, CH, l2h, l2l, 0, CH,
      nullptr, nullptr, out, 0, 511, lin2_b, nullptr, NB, 511, CH, 1 | 16);
}

// Round 7
// 3665.445 us; speedup vs baseline: 2.6623x; 1.0433x over previous
//
#include <hip/hip_runtime.h>
#include <math.h>

#define NB   256
#define NMAX 256
#define CH   512
#define LD2  256
#define LDC  512
#define BS2  (256*256)
#define BSC  (256*512)

typedef _Float16 f16;
typedef __attribute__((ext_vector_type(4))) f16 f16x4;
typedef __attribute__((ext_vector_type(8))) f16 f16x8;
typedef __attribute__((ext_vector_type(4))) float f32x4;

#define INV2048 4.8828125e-04f

__device__ __forceinline__ float warp_sum_f(float v) {
#pragma unroll
  for (int m = 32; m >= 1; m >>= 1) v += __shfl_xor(v, m);
  return v;
}

__device__ __forceinline__ void split1(float x, f16& h, f16& l) {
  float xh = (__builtin_fabsf(x) >= 6.103515625e-05f) ? x : 0.f;
  f16 hh = (f16)xh;
  float hf = (float)hh;
  h = hh;
  l = (f16)((x - hf) * 2048.0f);
}

__device__ __forceinline__ float rc(f16 h, f16 l) {
  return (float)h + (float)l * INV2048;
}

__device__ __forceinline__ float rc8q(const f16x8& h, const f16x8& l, int q) {
  return (float)h[q] + (float)l[q] * INV2048;
}

// ---------------- plane GEMM v2: 64x128 tile, 2 blocks/CU, wide staging ----------------
// A: [M][K] planes. B: BMODE 0 -> [N][K] planes; BMODE 1 -> [K][N] planes.
// flags: 1 bias, 2 relu, 4 rowscale, 8 write planes, 16 write f32
template <int BMODE>
__global__ __launch_bounds__(256, 2)
void pgemm_kernel(const f16* __restrict__ Ahp, const f16* __restrict__ Alp, long bsA, int lda,
                  const f16* __restrict__ Bhp, const f16* __restrict__ Blp, long bsB, int ldb,
                  f16* __restrict__ Yh, f16* __restrict__ Yl, float* __restrict__ Yf,
                  long bsY, int ldy,
                  const float* __restrict__ bias, const float* __restrict__ rowscale,
                  int M, int Ncol, int K, int flags)
{
  __shared__ f16 Ah[64][40];
  __shared__ f16 Al[64][40];
  __shared__ f16 Bh[128][40];
  __shared__ f16 Bl[128][40];
  const int b   = blockIdx.z;
  const int i0  = blockIdx.y * 64;
  const int n0  = blockIdx.x * 128;
  const int tid = threadIdx.x;
  const int w  = tid >> 6, l = tid & 63;
  const int wr = (w >> 1) * 32, wc = (w & 1) * 64;
  const int lr = l & 15, lq = l >> 4;
  const f16* Abh = Ahp + (long)b * bsA;
  const f16* Abl = Alp + (long)b * bsA;
  const f16* Bbh = Bhp + (long)b * bsB;
  const f16* Bbl = Blp + (long)b * bsB;

  f32x4 acc1[2][4], acc2[2][4];
#pragma unroll
  for (int mi = 0; mi < 2; ++mi)
#pragma unroll
    for (int ni = 0; ni < 4; ++ni) {
      acc1[mi][ni] = (f32x4){0.f, 0.f, 0.f, 0.f};
      acc2[mi][ni] = (f32x4){0.f, 0.f, 0.f, 0.f};
    }

  const f16x8 z8 = (f16x8){0,0,0,0,0,0,0,0};
  // prefetch registers
  f16x8 rah, ral;              // A: 64 rows x 32 k -> one f16x8 per thread per plane
  f16x8 rbh[2], rbl[2];        // BMODE 0: 128 rows x 32 k -> two per plane
  f16x8 rva, rvb, rwa, rwb;    // BMODE 1

  const int arow = tid >> 2, akq = (tid & 3) * 8;

  auto LOADA = [&](int k0) {
    int gr = i0 + arow, gk = k0 + akq;
    rah = z8; ral = z8;
    if (gr < M) {
      if (gk + 7 < K) {
        rah = *(const f16x8*)(Abh + (long)gr * lda + gk);
        ral = *(const f16x8*)(Abl + (long)gr * lda + gk);
      } else {
#pragma unroll
        for (int j = 0; j < 8; ++j) if (gk + j < K) {
          rah[j] = Abh[(long)gr * lda + gk + j];
          ral[j] = Abl[(long)gr * lda + gk + j];
        }
      }
    }
  };
  auto STOREA = [&]() {
    *(f16x8*)&Ah[arow][akq] = rah;
    *(f16x8*)&Al[arow][akq] = ral;
  };
  auto LOADB = [&](int k0) {
    if (BMODE == 0) {
#pragma unroll
      for (int rep = 0; rep < 2; ++rep) {
        int idx = rep * 256 + tid;
        int c = idx >> 2, kq = (idx & 3) * 8;
        int gc = n0 + c, gk = k0 + kq;
        rbh[rep] = z8; rbl[rep] = z8;
        if (gc < Ncol) {
          if (gk + 7 < K) {
            rbh[rep] = *(const f16x8*)(Bbh + (long)gc * ldb + gk);
            rbl[rep] = *(const f16x8*)(Bbl + (long)gc * ldb + gk);
          } else {
#pragma unroll
            for (int j = 0; j < 8; ++j) if (gk + j < K) {
              rbh[rep][j] = Bbh[(long)gc * ldb + gk + j];
              rbl[rep][j] = Bbl[(long)gc * ldb + gk + j];
            }
          }
        }
      }
    } else {
      // k-major lane assignment: 16 consecutive lanes span 16 k-pairs (bank-friendly stores)
      int c8  = (tid >> 4) * 8;
      int k0p = (tid & 15) * 2;
      int gc = n0 + c8;
      rva = z8; rvb = z8; rwa = z8; rwb = z8;
      int gka = k0 + k0p, gkb = gka + 1;
      if (gc + 7 < Ncol) {
        if (gka < K) { rva = *(const f16x8*)(Bbh + (long)gka * ldb + gc);
                       rwa = *(const f16x8*)(Bbl + (long)gka * ldb + gc); }
        if (gkb < K) { rvb = *(const f16x8*)(Bbh + (long)gkb * ldb + gc);
                       rwb = *(const f16x8*)(Bbl + (long)gkb * ldb + gc); }
      }
    }
  };
  auto STOREB = [&]() {
    if (BMODE == 0) {
#pragma unroll
      for (int rep = 0; rep < 2; ++rep) {
        int idx = rep * 256 + tid;
        int c = idx >> 2, kq = (idx & 3) * 8;
        *(f16x8*)&Bh[c][kq] = rbh[rep];
        *(f16x8*)&Bl[c][kq] = rbl[rep];
      }
    } else {
      int c8  = (tid >> 4) * 8;
      int k0p = (tid & 15) * 2;
#pragma unroll
      for (int j = 0; j < 8; ++j) {
        union { f16 f[2]; unsigned u; } ph, pl;
        ph.f[0] = rva[j]; ph.f[1] = rvb[j];
        pl.f[0] = rwa[j]; pl.f[1] = rwb[j];
        *(unsigned*)&Bh[c8 + j][k0p] = ph.u;
        *(unsigned*)&Bl[c8 + j][k0p] = pl.u;
      }
    }
  };

  const int nk = (K + 31) / 32;
  LOADA(0); LOADB(0);
  for (int ki = 0; ki < nk; ++ki) {
    STOREA(); STOREB();
    __syncthreads();
    if (ki + 1 < nk) { LOADA((ki + 1) * 32); LOADB((ki + 1) * 32); }

    f16x8 bh[4], bl[4];
#pragma unroll
    for (int ni = 0; ni < 4; ++ni) {
      bh[ni] = *(const f16x8*)&Bh[wc + ni * 16 + lr][lq * 8];
      bl[ni] = *(const f16x8*)&Bl[wc + ni * 16 + lr][lq * 8];
    }
#pragma unroll
    for (int mi = 0; mi < 2; ++mi) {
      f16x8 ah = *(const f16x8*)&Ah[wr + mi * 16 + lr][lq * 8];
      f16x8 al = *(const f16x8*)&Al[wr + mi * 16 + lr][lq * 8];
#pragma unroll
      for (int ni = 0; ni < 4; ++ni) {
        acc1[mi][ni] = __builtin_amdgcn_mfma_f32_16x16x32_f16(ah, bh[ni], acc1[mi][ni], 0, 0, 0);
        acc2[mi][ni] = __builtin_amdgcn_mfma_f32_16x16x32_f16(ah, bl[ni], acc2[mi][ni], 0, 0, 0);
        acc2[mi][ni] = __builtin_amdgcn_mfma_f32_16x16x32_f16(al, bh[ni], acc2[mi][ni], 0, 0, 0);
      }
    }
    __syncthreads();
  }

  // epilogue: col = lane&15, row = (lane>>4)*4 + reg
#pragma unroll
  for (int mi = 0; mi < 2; ++mi) {
#pragma unroll
    for (int ni = 0; ni < 4; ++ni) {
      int col = n0 + wc + ni * 16 + lr;
      if (col >= Ncol) continue;
      float bv = (flags & 1) ? bias[col] : 0.f;
#pragma unroll
      for (int r = 0; r < 4; ++r) {
        int row = i0 + wr + mi * 16 + lq * 4 + r;
        if (row >= M) continue;
        float vv = acc1[mi][ni][r] + acc2[mi][ni][r] * INV2048;
        if (flags & 4) vv *= rowscale[b * 256 + row];
        vv += bv;
        if (flags & 2) vv = fmaxf(vv, 0.f);
        long off = (long)b * bsY + (long)row * ldy + col;
        if (flags & 8) { f16 h, lo; split1(vv, h, lo); Yh[off] = h; Yl[off] = lo; }
        if (flags & 16) Yf[off] = vv;
      }
    }
  }
}

__global__ void presplit_kernel(const float* __restrict__ W, f16* __restrict__ Wh,
                                f16* __restrict__ Wl, int K, int N) {
  int n = blockIdx.x;
  for (int k = threadIdx.x; k < K; k += blockDim.x) {
    f16 h, l; split1(W[(long)k * N + n], h, l);
    Wh[(long)n * K + k] = h;
    Wl[(long)n * K + k] = l;
  }
}

__global__ void splitbuf_kernel(const float* __restrict__ X, f16* __restrict__ Xh,
                                f16* __restrict__ Xl, int cols) {
  int i = blockIdx.x;
  for (int c = threadIdx.x; c < cols; c += blockDim.x) {
    f16 h, l; split1(X[(long)i * cols + c], h, l);
    Xh[(long)i * cols + c] = h;
    Xl[(long)i * cols + c] = l;
  }
}

// ---------------- layer-1 small kernels ----------------
__global__ void build_a_deg_kernel(const float* __restrict__ adj, f16* __restrict__ AAh,
                                   f16* __restrict__ AAl, float* __restrict__ deg,
                                   float* __restrict__ dinv) {
  int b = blockIdx.y, i = blockIdx.x, j = threadIdx.x;
  __shared__ float red[256];
  float v = adj[(long)b * BS2 + i * 256 + j];
  if (i == j) v = fmaxf(v, 1.f);
  f16 h, l; split1(v, h, l);
  long o = (long)b * BS2 + i * 256 + j;
  AAh[o] = h; AAl[o] = l;
  red[j] = v; __syncthreads();
  for (int s = 128; s > 0; s >>= 1) { if (j < s) red[j] += red[j + s]; __syncthreads(); }
  if (j == 0) {
    float s = red[0];
    deg[b * 256 + i] = s;
    dinv[b * 256 + i] = (s > 0.f) ? (1.f / sqrtf(s)) : 0.f;
  }
}

__global__ void embed_kernel(const int* __restrict__ ids, const float* __restrict__ emb,
                             f16* __restrict__ Xh, f16* __restrict__ Xl) {
  int b = blockIdx.y, i = blockIdx.x, t = threadIdx.x;
  int id = ids[b * NMAX + i];
  float4 v = *(const float4*)(emb + (long)id * CH + t * 4);
  long o = (long)b * BSC + (long)i * LDC + t * 4;
  float vv[4] = {v.x, v.y, v.z, v.w};
#pragma unroll
  for (int j = 0; j < 4; ++j) { f16 h, l; split1(vv[j], h, l); Xh[o + j] = h; Xl[o + j] = l; }
}

__global__ void rowdot_kernel(const f16* __restrict__ Xh, const f16* __restrict__ Xl,
                              const float* __restrict__ v1, const float* __restrict__ v2,
                              const float* __restrict__ v3,
                              float* __restrict__ o1, float* __restrict__ o2,
                              float* __restrict__ o3, int nvec) {
  int b = blockIdx.y, i = blockIdx.x, lane = threadIdx.x;
  long base = (long)b * BSC + (long)i * LDC;
  float a1 = 0.f, a2 = 0.f, a3 = 0.f;
  for (int c = lane; c < CH; c += 64) {
    float x = rc(Xh[base + c], Xl[base + c]);
    a1 = fmaf(x, v1[c], a1);
    if (nvec > 1) a2 = fmaf(x, v2[c], a2);
    if (nvec > 2) a3 = fmaf(x, v3[c], a3);
  }
  a1 = warp_sum_f(a1);
  if (nvec > 1) a2 = warp_sum_f(a2);
  if (nvec > 2) a3 = warp_sum_f(a3);
  if (lane == 0) {
    o1[b * 256 + i] = a1;
    if (nvec > 1) o2[b * 256 + i] = a2;
    if (nvec > 2) o3[b * 256 + i] = a3;
  }
}

__global__ void vq_kernel(const float* __restrict__ qW, const float* __restrict__ qb,
                          const float* __restrict__ aw, float* __restrict__ v,
                          float* __restrict__ c0) {
  int blk = blockIdx.x, lane = threadIdx.x;
  if (blk < 512) {
    float s = 0.f;
    for (int j = lane; j < CH; j += 64) s = fmaf(qW[(long)blk * CH + j], aw[j], s);
    s = warp_sum_f(s);
    if (lane == 0) v[blk] = s;
  } else {
    float s = 0.f;
    for (int j = lane; j < CH; j += 64) s = fmaf(qb[j], aw[j], s);
    s = warp_sum_f(s);
    if (lane == 0) c0[0] = s;
  }
}

__global__ __launch_bounds__(256)
void softmax_kernel(const f16* __restrict__ AAh, const f16* __restrict__ AAl,
                    const float* __restrict__ si, const float* __restrict__ sj,
                    const float* __restrict__ attb,
                    f16* __restrict__ Ph, f16* __restrict__ Pl, int n, int masked) {
  int b = blockIdx.y, i = blockIdx.x, j = threadIdx.x;
  __shared__ float red[256];
  float logit = -1e30f, e = 0.f;
  float siv = si[b * 256 + i];
  long ro = (long)b * BS2 + i * 256;
  if (j < n) {
    float z = siv + sj[b * 256 + j] + (attb ? attb[0] : 0.f);
    z = (z > 0.f) ? z : 0.2f * z;
    if (masked) {
      float a = rc(AAh[ro + j], AAl[ro + j]);
      logit = (a > 0.f) ? z : -1e9f;
    } else logit = z;
  }
  red[j] = logit; __syncthreads();
  for (int s = 128; s > 0; s >>= 1) { if (j < s) red[j] = fmaxf(red[j], red[j + s]); __syncthreads(); }
  float mx = red[0]; __syncthreads();
  if (j < n) e = expf(logit - mx);
  red[j] = e; __syncthreads();
  for (int s = 128; s > 0; s >>= 1) { if (j < s) red[j] += red[j + s]; __syncthreads(); }
  float sum = red[0];
  if (j < n) {
    f16 h, l; split1(e / sum, h, l);
    Ph[ro + j] = h; Pl[ro + j] = l;
  }
}

__global__ __launch_bounds__(512)
void colmax_kernel(const f16* __restrict__ XPh, const f16* __restrict__ XPl,
                   const float* __restrict__ v, const float* __restrict__ c0,
                   float* __restrict__ si_full, int n) {
  int b = blockIdx.x, t = threadIdx.x;
  int cg = t >> 3, rl = t & 7, c0c = cg * 8;
  long base = (long)b * BSC;
  __shared__ float red[64];
  float m[8];
#pragma unroll
  for (int q = 0; q < 8; ++q) m[q] = -1e9f;
  for (int j = rl; j < n; j += 8) {
    f16x8 h = *(const f16x8*)(XPh + base + (long)j * LDC + c0c);
    f16x8 l = *(const f16x8*)(XPl + base + (long)j * LDC + c0c);
#pragma unroll
    for (int q = 0; q < 8; ++q) m[q] = fmaxf(m[q], rc8q(h, l, q));
  }
#pragma unroll
  for (int d = 1; d < 8; d <<= 1)
#pragma unroll
    for (int q = 0; q < 8; ++q) m[q] = fmaxf(m[q], __shfl_xor(m[q], d));
  if (rl == 0) {
    float p = 0.f;
#pragma unroll
    for (int q = 0; q < 8; ++q) p = fmaf(m[q], v[c0c + q], p);
    red[cg] = p;
  }
  __syncthreads();
  for (int s = 32; s > 0; s >>= 1) { if (t < s) red[t] += red[t + s]; __syncthreads(); }
  if (t == 0) si_full[b] = red[0] + c0[0];
}

__global__ __launch_bounds__(256)
void nbrdot_kernel(const f16* __restrict__ AAh, const f16* __restrict__ AAl,
                   const f16* __restrict__ XPh, const f16* __restrict__ XPl,
                   const float* __restrict__ v, const float* __restrict__ c0,
                   const float* __restrict__ si_full, float* __restrict__ si, int n) {
  int b = blockIdx.y, i = blockIdx.x, t = threadIdx.x;
  __shared__ int list[256];
  __shared__ int cnt, nmiss;
  __shared__ float red[256];
  if (t == 0) { cnt = 0; nmiss = 0; }
  __syncthreads();
  long ro = (long)b * BS2 + i * 256;
  if (t < n) {
    float a = rc(AAh[ro + t], AAl[ro + t]);
    if (a > 0.f) { int p = atomicAdd(&cnt, 1); list[p] = t; }
    else atomicAdd(&nmiss, 1);
  }
  __syncthreads();
  if (nmiss == 0) {
    if (t == 0) si[b * 256 + i] = si_full[b];
    return;
  }
  int c = cnt;
  long base = (long)b * BSC;
  float m1 = -1e9f, m2 = -1e9f;
  for (int q = 0; q < c; ++q) {
    int j = list[q];
    m1 = fmaxf(m1, rc(XPh[base + (long)j * LDC + t], XPl[base + (long)j * LDC + t]));
    m2 = fmaxf(m2, rc(XPh[base + (long)j * LDC + t + 256], XPl[base + (long)j * LDC + t + 256]));
  }
  red[t] = m1 * v[t] + m2 * v[t + 256];
  __syncthreads();
  for (int s = 128; s > 0; s >>= 1) { if (t < s) red[t] += red[t + s]; __syncthreads(); }
  if (t == 0) si[b * 256 + i] = red[0] + c0[0];
}

__global__ void fit_kernel(const f16* __restrict__ AAh, const f16* __restrict__ AAl,
                           const float* __restrict__ t1, const float* __restrict__ t2,
                           const float* __restrict__ t3,
                           const float* __restrict__ deg, const float* __restrict__ leb1,
                           float* __restrict__ fit, int n) {
  int b = blockIdx.y, i = blockIdx.x, lane = threadIdx.x;
  long ro = (long)b * BS2 + i * 256;
  float s = 0.f;
  for (int j = lane; j < n; j += 64) s = fmaf(rc(AAh[ro + j], AAl[ro + j]), t3[b * 256 + j], s);
  s = warp_sum_f(s);
  if (lane == 0) {
    float z = t1[b * 256 + i] + leb1[0] + t2[b * 256 + i] * deg[b * 256 + i] - s;
    fit[b * 256 + i] = 1.f / (1.f + expf(-z));
  }
}

__global__ __launch_bounds__(256)
void topk_kernel(const float* __restrict__ fit, int* __restrict__ perm,
                 float* __restrict__ vals, int n, int k) {
  __shared__ float v[256];
  __shared__ int ix[256];
  int b = blockIdx.x, t = threadIdx.x;
  v[t] = (t < n) ? fit[b * 256 + t] : -1e30f;
  ix[t] = t;
  __syncthreads();
  for (int size = 2; size <= 256; size <<= 1)
    for (int str = size >> 1; str > 0; str >>= 1) {
      int p = t ^ str;
      if (p > t) {
        bool desc = ((t & size) == 0);
        float v1 = v[t], v2 = v[p]; int i1 = ix[t], i2 = ix[p];
        bool inorder = (v1 > v2) || (v1 == v2 && i1 < i2);
        if (inorder != desc) { v[t] = v2; v[p] = v1; ix[t] = i2; ix[p] = i1; }
      }
      __syncthreads();
    }
  if (t < k) { perm[b * 256 + t] = ix[t]; vals[b * 256 + t] = v[t]; }
}

__global__ __launch_bounds__(256)
void gather_kernel(const f16* __restrict__ Hh, const f16* __restrict__ Hl,
                   const f16* __restrict__ Ph, const f16* __restrict__ Pl,
                   const int* __restrict__ perm, const float* __restrict__ vals,
                   f16* __restrict__ Xh, f16* __restrict__ Xl,
                   f16* __restrict__ Skh, f16* __restrict__ Skl, int n) {
  int b = blockIdx.y, p = blockIdx.x, t = threadIdx.x;
  int src = perm[b * 256 + p];
  float sv = vals[b * 256 + p];
#pragma unroll
  for (int r = 0; r < 2; ++r) {
    int c = t + r * 256;
    long so = (long)b * BSC + (long)src * LDC + c;
    long dof = (long)b * BSC + (long)p * LDC + c;
    float x = rc(Hh[so], Hl[so]) * sv;
    f16 h, l; split1(x, h, l);
    Xh[dof] = h; Xl[dof] = l;
  }
  if (t < n) {
    long so = (long)b * BS2 + src * 256 + t;
    long dof = (long)b * BSC + p * 256 + t;
    Skh[dof] = Ph[so]; Skl[dof] = Pl[so];
  }
}

__global__ void degfix_kernel(f16* __restrict__ AAh, f16* __restrict__ AAl,
                              float* __restrict__ deg, float* __restrict__ dinv, int k) {
  int b = blockIdx.y, i = blockIdx.x, j = threadIdx.x;
  __shared__ float red[256];
  long ro = (long)b * BS2 + i * 256;
  float v = 0.f;
  if (j < k) {
    v = rc(AAh[ro + j], AAl[ro + j]);
    if (j == i && v <= 0.f) {
      v += 1.f;
      f16 h, l; split1(v, h, l);
      AAh[ro + j] = h; AAl[ro + j] = l;
    }
  }
  red[j] = v; __syncthreads();
  for (int s = 128; s > 0; s >>= 1) { if (j < s) red[j] += red[j + s]; __syncthreads(); }
  if (j == 0) {
    float s = red[0];
    deg[b * 256 + i] = s;
    dinv[b * 256 + i] = (s > 0.f) ? (1.f / sqrtf(s)) : 0.f;
  }
}

__global__ __launch_bounds__(256)
void readout_kernel(const f16* __restrict__ Xh, const f16* __restrict__ Xl,
                    float* __restrict__ xs, int k) {
  int b = blockIdx.y, t = threadIdx.x;
  int cg = t >> 3, rl = t & 7;
  int c0c = blockIdx.x * 256 + cg * 8;
  long base = (long)b * BSC;
  float s[8], m[8];
#pragma unroll
  for (int q = 0; q < 8; ++q) { s[q] = 0.f; m[q] = -1e30f; }
  for (int p = rl; p < k; p += 8) {
    f16x8 h = *(const f16x8*)(Xh + base + (long)p * LDC + c0c);
    f16x8 l = *(const f16x8*)(Xl + base + (long)p * LDC + c0c);
#pragma unroll
    for (int q = 0; q < 8; ++q) {
      float v = rc8q(h, l, q);
      s[q] += v; m[q] = fmaxf(m[q], v);
    }
  }
#pragma unroll
  for (int d = 1; d < 8; d <<= 1)
#pragma unroll
    for (int q = 0; q < 8; ++q) {
      s[q] += __shfl_xor(s[q], d);
      m[q] = fmaxf(m[q], __shfl_xor(m[q], d));
    }
  if (rl == 0) {
#pragma unroll
    for (int q = 0; q < 8; ++q) {
      xs[b * 1024 + c0c + q] += s[q] / (float)k;
      xs[b * 1024 + 512 + c0c + q] += m[q];
    }
  }
}

// ---- fused layer-2 pool ----
__global__ __launch_bounds__(512)
void pool2_kernel(const f16* __restrict__ XPh, const f16* __restrict__ XPl,
                  const f16* __restrict__ Xh, const f16* __restrict__ Xl,
                  const f16* __restrict__ AAh, const f16* __restrict__ AAl,
                  const float* __restrict__ sj,
                  const float* __restrict__ v, const float* __restrict__ c0,
                  const float* __restrict__ attb,
                  const float* __restrict__ w1, const float* __restrict__ w2,
                  const float* __restrict__ w3,
                  float* __restrict__ xcr, f16* __restrict__ xcrh, f16* __restrict__ xcrl,
                  float* __restrict__ t1, float* __restrict__ t2, float* __restrict__ t3,
                  float* __restrict__ sc, int n, int n3) {
  int b = blockIdx.x, t = threadIdx.x;
  int cg = t >> 3, rl = t & 7, c0c = cg * 8;
  long baseC = (long)b * BSC;
  __shared__ float red[512];
  __shared__ float pvs[256];
  __shared__ float xcs[512];

  float m[8];
#pragma unroll
  for (int q = 0; q < 8; ++q) m[q] = -1e9f;
  for (int j = rl; j < n; j += 8) {
    f16x8 h = *(const f16x8*)(XPh + baseC + (long)j * LDC + c0c);
    f16x8 l = *(const f16x8*)(XPl + baseC + (long)j * LDC + c0c);
#pragma unroll
    for (int q = 0; q < 8; ++q) m[q] = fmaxf(m[q], rc8q(h, l, q));
  }
#pragma unroll
  for (int d = 1; d < 8; d <<= 1)
#pragma unroll
    for (int q = 0; q < 8; ++q) m[q] = fmaxf(m[q], __shfl_xor(m[q], d));
  if (rl == 0) {
    float p = 0.f;
#pragma unroll
    for (int q = 0; q < 8; ++q) p = fmaf(m[q], v[c0c + q], p);
    red[cg] = p;
  }
  __syncthreads();
  for (int s2 = 32; s2 > 0; s2 >>= 1) { if (t < s2) red[t] += red[t + s2]; __syncthreads(); }
  float sifu = red[0] + c0[0];
  __syncthreads();

  float z = -1e30f;
  if (t < n) {
    float zz = sifu + sj[b * 256 + t] + attb[0];
    z = (zz > 0.f) ? zz : 0.2f * zz;
  }
  red[t] = z; __syncthreads();
  for (int s2 = 256; s2 > 0; s2 >>= 1) { if (t < s2) red[t] = fmaxf(red[t], red[t + s2]); __syncthreads(); }
  float mx = red[0]; __syncthreads();
  float e = (t < n) ? expf(z - mx) : 0.f;
  red[t] = e; __syncthreads();
  for (int s2 = 256; s2 > 0; s2 >>= 1) { if (t < s2) red[t] += red[t + s2]; __syncthreads(); }
  float psum = red[0];
  __syncthreads();
  if (t < 256) pvs[t] = (t < n) ? e / psum : 0.f;
  __syncthreads();

  float s8[8];
#pragma unroll
  for (int q = 0; q < 8; ++q) s8[q] = 0.f;
  for (int j = rl; j < n; j += 8) {
    float w_ = pvs[j];
    f16x8 h = *(const f16x8*)(Xh + baseC + (long)j * LDC + c0c);
    f16x8 l = *(const f16x8*)(Xl + baseC + (long)j * LDC + c0c);
#pragma unroll
    for (int q = 0; q < 8; ++q) s8[q] = fmaf(w_, rc8q(h, l, q), s8[q]);
  }
#pragma unroll
  for (int d = 1; d < 8; d <<= 1)
#pragma unroll
    for (int q = 0; q < 8; ++q) s8[q] += __shfl_xor(s8[q], d);
  if (rl == 0) {
#pragma unroll
    for (int q = 0; q < 8; ++q) {
      float vv = s8[q];
      xcs[c0c + q] = vv;
      xcr[b * 512 + c0c + q] = vv;
      f16 hh, ll; split1(vv, hh, ll);
      xcrh[b * 512 + c0c + q] = hh;
      xcrl[b * 512 + c0c + q] = ll;
    }
  }
  __syncthreads();

  float x_ = xcs[t];
  red[t] = x_ * w1[t]; __syncthreads();
  for (int s2 = 256; s2 > 0; s2 >>= 1) { if (t < s2) red[t] += red[t + s2]; __syncthreads(); }
  float a1 = red[0]; __syncthreads();
  red[t] = x_ * w2[t]; __syncthreads();
  for (int s2 = 256; s2 > 0; s2 >>= 1) { if (t < s2) red[t] += red[t + s2]; __syncthreads(); }
  float a2 = red[0]; __syncthreads();
  red[t] = x_ * w3[t]; __syncthreads();
  for (int s2 = 256; s2 > 0; s2 >>= 1) { if (t < s2) red[t] += red[t + s2]; __syncthreads(); }
  float a3 = red[0]; __syncthreads();
  if (t < n) { t1[b * 256 + t] = a1; t2[b * 256 + t] = a2; t3[b * 256 + t] = a3; }

  float qm = 0.f;
  if (t < n) {
    long ro = (long)b * BS2 + (long)t * 256;
    int j = 0;
    for (; j + 8 <= n; j += 8) {
      f16x8 h = *(const f16x8*)(AAh + ro + j);
      f16x8 l = *(const f16x8*)(AAl + ro + j);
#pragma unroll
      for (int q = 0; q < 8; ++q) qm = fmaf(pvs[j + q], rc8q(h, l, q), qm);
    }
    for (; j < n; ++j) qm = fmaf(pvs[j], rc(AAh[ro + j], AAl[ro + j]), qm);
  }
  red[t] = (t < n) ? qm * pvs[t] : 0.f;
  __syncthreads();
  for (int s2 = 256; s2 > 0; s2 >>= 1) { if (t < s2) red[t] += red[t + s2]; __syncthreads(); }
  if (t == 0) {
    float a = red[0];
    float d3 = a * (float)n3;
    sc[b * 16 + 2] = a;
    sc[b * 16 + 3] = d3;
    sc[b * 16 + 4] = (d3 > 0.f) ? (1.f / sqrtf(d3)) : 0.f;
  }
}

__global__ __launch_bounds__(256)
void readout_rank1_kernel(const float* __restrict__ vals, const float* __restrict__ xcr,
                          float* __restrict__ xs, int k) {
  int b = blockIdx.x, t = threadIdx.x;
  __shared__ float red[256];
  red[t] = (t < k) ? vals[b * 256 + t] : 0.f;
  __syncthreads();
  for (int s = 128; s > 0; s >>= 1) { if (t < s) red[t] += red[t + s]; __syncthreads(); }
  float sv = red[0] / (float)k;
  float vmax = vals[b * 256], vmin = vals[b * 256 + k - 1];
#pragma unroll
  for (int r = 0; r < 2; ++r) {
    int c = t + r * 256;
    float x = xcr[b * 512 + c];
    xs[b * 1024 + c] += sv * x;
    xs[b * 1024 + 512 + c] += (x >= 0.f ? vmax : vmin) * x;
  }
}

__global__ void gat3scal_kernel(const float* __restrict__ h, const float* __restrict__ adst,
                                const float* __restrict__ asrc, float* __restrict__ sc) {
  int b = blockIdx.x, lane = threadIdx.x;
  float a1 = 0.f, a2 = 0.f;
  for (int c = lane; c < CH; c += 64) {
    float x = h[b * 512 + c];
    a1 = fmaf(x, adst[c], a1); a2 = fmaf(x, asrc[c], a2);
  }
  a1 = warp_sum_f(a1); a2 = warp_sum_f(a2);
  if (lane == 0) { sc[b * 16 + 0] = a1; sc[b * 16 + 1] = a2; }
}

__global__ __launch_bounds__(256)
void gatw_kernel(const float* __restrict__ vals, const float* __restrict__ sc,
                 float* __restrict__ wv, int n) {
  int b = blockIdx.y, i = blockIdx.x, t = threadIdx.x;
  __shared__ float red[256];
  __shared__ float red2[256];
  float hd = sc[b * 16 + 0], hs = sc[b * 16 + 1];
  float si = vals[b * 256 + i] * hd;
  float z = -1e30f, vj = 0.f;
  if (t < n) {
    vj = vals[b * 256 + t];
    float zz = si + vj * hs;
    z = (zz > 0.f) ? zz : 0.2f * zz;
  }
  red[t] = z; __syncthreads();
  for (int s = 128; s > 0; s >>= 1) { if (t < s) red[t] = fmaxf(red[t], red[t + s]); __syncthreads(); }
  float mx = red[0]; __syncthreads();
  float e = (t < n) ? expf(z - mx) : 0.f;
  red[t] = e; red2[t] = e * vj; __syncthreads();
  for (int s = 128; s > 0; s >>= 1) {
    if (t < s) { red[t] += red[t + s]; red2[t] += red2[t + s]; }
    __syncthreads();
  }
  if (t == 0) wv[b * 256 + i] = red2[0] / red[0];
}

__global__ void xgat_kernel(const float* __restrict__ wv, const float* __restrict__ h,
                            const float* __restrict__ cb, f16* __restrict__ Xh,
                            f16* __restrict__ Xl) {
  int b = blockIdx.y, i = blockIdx.x, t = threadIdx.x;
  float w_ = wv[b * 256 + i];
#pragma unroll
  for (int r = 0; r < 2; ++r) {
    int c = t + r * 256;
    float v = fmaxf(w_ * h[b * 512 + c] + cb[c], 0.f);
    f16 hh, ll; split1(v, hh, ll);
    long o = (long)b * BSC + (long)i * LDC + c;
    Xh[o] = hh; Xl[o] = ll;
  }
}

__global__ __launch_bounds__(512)
void pool3_kernel(const f16* __restrict__ Hh, const f16* __restrict__ Hl,
                  const f16* __restrict__ Xh, const f16* __restrict__ Xl,
                  const float* __restrict__ sc, const float* __restrict__ gb,
                  const float* __restrict__ w1, const float* __restrict__ w2,
                  const float* __restrict__ w3, const float* __restrict__ leb1,
                  float* __restrict__ xs, int n) {
  int b = blockIdx.x, t = threadIdx.x;
  int cg = t >> 3, rl = t & 7, c0c = cg * 8;
  long baseC = (long)b * BSC;
  __shared__ float red[512];
  __shared__ float xc2[512];

  float s8[8];
#pragma unroll
  for (int q = 0; q < 8; ++q) s8[q] = 0.f;
  for (int j = rl; j < n; j += 8) {
    f16x8 h = *(const f16x8*)(Xh + baseC + (long)j * LDC + c0c);
    f16x8 l = *(const f16x8*)(Xl + baseC + (long)j * LDC + c0c);
#pragma unroll
    for (int q = 0; q < 8; ++q) s8[q] += rc8q(h, l, q);
  }
#pragma unroll
  for (int d = 1; d < 8; d <<= 1)
#pragma unroll
    for (int q = 0; q < 8; ++q) s8[q] += __shfl_xor(s8[q], d);
  float invn = 1.f / (float)n;
  if (rl == 0) {
#pragma unroll
    for (int q = 0; q < 8; ++q) xc2[c0c + q] = s8[q] * invn;
  }
  __syncthreads();

  float x2 = xc2[t];
  red[t] = x2 * w1[t]; __syncthreads();
  for (int s2 = 256; s2 > 0; s2 >>= 1) { if (t < s2) red[t] += red[t + s2]; __syncthreads(); }
  float a1 = red[0]; __syncthreads();
  red[t] = x2 * w2[t]; __syncthreads();
  for (int s2 = 256; s2 > 0; s2 >>= 1) { if (t < s2) red[t] += red[t + s2]; __syncthreads(); }
  float a2 = red[0]; __syncthreads();
  red[t] = x2 * w3[t]; __syncthreads();
  for (int s2 = 256; s2 > 0; s2 >>= 1) { if (t < s2) red[t] += red[t + s2]; __syncthreads(); }
  float a3 = red[0]; __syncthreads();

  float alpha = sc[b * 16 + 2], deg3 = sc[b * 16 + 3];
  float sub = 0.f;
  for (int j = 0; j < n; ++j) sub += alpha * a3;
  float z = a1 + leb1[0] + a2 * deg3 - sub;
  float fv = 1.f / (1.f + expf(-z));
  xs[b * 1024 + t] += fv * x2;
  xs[b * 1024 + 512 + t] += fv * x2;
  (void)Hh; (void)Hl; (void)gb;
}

// ---------------- host orchestration ----------------
extern "C" void kernel_launch(void* const* d_in, const int* in_sizes, int n_in,
                              void* d_out, int out_size, void* d_ws, size_t ws_size,
                              hipStream_t stream) {
  (void)in_sizes; (void)n_in; (void)out_size;
  const int*   x_ids  = (const int*)  d_in[0];
  const float* adj    = (const float*)d_in[2];
  const float* emb    = (const float*)d_in[3];
  const float* conv_W = (const float*)d_in[4];
  const float* conv_b = (const float*)d_in[5];
  const float* att_src= (const float*)d_in[6];
  const float* att_dst= (const float*)d_in[7];
  const float* q_W    = (const float*)d_in[8];
  const float* q_b    = (const float*)d_in[9];
  const float* att_w  = (const float*)d_in[10];
  const float* att_b  = (const float*)d_in[11];
  const float* gcn_W  = (const float*)d_in[12];
  const float* gcn_b  = (const float*)d_in[13];
  const float* le_W1  = (const float*)d_in[14];
  const float* le_b1  = (const float*)d_in[15];
  const float* le_W2  = (const float*)d_in[16];
  const float* le_W3  = (const float*)d_in[17];
  const float* lin1_W = (const float*)d_in[18];
  const float* lin1_b = (const float*)d_in[19];
  const float* lin2_W = (const float*)d_in[20];
  const float* lin2_b = (const float*)d_in[21];
  float* out = (float*)d_out;

  const size_t WN_CONV = 3u * CH * CH;
  const size_t WN_GCN  = 3u * CH * CH;
  const size_t WN_L1   = (size_t)(2 * CH) * CH;
  const size_t WN_L2   = (size_t)CH * 511;
  const size_t WTOT    = WN_CONV + WN_GCN + WN_L1 + WN_L2;

  const size_t per_b  = (size_t)(3 * BSC * 4 + 2 * BS2 * 4 + 11 * 256 * 4
                                 + (4 * 512 + 2 * 256 + 16) * 4 + 4096);
  const size_t fixedb = (size_t)(3 * 512 + 64 + NB * 1024 + NB * 512) * 4
                      + WTOT * 4 + (size_t)NB * 1024 * 4 + (size_t)NB * 512 * 4;
  const size_t slack  = 64 * 512;
  int bc = 4;
  for (int cand = 256; cand >= 4; cand >>= 1) {
    if ((size_t)cand * per_b + fixedb + slack <= ws_size) { bc = cand; break; }
  }
  const int nchunks = NB / bc;

  char* w = (char*)d_ws;
  auto alloc = [&](size_t bytes) { char* p = w; w += (bytes + 255) & ~(size_t)255; return p; };
  float* xs   = (float*)alloc(sizeof(float) * NB * 1024);
  float* vvec = (float*)alloc(sizeof(float) * 3 * CH);
  float* c0   = (float*)alloc(256);
  f16*   Wh   = (f16*)alloc(WTOT * 2);
  f16*   Wl   = (f16*)alloc(WTOT * 2);
  f16*   XSh  = (f16*)alloc((size_t)NB * 1024 * 2);
  f16*   XSl  = (f16*)alloc((size_t)NB * 1024 * 2);
  f16*   FHh  = (f16*)alloc((size_t)NB * 512 * 2);
  f16*   FHl  = (f16*)alloc((size_t)NB * 512 * 2);
  f16* Xh  = (f16*)alloc((size_t)bc * BSC * 2);
  f16* Xl  = (f16*)alloc((size_t)bc * BSC * 2);
  f16* Hh  = (f16*)alloc((size_t)bc * BSC * 2);
  f16* Hl  = (f16*)alloc((size_t)bc * BSC * 2);
  f16* XPh = (f16*)alloc((size_t)bc * BSC * 2);
  f16* XPl = (f16*)alloc((size_t)bc * BSC * 2);
  f16* Ph  = (f16*)alloc((size_t)bc * BS2 * 2);
  f16* Pl  = (f16*)alloc((size_t)bc * BS2 * 2);
  f16* AAh = (f16*)alloc((size_t)bc * BS2 * 2);
  f16* AAl = (f16*)alloc((size_t)bc * BS2 * 2);
  float* si   = (float*)alloc(sizeof(float) * bc * NMAX);
  float* sj   = (float*)alloc(sizeof(float) * bc * NMAX);
  float* deg  = (float*)alloc(sizeof(float) * bc * NMAX);
  float* dinv = (float*)alloc(sizeof(float) * bc * NMAX);
  float* t1   = (float*)alloc(sizeof(float) * bc * NMAX);
  float* t2   = (float*)alloc(sizeof(float) * bc * NMAX);
  float* t3   = (float*)alloc(sizeof(float) * bc * NMAX);
  float* fit  = (float*)alloc(sizeof(float) * bc * NMAX);
  float* vals = (float*)alloc(sizeof(float) * bc * NMAX);
  int*   perm = (int*)  alloc(sizeof(int)   * bc * NMAX);
  float* sifu = (float*)alloc(sizeof(float) * bc);
  float* wv   = (float*)alloc(sizeof(float) * bc * 256);
  float* xcr  = (float*)alloc(sizeof(float) * bc * 512);
  float* h3   = (float*)alloc(sizeof(float) * bc * 512);
  float* sc   = (float*)alloc(sizeof(float) * bc * 16);
  f16* xcrh   = (f16*)alloc((size_t)bc * 512 * 2);
  f16* xcrl   = (f16*)alloc((size_t)bc * 512 * 2);

  f16* cwh = Wh;                       f16* cwl = Wl;
  f16* gwh = Wh + WN_CONV;             f16* gwl = Wl + WN_CONV;
  f16* l1h = Wh + WN_CONV + WN_GCN;    f16* l1l = Wl + WN_CONV + WN_GCN;
  f16* l2h = l1h + WN_L1;              f16* l2l = l1l + WN_L1;

  hipMemsetAsync(xs, 0, sizeof(float) * NB * 1024, stream);

  for (int l = 0; l < 3; ++l) {
    presplit_kernel<<<512, 256, 0, stream>>>(conv_W + (size_t)l * CH * CH,
                                             cwh + (size_t)l * CH * CH,
                                             cwl + (size_t)l * CH * CH, CH, CH);
    presplit_kernel<<<512, 256, 0, stream>>>(gcn_W + (size_t)l * CH * CH,
                                             gwh + (size_t)l * CH * CH,
                                             gwl + (size_t)l * CH * CH, CH, CH);
    vq_kernel<<<513, 64, 0, stream>>>(q_W + (size_t)l * CH * CH, q_b + l * CH,
                                      att_w + (size_t)l * 2 * CH, vvec + l * CH, c0 + l);
  }
  presplit_kernel<<<512, 256, 0, stream>>>(lin1_W, l1h, l1l, 2 * CH, CH);
  presplit_kernel<<<511, 256, 0, stream>>>(lin2_W, l2h, l2l, CH, 511);

  for (int ch = 0; ch < nchunks; ++ch) {
    const int b0 = ch * bc;
    const int*   ids_c = x_ids + (size_t)b0 * NMAX;
    const float* adj_c = adj + (size_t)b0 * BS2;
    float*       xs_c  = xs + (size_t)b0 * 1024;

    build_a_deg_kernel<<<dim3(NMAX, bc), 256, 0, stream>>>(adj_c, AAh, AAl, deg, dinv);
    embed_kernel<<<dim3(NMAX, bc), 128, 0, stream>>>(ids_c, emb, Xh, Xl);

    // ================= layer 1 (full, masked) =================
    {
      const int n = 256, kk = 205;
      const float* aw = att_w;
      pgemm_kernel<0><<<dim3(4, 4, bc), 256, 0, stream>>>(
          Xh, Xl, BSC, LDC, cwh, cwl, 0, CH,
          Hh, Hl, nullptr, BSC, LDC, nullptr, nullptr, n, CH, CH, 8);
      rowdot_kernel<<<dim3(n, bc), 64, 0, stream>>>(Hh, Hl, att_dst, att_src, nullptr,
                                                    si, sj, nullptr, 2);
      softmax_kernel<<<dim3(n, bc), 256, 0, stream>>>(AAh, AAl, si, sj, nullptr, Ph, Pl, n, 1);
      pgemm_kernel<1><<<dim3(4, 4, bc), 256, 0, stream>>>(
          Ph, Pl, BS2, LD2, Hh, Hl, BSC, LDC,
          Xh, Xl, nullptr, BSC, LDC, conv_b, nullptr, n, CH, n, 1 | 2 | 8);
      pgemm_kernel<0><<<dim3(4, 4, bc), 256, 0, stream>>>(
          Xh, Xl, BSC, LDC, gwh, gwl, 0, CH,
          Hh, Hl, nullptr, BSC, LDC, nullptr, dinv, n, CH, CH, 4 | 8);
      pgemm_kernel<1><<<dim3(4, 4, bc), 256, 0, stream>>>(
          AAh, AAl, BS2, LD2, Hh, Hl, BSC, LDC,
          XPh, XPl, nullptr, BSC, LDC, gcn_b, dinv, n, CH, n, 1 | 4 | 8);
      rowdot_kernel<<<dim3(n, bc), 64, 0, stream>>>(XPh, XPl, aw + CH, nullptr, nullptr,
                                                    sj, nullptr, nullptr, 1);
      colmax_kernel<<<bc, 512, 0, stream>>>(XPh, XPl, vvec, c0, sifu, n);
      nbrdot_kernel<<<dim3(n, bc), 256, 0, stream>>>(AAh, AAl, XPh, XPl, vvec, c0, sifu, si, n);
      softmax_kernel<<<dim3(n, bc), 256, 0, stream>>>(AAh, AAl, si, sj, att_b, Ph, Pl, n, 1);
      pgemm_kernel<1><<<dim3(4, 4, bc), 256, 0, stream>>>(
          Ph, Pl, BS2, LD2, Xh, Xl, BSC, LDC,
          Hh, Hl, nullptr, BSC, LDC, nullptr, nullptr, n, CH, n, 8);  // xc
      rowdot_kernel<<<dim3(n, bc), 64, 0, stream>>>(Hh, Hl, le_W1, le_W2, le_W3,
                                                    t1, t2, t3, 3);
      fit_kernel<<<dim3(n, bc), 64, 0, stream>>>(AAh, AAl, t1, t2, t3, deg, le_b1, fit, n);
      topk_kernel<<<bc, 256, 0, stream>>>(fit, perm, vals, n, kk);
      gather_kernel<<<dim3(kk, bc), 256, 0, stream>>>(Hh, Hl, Ph, Pl, perm, vals,
                                                      Xh, Xl, XPh, XPl, n);
      pgemm_kernel<0><<<dim3(2, 4, bc), 256, 0, stream>>>(
          XPh, XPl, BSC, LD2, AAh, AAl, BS2, LD2,
          Ph, Pl, nullptr, BS2, LD2, nullptr, nullptr, kk, n, n, 8);          // SA
      pgemm_kernel<0><<<dim3(2, 4, bc), 256, 0, stream>>>(
          Ph, Pl, BS2, LD2, XPh, XPl, BSC, LD2,
          AAh, AAl, nullptr, BS2, LD2, nullptr, nullptr, kk, kk, n, 8);       // A_new
      degfix_kernel<<<dim3(kk, bc), 256, 0, stream>>>(AAh, AAl, deg, dinv, kk);
      readout_kernel<<<dim3(2, bc), 256, 0, stream>>>(Xh, Xl, xs_c, kk);
    }

    // ================= layer 2 (dense mask; pool collapsed+fused) =================
    {
      const int n = 205, kk = 164;
      const float* aw = att_w + (size_t)2 * CH;
      pgemm_kernel<0><<<dim3(4, 4, bc), 256, 0, stream>>>(
          Xh, Xl, BSC, LDC, cwh + (size_t)CH * CH, cwl + (size_t)CH * CH, 0, CH,
          Hh, Hl, nullptr, BSC, LDC, nullptr, nullptr, n, CH, CH, 8);
      rowdot_kernel<<<dim3(n, bc), 64, 0, stream>>>(Hh, Hl, att_dst + CH, att_src + CH, nullptr,
                                                    si, sj, nullptr, 2);
      softmax_kernel<<<dim3(n, bc), 256, 0, stream>>>(AAh, AAl, si, sj, nullptr, Ph, Pl, n, 0);
      pgemm_kernel<1><<<dim3(4, 4, bc), 256, 0, stream>>>(
          Ph, Pl, BS2, LD2, Hh, Hl, BSC, LDC,
          Xh, Xl, nullptr, BSC, LDC, conv_b + CH, nullptr, n, CH, n, 1 | 2 | 8);
      pgemm_kernel<0><<<dim3(4, 4, bc), 256, 0, stream>>>(
          Xh, Xl, BSC, LDC, gwh + (size_t)CH * CH, gwl + (size_t)CH * CH, 0, CH,
          Hh, Hl, nullptr, BSC, LDC, nullptr, dinv, n, CH, CH, 4 | 8);
      pgemm_kernel<1><<<dim3(4, 4, bc), 256, 0, stream>>>(
          AAh, AAl, BS2, LD2, Hh, Hl, BSC, LDC,
          XPh, XPl, nullptr, BSC, LDC, gcn_b + CH, dinv, n, CH, n, 1 | 4 | 8);
      rowdot_kernel<<<dim3(n, bc), 64, 0, stream>>>(XPh, XPl, aw + CH, nullptr, nullptr,
                                                    sj, nullptr, nullptr, 1);
      pool2_kernel<<<bc, 512, 0, stream>>>(
          XPh, XPl, Xh, Xl, AAh, AAl, sj, vvec + CH, c0 + 1, att_b + 1,
          le_W1 + CH, le_W2 + CH, le_W3 + CH, xcr, xcrh, xcrl, t1, t2, t3, sc, n, kk);
      fit_kernel<<<dim3(n, bc), 64, 0, stream>>>(AAh, AAl, t1, t2, t3, deg, le_b1 + 1, fit, n);
      topk_kernel<<<bc, 256, 0, stream>>>(fit, perm, vals, n, kk);
      readout_rank1_kernel<<<bc, 256, 0, stream>>>(vals, xcr, xs_c, kk);
    }

    // ================= layer 3 (rank-1 X; fused) =================
    {
      const int n = 164;
      pgemm_kernel<0><<<dim3(4, 1, 1), 256, 0, stream>>>(
          xcrh, xcrl, 0, 512, cwh + (size_t)2 * CH * CH, cwl + (size_t)2 * CH * CH, 0, CH,
          nullptr, nullptr, h3, 0, 512, nullptr, nullptr, bc, CH, CH, 16);
      gat3scal_kernel<<<bc, 64, 0, stream>>>(h3, att_dst + 2 * CH, att_src + 2 * CH, sc);
      gatw_kernel<<<dim3(n, bc), 256, 0, stream>>>(vals, sc, wv, n);
      xgat_kernel<<<dim3(n, bc), 256, 0, stream>>>(wv, h3, conv_b + 2 * CH, Xh, Xl);
      pool3_kernel<<<bc, 512, 0, stream>>>(
          Hh, Hl, Xh, Xl, sc, gcn_b + 2 * CH,
          le_W1 + 2 * CH, le_W2 + 2 * CH, le_W3 + 2 * CH, le_b1 + 2, xs_c, n);
    }
  }

  // ---- final MLP (full batch) ----
  splitbuf_kernel<<<NB, 256, 0, stream>>>(xs, XSh, XSl, 1024);
  pgemm_kernel<0><<<dim3(4, 4, 1), 256, 0, stream>>>(
      XSh, XSl, 0, 1024, l1h, l1l, 0, 1024,
      FHh, FHl, nullptr, 0, CH, lin1_b, nullptr, NB, CH, 2 * CH, 1 | 2 | 8);
  pgemm_kernel<0><<<dim3(4, 4, 1), 256, 0, stream>>>(
      FHh, FHl, 0, CH, l2h, l2l, 0, CH,
      nullptr, nullptr, out, 0, 511, lin2_b, nullptr, NB, 511, CH, 1 | 16);
}

// Round 8
// 3414.962 us; speedup vs baseline: 2.8576x; 1.0733x over previous
//
#include <hip/hip_runtime.h>
#include <math.h>

#define NB   256
#define NMAX 256
#define CH   512
#define LD2  256
#define LDC  512
#define BS2  (256*256)
#define BSC  (256*512)

typedef _Float16 f16;
typedef __attribute__((ext_vector_type(4))) f16 f16x4;
typedef __attribute__((ext_vector_type(8))) f16 f16x8;
typedef __attribute__((ext_vector_type(4))) float f32x4;

#define INV2048 4.8828125e-04f

__device__ __forceinline__ float warp_sum_f(float v) {
#pragma unroll
  for (int m = 32; m >= 1; m >>= 1) v += __shfl_xor(v, m);
  return v;
}

__device__ __forceinline__ void split1(float x, f16& h, f16& l) {
  float xh = (__builtin_fabsf(x) >= 6.103515625e-05f) ? x : 0.f;
  f16 hh = (f16)xh;
  float hf = (float)hh;
  h = hh;
  l = (f16)((x - hf) * 2048.0f);
}

__device__ __forceinline__ float rc(f16 h, f16 l) {
  return (float)h + (float)l * INV2048;
}

__device__ __forceinline__ float rc8q(const f16x8& h, const f16x8& l, int q) {
  return (float)h[q] + (float)l[q] * INV2048;
}

// ---------------- plane GEMM v3: 64x128 tile + XCD-aware block swizzle ----------------
// A: [M][K] planes. B: BMODE 0 -> [N][K] planes; BMODE 1 -> [K][N] planes.
// flags: 1 bias, 2 relu, 4 rowscale, 8 write planes, 16 write f32
template <int BMODE>
__global__ __launch_bounds__(256, 2)
void pgemm_kernel(const f16* __restrict__ Ahp, const f16* __restrict__ Alp, long bsA, int lda,
                  const f16* __restrict__ Bhp, const f16* __restrict__ Blp, long bsB, int ldb,
                  f16* __restrict__ Yh, f16* __restrict__ Yl, float* __restrict__ Yf,
                  long bsY, int ldy,
                  const float* __restrict__ bias, const float* __restrict__ rowscale,
                  int M, int Ncol, int K, int flags)
{
  __shared__ f16 Ah[64][40];
  __shared__ f16 Al[64][40];
  __shared__ f16 Bh[128][40];
  __shared__ f16 Bl[128][40];

  // XCD-aware swizzle (bijective, m204 form): HW round-robins linear id % 8
  // across XCDs; remap so each XCD gets a CONTIGUOUS chunk of logical tiles.
  // Logical-consecutive ids share the A panel (x fastest) -> A L2-resident per XCD.
  const int gx = gridDim.x, gy = gridDim.y;
  const int nwg = gx * gy * gridDim.z;
  const int lin = blockIdx.x + gx * (blockIdx.y + gy * blockIdx.z);
  const int q8 = nwg >> 3, r8 = nwg & 7;
  const int xcd = lin & 7, sub = lin >> 3;
  const int swz = ((xcd < r8) ? xcd * (q8 + 1) : r8 * (q8 + 1) + (xcd - r8) * q8) + sub;
  const int bxi = swz % gx;
  const int tmp = swz / gx;
  const int byi = tmp % gy;
  const int b   = tmp / gy;

  const int i0  = byi * 64;
  const int n0  = bxi * 128;
  const int tid = threadIdx.x;
  const int w  = tid >> 6, l = tid & 63;
  const int wr = (w >> 1) * 32, wc = (w & 1) * 64;
  const int lr = l & 15, lq = l >> 4;
  const f16* Abh = Ahp + (long)b * bsA;
  const f16* Abl = Alp + (long)b * bsA;
  const f16* Bbh = Bhp + (long)b * bsB;
  const f16* Bbl = Blp + (long)b * bsB;

  f32x4 acc1[2][4], acc2[2][4];
#pragma unroll
  for (int mi = 0; mi < 2; ++mi)
#pragma unroll
    for (int ni = 0; ni < 4; ++ni) {
      acc1[mi][ni] = (f32x4){0.f, 0.f, 0.f, 0.f};
      acc2[mi][ni] = (f32x4){0.f, 0.f, 0.f, 0.f};
    }

  const f16x8 z8 = (f16x8){0,0,0,0,0,0,0,0};
  f16x8 rah, ral;
  f16x8 rbh[2], rbl[2];
  f16x8 rva, rvb, rwa, rwb;

  const int arow = tid >> 2, akq = (tid & 3) * 8;

  auto LOADA = [&](int k0) {
    int gr = i0 + arow, gk = k0 + akq;
    rah = z8; ral = z8;
    if (gr < M) {
      if (gk + 7 < K) {
        rah = *(const f16x8*)(Abh + (long)gr * lda + gk);
        ral = *(const f16x8*)(Abl + (long)gr * lda + gk);
      } else {
#pragma unroll
        for (int j = 0; j < 8; ++j) if (gk + j < K) {
          rah[j] = Abh[(long)gr * lda + gk + j];
          ral[j] = Abl[(long)gr * lda + gk + j];
        }
      }
    }
  };
  auto STOREA = [&]() {
    *(f16x8*)&Ah[arow][akq] = rah;
    *(f16x8*)&Al[arow][akq] = ral;
  };
  auto LOADB = [&](int k0) {
    if (BMODE == 0) {
#pragma unroll
      for (int rep = 0; rep < 2; ++rep) {
        int idx = rep * 256 + tid;
        int c = idx >> 2, kq = (idx & 3) * 8;
        int gc = n0 + c, gk = k0 + kq;
        rbh[rep] = z8; rbl[rep] = z8;
        if (gc < Ncol) {
          if (gk + 7 < K) {
            rbh[rep] = *(const f16x8*)(Bbh + (long)gc * ldb + gk);
            rbl[rep] = *(const f16x8*)(Bbl + (long)gc * ldb + gk);
          } else {
#pragma unroll
            for (int j = 0; j < 8; ++j) if (gk + j < K) {
              rbh[rep][j] = Bbh[(long)gc * ldb + gk + j];
              rbl[rep][j] = Bbl[(long)gc * ldb + gk + j];
            }
          }
        }
      }
    } else {
      int c8  = (tid >> 4) * 8;
      int k0p = (tid & 15) * 2;
      int gc = n0 + c8;
      rva = z8; rvb = z8; rwa = z8; rwb = z8;
      int gka = k0 + k0p, gkb = gka + 1;
      if (gc + 7 < Ncol) {
        if (gka < K) { rva = *(const f16x8*)(Bbh + (long)gka * ldb + gc);
                       rwa = *(const f16x8*)(Bbl + (long)gka * ldb + gc); }
        if (gkb < K) { rvb = *(const f16x8*)(Bbh + (long)gkb * ldb + gc);
                       rwb = *(const f16x8*)(Bbl + (long)gkb * ldb + gc); }
      }
    }
  };
  auto STOREB = [&]() {
    if (BMODE == 0) {
#pragma unroll
      for (int rep = 0; rep < 2; ++rep) {
        int idx = rep * 256 + tid;
        int c = idx >> 2, kq = (idx & 3) * 8;
        *(f16x8*)&Bh[c][kq] = rbh[rep];
        *(f16x8*)&Bl[c][kq] = rbl[rep];
      }
    } else {
      int c8  = (tid >> 4) * 8;
      int k0p = (tid & 15) * 2;
#pragma unroll
      for (int j = 0; j < 8; ++j) {
        union { f16 f[2]; unsigned u; } ph, pl;
        ph.f[0] = rva[j]; ph.f[1] = rvb[j];
        pl.f[0] = rwa[j]; pl.f[1] = rwb[j];
        *(unsigned*)&Bh[c8 + j][k0p] = ph.u;
        *(unsigned*)&Bl[c8 + j][k0p] = pl.u;
      }
    }
  };

  const int nk = (K + 31) / 32;
  LOADA(0); LOADB(0);
  for (int ki = 0; ki < nk; ++ki) {
    STOREA(); STOREB();
    __syncthreads();
    if (ki + 1 < nk) { LOADA((ki + 1) * 32); LOADB((ki + 1) * 32); }

    f16x8 bh[4], bl[4];
#pragma unroll
    for (int ni = 0; ni < 4; ++ni) {
      bh[ni] = *(const f16x8*)&Bh[wc + ni * 16 + lr][lq * 8];
      bl[ni] = *(const f16x8*)&Bl[wc + ni * 16 + lr][lq * 8];
    }
#pragma unroll
    for (int mi = 0; mi < 2; ++mi) {
      f16x8 ah = *(const f16x8*)&Ah[wr + mi * 16 + lr][lq * 8];
      f16x8 al = *(const f16x8*)&Al[wr + mi * 16 + lr][lq * 8];
#pragma unroll
      for (int ni = 0; ni < 4; ++ni) {
        acc1[mi][ni] = __builtin_amdgcn_mfma_f32_16x16x32_f16(ah, bh[ni], acc1[mi][ni], 0, 0, 0);
        acc2[mi][ni] = __builtin_amdgcn_mfma_f32_16x16x32_f16(ah, bl[ni], acc2[mi][ni], 0, 0, 0);
        acc2[mi][ni] = __builtin_amdgcn_mfma_f32_16x16x32_f16(al, bh[ni], acc2[mi][ni], 0, 0, 0);
      }
    }
    __syncthreads();
  }

  // epilogue: col = lane&15, row = (lane>>4)*4 + reg
#pragma unroll
  for (int mi = 0; mi < 2; ++mi) {
#pragma unroll
    for (int ni = 0; ni < 4; ++ni) {
      int col = n0 + wc + ni * 16 + lr;
      if (col >= Ncol) continue;
      float bv = (flags & 1) ? bias[col] : 0.f;
#pragma unroll
      for (int r = 0; r < 4; ++r) {
        int row = i0 + wr + mi * 16 + lq * 4 + r;
        if (row >= M) continue;
        float vv = acc1[mi][ni][r] + acc2[mi][ni][r] * INV2048;
        if (flags & 4) vv *= rowscale[b * 256 + row];
        vv += bv;
        if (flags & 2) vv = fmaxf(vv, 0.f);
        long off = (long)b * bsY + (long)row * ldy + col;
        if (flags & 8) { f16 h, lo; split1(vv, h, lo); Yh[off] = h; Yl[off] = lo; }
        if (flags & 16) Yf[off] = vv;
      }
    }
  }
}

__global__ void presplit_kernel(const float* __restrict__ W, f16* __restrict__ Wh,
                                f16* __restrict__ Wl, int K, int N) {
  int n = blockIdx.x;
  for (int k = threadIdx.x; k < K; k += blockDim.x) {
    f16 h, l; split1(W[(long)k * N + n], h, l);
    Wh[(long)n * K + k] = h;
    Wl[(long)n * K + k] = l;
  }
}

__global__ void splitbuf_kernel(const float* __restrict__ X, f16* __restrict__ Xh,
                                f16* __restrict__ Xl, int cols) {
  int i = blockIdx.x;
  for (int c = threadIdx.x; c < cols; c += blockDim.x) {
    f16 h, l; split1(X[(long)i * cols + c], h, l);
    Xh[(long)i * cols + c] = h;
    Xl[(long)i * cols + c] = l;
  }
}

// ---------------- layer-1 small kernels ----------------
__global__ void build_a_deg_kernel(const float* __restrict__ adj, f16* __restrict__ AAh,
                                   f16* __restrict__ AAl, float* __restrict__ deg,
                                   float* __restrict__ dinv) {
  int b = blockIdx.y, i = blockIdx.x, j = threadIdx.x;
  __shared__ float red[256];
  float v = adj[(long)b * BS2 + i * 256 + j];
  if (i == j) v = fmaxf(v, 1.f);
  f16 h, l; split1(v, h, l);
  long o = (long)b * BS2 + i * 256 + j;
  AAh[o] = h; AAl[o] = l;
  red[j] = v; __syncthreads();
  for (int s = 128; s > 0; s >>= 1) { if (j < s) red[j] += red[j + s]; __syncthreads(); }
  if (j == 0) {
    float s = red[0];
    deg[b * 256 + i] = s;
    dinv[b * 256 + i] = (s > 0.f) ? (1.f / sqrtf(s)) : 0.f;
  }
}

__global__ void embed_kernel(const int* __restrict__ ids, const float* __restrict__ emb,
                             f16* __restrict__ Xh, f16* __restrict__ Xl) {
  int b = blockIdx.y, i = blockIdx.x, t = threadIdx.x;
  int id = ids[b * NMAX + i];
  float4 v = *(const float4*)(emb + (long)id * CH + t * 4);
  long o = (long)b * BSC + (long)i * LDC + t * 4;
  float vv[4] = {v.x, v.y, v.z, v.w};
#pragma unroll
  for (int j = 0; j < 4; ++j) { f16 h, l; split1(vv[j], h, l); Xh[o + j] = h; Xl[o + j] = l; }
}

__global__ void rowdot_kernel(const f16* __restrict__ Xh, const f16* __restrict__ Xl,
                              const float* __restrict__ v1, const float* __restrict__ v2,
                              const float* __restrict__ v3,
                              float* __restrict__ o1, float* __restrict__ o2,
                              float* __restrict__ o3, int nvec) {
  int b = blockIdx.y, i = blockIdx.x, lane = threadIdx.x;
  long base = (long)b * BSC + (long)i * LDC;
  float a1 = 0.f, a2 = 0.f, a3 = 0.f;
  for (int c = lane; c < CH; c += 64) {
    float x = rc(Xh[base + c], Xl[base + c]);
    a1 = fmaf(x, v1[c], a1);
    if (nvec > 1) a2 = fmaf(x, v2[c], a2);
    if (nvec > 2) a3 = fmaf(x, v3[c], a3);
  }
  a1 = warp_sum_f(a1);
  if (nvec > 1) a2 = warp_sum_f(a2);
  if (nvec > 2) a3 = warp_sum_f(a3);
  if (lane == 0) {
    o1[b * 256 + i] = a1;
    if (nvec > 1) o2[b * 256 + i] = a2;
    if (nvec > 2) o3[b * 256 + i] = a3;
  }
}

__global__ void vq_kernel(const float* __restrict__ qW, const float* __restrict__ qb,
                          const float* __restrict__ aw, float* __restrict__ v,
                          float* __restrict__ c0) {
  int blk = blockIdx.x, lane = threadIdx.x;
  if (blk < 512) {
    float s = 0.f;
    for (int j = lane; j < CH; j += 64) s = fmaf(qW[(long)blk * CH + j], aw[j], s);
    s = warp_sum_f(s);
    if (lane == 0) v[blk] = s;
  } else {
    float s = 0.f;
    for (int j = lane; j < CH; j += 64) s = fmaf(qb[j], aw[j], s);
    s = warp_sum_f(s);
    if (lane == 0) c0[0] = s;
  }
}

__global__ __launch_bounds__(256)
void softmax_kernel(const f16* __restrict__ AAh, const f16* __restrict__ AAl,
                    const float* __restrict__ si, const float* __restrict__ sj,
                    const float* __restrict__ attb,
                    f16* __restrict__ Ph, f16* __restrict__ Pl, int n, int masked) {
  int b = blockIdx.y, i = blockIdx.x, j = threadIdx.x;
  __shared__ float red[256];
  float logit = -1e30f, e = 0.f;
  float siv = si[b * 256 + i];
  long ro = (long)b * BS2 + i * 256;
  if (j < n) {
    float z = siv + sj[b * 256 + j] + (attb ? attb[0] : 0.f);
    z = (z > 0.f) ? z : 0.2f * z;
    if (masked) {
      float a = rc(AAh[ro + j], AAl[ro + j]);
      logit = (a > 0.f) ? z : -1e9f;
    } else logit = z;
  }
  red[j] = logit; __syncthreads();
  for (int s = 128; s > 0; s >>= 1) { if (j < s) red[j] = fmaxf(red[j], red[j + s]); __syncthreads(); }
  float mx = red[0]; __syncthreads();
  if (j < n) e = expf(logit - mx);
  red[j] = e; __syncthreads();
  for (int s = 128; s > 0; s >>= 1) { if (j < s) red[j] += red[j + s]; __syncthreads(); }
  float sum = red[0];
  if (j < n) {
    f16 h, l; split1(e / sum, h, l);
    Ph[ro + j] = h; Pl[ro + j] = l;
  }
}

__global__ __launch_bounds__(512)
void colmax_kernel(const f16* __restrict__ XPh, const f16* __restrict__ XPl,
                   const float* __restrict__ v, const float* __restrict__ c0,
                   float* __restrict__ si_full, int n) {
  int b = blockIdx.x, t = threadIdx.x;
  int cg = t >> 3, rl = t & 7, c0c = cg * 8;
  long base = (long)b * BSC;
  __shared__ float red[64];
  float m[8];
#pragma unroll
  for (int q = 0; q < 8; ++q) m[q] = -1e9f;
  for (int j = rl; j < n; j += 8) {
    f16x8 h = *(const f16x8*)(XPh + base + (long)j * LDC + c0c);
    f16x8 l = *(const f16x8*)(XPl + base + (long)j * LDC + c0c);
#pragma unroll
    for (int q = 0; q < 8; ++q) m[q] = fmaxf(m[q], rc8q(h, l, q));
  }
#pragma unroll
  for (int d = 1; d < 8; d <<= 1)
#pragma unroll
    for (int q = 0; q < 8; ++q) m[q] = fmaxf(m[q], __shfl_xor(m[q], d));
  if (rl == 0) {
    float p = 0.f;
#pragma unroll
    for (int q = 0; q < 8; ++q) p = fmaf(m[q], v[c0c + q], p);
    red[cg] = p;
  }
  __syncthreads();
  for (int s = 32; s > 0; s >>= 1) { if (t < s) red[t] += red[t + s]; __syncthreads(); }
  if (t == 0) si_full[b] = red[0] + c0[0];
}

__global__ __launch_bounds__(256)
void nbrdot_kernel(const f16* __restrict__ AAh, const f16* __restrict__ AAl,
                   const f16* __restrict__ XPh, const f16* __restrict__ XPl,
                   const float* __restrict__ v, const float* __restrict__ c0,
                   const float* __restrict__ si_full, float* __restrict__ si, int n) {
  int b = blockIdx.y, i = blockIdx.x, t = threadIdx.x;
  __shared__ int list[256];
  __shared__ int cnt, nmiss;
  __shared__ float red[256];
  if (t == 0) { cnt = 0; nmiss = 0; }
  __syncthreads();
  long ro = (long)b * BS2 + i * 256;
  if (t < n) {
    float a = rc(AAh[ro + t], AAl[ro + t]);
    if (a > 0.f) { int p = atomicAdd(&cnt, 1); list[p] = t; }
    else atomicAdd(&nmiss, 1);
  }
  __syncthreads();
  if (nmiss == 0) {
    if (t == 0) si[b * 256 + i] = si_full[b];
    return;
  }
  int c = cnt;
  long base = (long)b * BSC;
  float m1 = -1e9f, m2 = -1e9f;
  for (int q = 0; q < c; ++q) {
    int j = list[q];
    m1 = fmaxf(m1, rc(XPh[base + (long)j * LDC + t], XPl[base + (long)j * LDC + t]));
    m2 = fmaxf(m2, rc(XPh[base + (long)j * LDC + t + 256], XPl[base + (long)j * LDC + t + 256]));
  }
  red[t] = m1 * v[t] + m2 * v[t + 256];
  __syncthreads();
  for (int s = 128; s > 0; s >>= 1) { if (t < s) red[t] += red[t + s]; __syncthreads(); }
  if (t == 0) si[b * 256 + i] = red[0] + c0[0];
}

__global__ void fit_kernel(const f16* __restrict__ AAh, const f16* __restrict__ AAl,
                           const float* __restrict__ t1, const float* __restrict__ t2,
                           const float* __restrict__ t3,
                           const float* __restrict__ deg, const float* __restrict__ leb1,
                           float* __restrict__ fit, int n) {
  int b = blockIdx.y, i = blockIdx.x, lane = threadIdx.x;
  long ro = (long)b * BS2 + i * 256;
  float s = 0.f;
  for (int j = lane; j < n; j += 64) s = fmaf(rc(AAh[ro + j], AAl[ro + j]), t3[b * 256 + j], s);
  s = warp_sum_f(s);
  if (lane == 0) {
    float z = t1[b * 256 + i] + leb1[0] + t2[b * 256 + i] * deg[b * 256 + i] - s;
    fit[b * 256 + i] = 1.f / (1.f + expf(-z));
  }
}

__global__ __launch_bounds__(256)
void topk_kernel(const float* __restrict__ fit, int* __restrict__ perm,
                 float* __restrict__ vals, int n, int k) {
  __shared__ float v[256];
  __shared__ int ix[256];
  int b = blockIdx.x, t = threadIdx.x;
  v[t] = (t < n) ? fit[b * 256 + t] : -1e30f;
  ix[t] = t;
  __syncthreads();
  for (int size = 2; size <= 256; size <<= 1)
    for (int str = size >> 1; str > 0; str >>= 1) {
      int p = t ^ str;
      if (p > t) {
        bool desc = ((t & size) == 0);
        float v1 = v[t], v2 = v[p]; int i1 = ix[t], i2 = ix[p];
        bool inorder = (v1 > v2) || (v1 == v2 && i1 < i2);
        if (inorder != desc) { v[t] = v2; v[p] = v1; ix[t] = i2; ix[p] = i1; }
      }
      __syncthreads();
    }
  if (t < k) { perm[b * 256 + t] = ix[t]; vals[b * 256 + t] = v[t]; }
}

__global__ __launch_bounds__(256)
void gather_kernel(const f16* __restrict__ Hh, const f16* __restrict__ Hl,
                   const f16* __restrict__ Ph, const f16* __restrict__ Pl,
                   const int* __restrict__ perm, const float* __restrict__ vals,
                   f16* __restrict__ Xh, f16* __restrict__ Xl,
                   f16* __restrict__ Skh, f16* __restrict__ Skl, int n) {
  int b = blockIdx.y, p = blockIdx.x, t = threadIdx.x;
  int src = perm[b * 256 + p];
  float sv = vals[b * 256 + p];
#pragma unroll
  for (int r = 0; r < 2; ++r) {
    int c = t + r * 256;
    long so = (long)b * BSC + (long)src * LDC + c;
    long dof = (long)b * BSC + (long)p * LDC + c;
    float x = rc(Hh[so], Hl[so]) * sv;
    f16 h, l; split1(x, h, l);
    Xh[dof] = h; Xl[dof] = l;
  }
  if (t < n) {
    long so = (long)b * BS2 + src * 256 + t;
    long dof = (long)b * BSC + p * 256 + t;
    Skh[dof] = Ph[so]; Skl[dof] = Pl[so];
  }
}

__global__ void degfix_kernel(f16* __restrict__ AAh, f16* __restrict__ AAl,
                              float* __restrict__ deg, float* __restrict__ dinv, int k) {
  int b = blockIdx.y, i = blockIdx.x, j = threadIdx.x;
  __shared__ float red[256];
  long ro = (long)b * BS2 + i * 256;
  float v = 0.f;
  if (j < k) {
    v = rc(AAh[ro + j], AAl[ro + j]);
    if (j == i && v <= 0.f) {
      v += 1.f;
      f16 h, l; split1(v, h, l);
      AAh[ro + j] = h; AAl[ro + j] = l;
    }
  }
  red[j] = v; __syncthreads();
  for (int s = 128; s > 0; s >>= 1) { if (j < s) red[j] += red[j + s]; __syncthreads(); }
  if (j == 0) {
    float s = red[0];
    deg[b * 256 + i] = s;
    dinv[b * 256 + i] = (s > 0.f) ? (1.f / sqrtf(s)) : 0.f;
  }
}

__global__ __launch_bounds__(256)
void readout_kernel(const f16* __restrict__ Xh, const f16* __restrict__ Xl,
                    float* __restrict__ xs, int k) {
  int b = blockIdx.y, t = threadIdx.x;
  int cg = t >> 3, rl = t & 7;
  int c0c = blockIdx.x * 256 + cg * 8;
  long base = (long)b * BSC;
  float s[8], m[8];
#pragma unroll
  for (int q = 0; q < 8; ++q) { s[q] = 0.f; m[q] = -1e30f; }
  for (int p = rl; p < k; p += 8) {
    f16x8 h = *(const f16x8*)(Xh + base + (long)p * LDC + c0c);
    f16x8 l = *(const f16x8*)(Xl + base + (long)p * LDC + c0c);
#pragma unroll
    for (int q = 0; q < 8; ++q) {
      float v = rc8q(h, l, q);
      s[q] += v; m[q] = fmaxf(m[q], v);
    }
  }
#pragma unroll
  for (int d = 1; d < 8; d <<= 1)
#pragma unroll
    for (int q = 0; q < 8; ++q) {
      s[q] += __shfl_xor(s[q], d);
      m[q] = fmaxf(m[q], __shfl_xor(m[q], d));
    }
  if (rl == 0) {
#pragma unroll
    for (int q = 0; q < 8; ++q) {
      xs[b * 1024 + c0c + q] += s[q] / (float)k;
      xs[b * 1024 + 512 + c0c + q] += m[q];
    }
  }
}

// ---- fused layer-2 pool ----
__global__ __launch_bounds__(512)
void pool2_kernel(const f16* __restrict__ XPh, const f16* __restrict__ XPl,
                  const f16* __restrict__ Xh, const f16* __restrict__ Xl,
                  const f16* __restrict__ AAh, const f16* __restrict__ AAl,
                  const float* __restrict__ sj,
                  const float* __restrict__ v, const float* __restrict__ c0,
                  const float* __restrict__ attb,
                  const float* __restrict__ w1, const float* __restrict__ w2,
                  const float* __restrict__ w3,
                  float* __restrict__ xcr, f16* __restrict__ xcrh, f16* __restrict__ xcrl,
                  float* __restrict__ t1, float* __restrict__ t2, float* __restrict__ t3,
                  float* __restrict__ sc, int n, int n3) {
  int b = blockIdx.x, t = threadIdx.x;
  int cg = t >> 3, rl = t & 7, c0c = cg * 8;
  long baseC = (long)b * BSC;
  __shared__ float red[512];
  __shared__ float pvs[256];
  __shared__ float xcs[512];

  float m[8];
#pragma unroll
  for (int q = 0; q < 8; ++q) m[q] = -1e9f;
  for (int j = rl; j < n; j += 8) {
    f16x8 h = *(const f16x8*)(XPh + baseC + (long)j * LDC + c0c);
    f16x8 l = *(const f16x8*)(XPl + baseC + (long)j * LDC + c0c);
#pragma unroll
    for (int q = 0; q < 8; ++q) m[q] = fmaxf(m[q], rc8q(h, l, q));
  }
#pragma unroll
  for (int d = 1; d < 8; d <<= 1)
#pragma unroll
    for (int q = 0; q < 8; ++q) m[q] = fmaxf(m[q], __shfl_xor(m[q], d));
  if (rl == 0) {
    float p = 0.f;
#pragma unroll
    for (int q = 0; q < 8; ++q) p = fmaf(m[q], v[c0c + q], p);
    red[cg] = p;
  }
  __syncthreads();
  for (int s2 = 32; s2 > 0; s2 >>= 1) { if (t < s2) red[t] += red[t + s2]; __syncthreads(); }
  float sifu = red[0] + c0[0];
  __syncthreads();

  float z = -1e30f;
  if (t < n) {
    float zz = sifu + sj[b * 256 + t] + attb[0];
    z = (zz > 0.f) ? zz : 0.2f * zz;
  }
  red[t] = z; __syncthreads();
  for (int s2 = 256; s2 > 0; s2 >>= 1) { if (t < s2) red[t] = fmaxf(red[t], red[t + s2]); __syncthreads(); }
  float mx = red[0]; __syncthreads();
  float e = (t < n) ? expf(z - mx) : 0.f;
  red[t] = e; __syncthreads();
  for (int s2 = 256; s2 > 0; s2 >>= 1) { if (t < s2) red[t] += red[t + s2]; __syncthreads(); }
  float psum = red[0];
  __syncthreads();
  if (t < 256) pvs[t] = (t < n) ? e / psum : 0.f;
  __syncthreads();

  float s8[8];
#pragma unroll
  for (int q = 0; q < 8; ++q) s8[q] = 0.f;
  for (int j = rl; j < n; j += 8) {
    float w_ = pvs[j];
    f16x8 h = *(const f16x8*)(Xh + baseC + (long)j * LDC + c0c);
    f16x8 l = *(const f16x8*)(Xl + baseC + (long)j * LDC + c0c);
#pragma unroll
    for (int q = 0; q < 8; ++q) s8[q] = fmaf(w_, rc8q(h, l, q), s8[q]);
  }
#pragma unroll
  for (int d = 1; d < 8; d <<= 1)
#pragma unroll
    for (int q = 0; q < 8; ++q) s8[q] += __shfl_xor(s8[q], d);
  if (rl == 0) {
#pragma unroll
    for (int q = 0; q < 8; ++q) {
      float vv = s8[q];
      xcs[c0c + q] = vv;
      xcr[b * 512 + c0c + q] = vv;
      f16 hh, ll; split1(vv, hh, ll);
      xcrh[b * 512 + c0c + q] = hh;
      xcrl[b * 512 + c0c + q] = ll;
    }
  }
  __syncthreads();

  float x_ = xcs[t];
  red[t] = x_ * w1[t]; __syncthreads();
  for (int s2 = 256; s2 > 0; s2 >>= 1) { if (t < s2) red[t] += red[t + s2]; __syncthreads(); }
  float a1 = red[0]; __syncthreads();
  red[t] = x_ * w2[t]; __syncthreads();
  for (int s2 = 256; s2 > 0; s2 >>= 1) { if (t < s2) red[t] += red[t + s2]; __syncthreads(); }
  float a2 = red[0]; __syncthreads();
  red[t] = x_ * w3[t]; __syncthreads();
  for (int s2 = 256; s2 > 0; s2 >>= 1) { if (t < s2) red[t] += red[t + s2]; __syncthreads(); }
  float a3 = red[0]; __syncthreads();
  if (t < n) { t1[b * 256 + t] = a1; t2[b * 256 + t] = a2; t3[b * 256 + t] = a3; }

  float qm = 0.f;
  if (t < n) {
    long ro = (long)b * BS2 + (long)t * 256;
    int j = 0;
    for (; j + 8 <= n; j += 8) {
      f16x8 h = *(const f16x8*)(AAh + ro + j);
      f16x8 l = *(const f16x8*)(AAl + ro + j);
#pragma unroll
      for (int q = 0; q < 8; ++q) qm = fmaf(pvs[j + q], rc8q(h, l, q), qm);
    }
    for (; j < n; ++j) qm = fmaf(pvs[j], rc(AAh[ro + j], AAl[ro + j]), qm);
  }
  red[t] = (t < n) ? qm * pvs[t] : 0.f;
  __syncthreads();
  for (int s2 = 256; s2 > 0; s2 >>= 1) { if (t < s2) red[t] += red[t + s2]; __syncthreads(); }
  if (t == 0) {
    float a = red[0];
    float d3 = a * (float)n3;
    sc[b * 16 + 2] = a;
    sc[b * 16 + 3] = d3;
    sc[b * 16 + 4] = (d3 > 0.f) ? (1.f / sqrtf(d3)) : 0.f;
  }
}

__global__ __launch_bounds__(256)
void readout_rank1_kernel(const float* __restrict__ vals, const float* __restrict__ xcr,
                          float* __restrict__ xs, int k) {
  int b = blockIdx.x, t = threadIdx.x;
  __shared__ float red[256];
  red[t] = (t < k) ? vals[b * 256 + t] : 0.f;
  __syncthreads();
  for (int s = 128; s > 0; s >>= 1) { if (t < s) red[t] += red[t + s]; __syncthreads(); }
  float sv = red[0] / (float)k;
  float vmax = vals[b * 256], vmin = vals[b * 256 + k - 1];
#pragma unroll
  for (int r = 0; r < 2; ++r) {
    int c = t + r * 256;
    float x = xcr[b * 512 + c];
    xs[b * 1024 + c] += sv * x;
    xs[b * 1024 + 512 + c] += (x >= 0.f ? vmax : vmin) * x;
  }
}

__global__ void gat3scal_kernel(const float* __restrict__ h, const float* __restrict__ adst,
                                const float* __restrict__ asrc, float* __restrict__ sc) {
  int b = blockIdx.x, lane = threadIdx.x;
  float a1 = 0.f, a2 = 0.f;
  for (int c = lane; c < CH; c += 64) {
    float x = h[b * 512 + c];
    a1 = fmaf(x, adst[c], a1); a2 = fmaf(x, asrc[c], a2);
  }
  a1 = warp_sum_f(a1); a2 = warp_sum_f(a2);
  if (lane == 0) { sc[b * 16 + 0] = a1; sc[b * 16 + 1] = a2; }
}

__global__ __launch_bounds__(256)
void gatw_kernel(const float* __restrict__ vals, const float* __restrict__ sc,
                 float* __restrict__ wv, int n) {
  int b = blockIdx.y, i = blockIdx.x, t = threadIdx.x;
  __shared__ float red[256];
  __shared__ float red2[256];
  float hd = sc[b * 16 + 0], hs = sc[b * 16 + 1];
  float si = vals[b * 256 + i] * hd;
  float z = -1e30f, vj = 0.f;
  if (t < n) {
    vj = vals[b * 256 + t];
    float zz = si + vj * hs;
    z = (zz > 0.f) ? zz : 0.2f * zz;
  }
  red[t] = z; __syncthreads();
  for (int s = 128; s > 0; s >>= 1) { if (t < s) red[t] = fmaxf(red[t], red[t + s]); __syncthreads(); }
  float mx = red[0]; __syncthreads();
  float e = (t < n) ? expf(z - mx) : 0.f;
  red[t] = e; red2[t] = e * vj; __syncthreads();
  for (int s = 128; s > 0; s >>= 1) {
    if (t < s) { red[t] += red[t + s]; red2[t] += red2[t + s]; }
    __syncthreads();
  }
  if (t == 0) wv[b * 256 + i] = red2[0] / red[0];
}

__global__ void xgat_kernel(const float* __restrict__ wv, const float* __restrict__ h,
                            const float* __restrict__ cb, f16* __restrict__ Xh,
                            f16* __restrict__ Xl) {
  int b = blockIdx.y, i = blockIdx.x, t = threadIdx.x;
  float w_ = wv[b * 256 + i];
#pragma unroll
  for (int r = 0; r < 2; ++r) {
    int c = t + r * 256;
    float v = fmaxf(w_ * h[b * 512 + c] + cb[c], 0.f);
    f16 hh, ll; split1(v, hh, ll);
    long o = (long)b * BSC + (long)i * LDC + c;
    Xh[o] = hh; Xl[o] = ll;
  }
}

__global__ __launch_bounds__(512)
void pool3_kernel(const f16* __restrict__ Hh, const f16* __restrict__ Hl,
                  const f16* __restrict__ Xh, const f16* __restrict__ Xl,
                  const float* __restrict__ sc, const float* __restrict__ gb,
                  const float* __restrict__ w1, const float* __restrict__ w2,
                  const float* __restrict__ w3, const float* __restrict__ leb1,
                  float* __restrict__ xs, int n) {
  int b = blockIdx.x, t = threadIdx.x;
  int cg = t >> 3, rl = t & 7, c0c = cg * 8;
  long baseC = (long)b * BSC;
  __shared__ float red[512];
  __shared__ float xc2[512];

  float s8[8];
#pragma unroll
  for (int q = 0; q < 8; ++q) s8[q] = 0.f;
  for (int j = rl; j < n; j += 8) {
    f16x8 h = *(const f16x8*)(Xh + baseC + (long)j * LDC + c0c);
    f16x8 l = *(const f16x8*)(Xl + baseC + (long)j * LDC + c0c);
#pragma unroll
    for (int q = 0; q < 8; ++q) s8[q] += rc8q(h, l, q);
  }
#pragma unroll
  for (int d = 1; d < 8; d <<= 1)
#pragma unroll
    for (int q = 0; q < 8; ++q) s8[q] += __shfl_xor(s8[q], d);
  float invn = 1.f / (float)n;
  if (rl == 0) {
#pragma unroll
    for (int q = 0; q < 8; ++q) xc2[c0c + q] = s8[q] * invn;
  }
  __syncthreads();

  float x2 = xc2[t];
  red[t] = x2 * w1[t]; __syncthreads();
  for (int s2 = 256; s2 > 0; s2 >>= 1) { if (t < s2) red[t] += red[t + s2]; __syncthreads(); }
  float a1 = red[0]; __syncthreads();
  red[t] = x2 * w2[t]; __syncthreads();
  for (int s2 = 256; s2 > 0; s2 >>= 1) { if (t < s2) red[t] += red[t + s2]; __syncthreads(); }
  float a2 = red[0]; __syncthreads();
  red[t] = x2 * w3[t]; __syncthreads();
  for (int s2 = 256; s2 > 0; s2 >>= 1) { if (t < s2) red[t] += red[t + s2]; __syncthreads(); }
  float a3 = red[0]; __syncthreads();

  float alpha = sc[b * 16 + 2], deg3 = sc[b * 16 + 3];
  float sub = 0.f;
  for (int j = 0; j < n; ++j) sub += alpha * a3;
  float z = a1 + leb1[0] + a2 * deg3 - sub;
  float fv = 1.f / (1.f + expf(-z));
  xs[b * 1024 + t] += fv * x2;
  xs[b * 1024 + 512 + t] += fv * x2;
  (void)Hh; (void)Hl; (void)gb;
}

// ---------------- host orchestration ----------------
extern "C" void kernel_launch(void* const* d_in, const int* in_sizes, int n_in,
                              void* d_out, int out_size, void* d_ws, size_t ws_size,
                              hipStream_t stream) {
  (void)in_sizes; (void)n_in; (void)out_size;
  const int*   x_ids  = (const int*)  d_in[0];
  const float* adj    = (const float*)d_in[2];
  const float* emb    = (const float*)d_in[3];
  const float* conv_W = (const float*)d_in[4];
  const float* conv_b = (const float*)d_in[5];
  const float* att_src= (const float*)d_in[6];
  const float* att_dst= (const float*)d_in[7];
  const float* q_W    = (const float*)d_in[8];
  const float* q_b    = (const float*)d_in[9];
  const float* att_w  = (const float*)d_in[10];
  const float* att_b  = (const float*)d_in[11];
  const float* gcn_W  = (const float*)d_in[12];
  const float* gcn_b  = (const float*)d_in[13];
  const float* le_W1  = (const float*)d_in[14];
  const float* le_b1  = (const float*)d_in[15];
  const float* le_W2  = (const float*)d_in[16];
  const float* le_W3  = (const float*)d_in[17];
  const float* lin1_W = (const float*)d_in[18];
  const float* lin1_b = (const float*)d_in[19];
  const float* lin2_W = (const float*)d_in[20];
  const float* lin2_b = (const float*)d_in[21];
  float* out = (float*)d_out;

  const size_t WN_CONV = 3u * CH * CH;
  const size_t WN_GCN  = 3u * CH * CH;
  const size_t WN_L1   = (size_t)(2 * CH) * CH;
  const size_t WN_L2   = (size_t)CH * 511;
  const size_t WTOT    = WN_CONV + WN_GCN + WN_L1 + WN_L2;

  const size_t per_b  = (size_t)(3 * BSC * 4 + 2 * BS2 * 4 + 11 * 256 * 4
                                 + (4 * 512 + 2 * 256 + 16) * 4 + 4096);
  const size_t fixedb = (size_t)(3 * 512 + 64 + NB * 1024 + NB * 512) * 4
                      + WTOT * 4 + (size_t)NB * 1024 * 4 + (size_t)NB * 512 * 4;
  const size_t slack  = 64 * 512;
  int bc = 4;
  for (int cand = 256; cand >= 4; cand >>= 1) {
    if ((size_t)cand * per_b + fixedb + slack <= ws_size) { bc = cand; break; }
  }
  const int nchunks = NB / bc;

  char* w = (char*)d_ws;
  auto alloc = [&](size_t bytes) { char* p = w; w += (bytes + 255) & ~(size_t)255; return p; };
  float* xs   = (float*)alloc(sizeof(float) * NB * 1024);
  float* vvec = (float*)alloc(sizeof(float) * 3 * CH);
  float* c0   = (float*)alloc(256);
  f16*   Wh   = (f16*)alloc(WTOT * 2);
  f16*   Wl   = (f16*)alloc(WTOT * 2);
  f16*   XSh  = (f16*)alloc((size_t)NB * 1024 * 2);
  f16*   XSl  = (f16*)alloc((size_t)NB * 1024 * 2);
  f16*   FHh  = (f16*)alloc((size_t)NB * 512 * 2);
  f16*   FHl  = (f16*)alloc((size_t)NB * 512 * 2);
  f16* Xh  = (f16*)alloc((size_t)bc * BSC * 2);
  f16* Xl  = (f16*)alloc((size_t)bc * BSC * 2);
  f16* Hh  = (f16*)alloc((size_t)bc * BSC * 2);
  f16* Hl  = (f16*)alloc((size_t)bc * BSC * 2);
  f16* XPh = (f16*)alloc((size_t)bc * BSC * 2);
  f16* XPl = (f16*)alloc((size_t)bc * BSC * 2);
  f16* Ph  = (f16*)alloc((size_t)bc * BS2 * 2);
  f16* Pl  = (f16*)alloc((size_t)bc * BS2 * 2);
  f16* AAh = (f16*)alloc((size_t)bc * BS2 * 2);
  f16* AAl = (f16*)alloc((size_t)bc * BS2 * 2);
  float* si   = (float*)alloc(sizeof(float) * bc * NMAX);
  float* sj   = (float*)alloc(sizeof(float) * bc * NMAX);
  float* deg  = (float*)alloc(sizeof(float) * bc * NMAX);
  float* dinv = (float*)alloc(sizeof(float) * bc * NMAX);
  float* t1   = (float*)alloc(sizeof(float) * bc * NMAX);
  float* t2   = (float*)alloc(sizeof(float) * bc * NMAX);
  float* t3   = (float*)alloc(sizeof(float) * bc * NMAX);
  float* fit  = (float*)alloc(sizeof(float) * bc * NMAX);
  float* vals = (float*)alloc(sizeof(float) * bc * NMAX);
  int*   perm = (int*)  alloc(sizeof(int)   * bc * NMAX);
  float* sifu = (float*)alloc(sizeof(float) * bc);
  float* wv   = (float*)alloc(sizeof(float) * bc * 256);
  float* xcr  = (float*)alloc(sizeof(float) * bc * 512);
  float* h3   = (float*)alloc(sizeof(float) * bc * 512);
  float* sc   = (float*)alloc(sizeof(float) * bc * 16);
  f16* xcrh   = (f16*)alloc((size_t)bc * 512 * 2);
  f16* xcrl   = (f16*)alloc((size_t)bc * 512 * 2);

  f16* cwh = Wh;                       f16* cwl = Wl;
  f16* gwh = Wh + WN_CONV;             f16* gwl = Wl + WN_CONV;
  f16* l1h = Wh + WN_CONV + WN_GCN;    f16* l1l = Wl + WN_CONV + WN_GCN;
  f16* l2h = l1h + WN_L1;              f16* l2l = l1l + WN_L1;

  hipMemsetAsync(xs, 0, sizeof(float) * NB * 1024, stream);

  for (int l = 0; l < 3; ++l) {
    presplit_kernel<<<512, 256, 0, stream>>>(conv_W + (size_t)l * CH * CH,
                                             cwh + (size_t)l * CH * CH,
                                             cwl + (size_t)l * CH * CH, CH, CH);
    presplit_kernel<<<512, 256, 0, stream>>>(gcn_W + (size_t)l * CH * CH,
                                             gwh + (size_t)l * CH * CH,
                                             gwl + (size_t)l * CH * CH, CH, CH);
    vq_kernel<<<513, 64, 0, stream>>>(q_W + (size_t)l * CH * CH, q_b + l * CH,
                                      att_w + (size_t)l * 2 * CH, vvec + l * CH, c0 + l);
  }
  presplit_kernel<<<512, 256, 0, stream>>>(lin1_W, l1h, l1l, 2 * CH, CH);
  presplit_kernel<<<511, 256, 0, stream>>>(lin2_W, l2h, l2l, CH, 511);

  for (int ch = 0; ch < nchunks; ++ch) {
    const int b0 = ch * bc;
    const int*   ids_c = x_ids + (size_t)b0 * NMAX;
    const float* adj_c = adj + (size_t)b0 * BS2;
    float*       xs_c  = xs + (size_t)b0 * 1024;

    build_a_deg_kernel<<<dim3(NMAX, bc), 256, 0, stream>>>(adj_c, AAh, AAl, deg, dinv);
    embed_kernel<<<dim3(NMAX, bc), 128, 0, stream>>>(ids_c, emb, Xh, Xl);

    // ================= layer 1 (full, masked) =================
    {
      const int n = 256, kk = 205;
      const float* aw = att_w;
      pgemm_kernel<0><<<dim3(4, 4, bc), 256, 0, stream>>>(
          Xh, Xl, BSC, LDC, cwh, cwl, 0, CH,
          Hh, Hl, nullptr, BSC, LDC, nullptr, nullptr, n, CH, CH, 8);
      rowdot_kernel<<<dim3(n, bc), 64, 0, stream>>>(Hh, Hl, att_dst, att_src, nullptr,
                                                    si, sj, nullptr, 2);
      softmax_kernel<<<dim3(n, bc), 256, 0, stream>>>(AAh, AAl, si, sj, nullptr, Ph, Pl, n, 1);
      pgemm_kernel<1><<<dim3(4, 4, bc), 256, 0, stream>>>(
          Ph, Pl, BS2, LD2, Hh, Hl, BSC, LDC,
          Xh, Xl, nullptr, BSC, LDC, conv_b, nullptr, n, CH, n, 1 | 2 | 8);
      pgemm_kernel<0><<<dim3(4, 4, bc), 256, 0, stream>>>(
          Xh, Xl, BSC, LDC, gwh, gwl, 0, CH,
          Hh, Hl, nullptr, BSC, LDC, nullptr, dinv, n, CH, CH, 4 | 8);
      pgemm_kernel<1><<<dim3(4, 4, bc), 256, 0, stream>>>(
          AAh, AAl, BS2, LD2, Hh, Hl, BSC, LDC,
          XPh, XPl, nullptr, BSC, LDC, gcn_b, dinv, n, CH, n, 1 | 4 | 8);
      rowdot_kernel<<<dim3(n, bc), 64, 0, stream>>>(XPh, XPl, aw + CH, nullptr, nullptr,
                                                    sj, nullptr, nullptr, 1);
      colmax_kernel<<<bc, 512, 0, stream>>>(XPh, XPl, vvec, c0, sifu, n);
      nbrdot_kernel<<<dim3(n, bc), 256, 0, stream>>>(AAh, AAl, XPh, XPl, vvec, c0, sifu, si, n);
      softmax_kernel<<<dim3(n, bc), 256, 0, stream>>>(AAh, AAl, si, sj, att_b, Ph, Pl, n, 1);
      pgemm_kernel<1><<<dim3(4, 4, bc), 256, 0, stream>>>(
          Ph, Pl, BS2, LD2, Xh, Xl, BSC, LDC,
          Hh, Hl, nullptr, BSC, LDC, nullptr, nullptr, n, CH, n, 8);  // xc
      rowdot_kernel<<<dim3(n, bc), 64, 0, stream>>>(Hh, Hl, le_W1, le_W2, le_W3,
                                                    t1, t2, t3, 3);
      fit_kernel<<<dim3(n, bc), 64, 0, stream>>>(AAh, AAl, t1, t2, t3, deg, le_b1, fit, n);
      topk_kernel<<<bc, 256, 0, stream>>>(fit, perm, vals, n, kk);
      gather_kernel<<<dim3(kk, bc), 256, 0, stream>>>(Hh, Hl, Ph, Pl, perm, vals,
                                                      Xh, Xl, XPh, XPl, n);
      pgemm_kernel<0><<<dim3(2, 4, bc), 256, 0, stream>>>(
          XPh, XPl, BSC, LD2, AAh, AAl, BS2, LD2,
          Ph, Pl, nullptr, BS2, LD2, nullptr, nullptr, kk, n, n, 8);          // SA
      pgemm_kernel<0><<<dim3(2, 4, bc), 256, 0, stream>>>(
          Ph, Pl, BS2, LD2, XPh, XPl, BSC, LD2,
          AAh, AAl, nullptr, BS2, LD2, nullptr, nullptr, kk, kk, n, 8);       // A_new
      degfix_kernel<<<dim3(kk, bc), 256, 0, stream>>>(AAh, AAl, deg, dinv, kk);
      readout_kernel<<<dim3(2, bc), 256, 0, stream>>>(Xh, Xl, xs_c, kk);
    }

    // ================= layer 2 (dense mask; pool collapsed+fused) =================
    {
      const int n = 205, kk = 164;
      const float* aw = att_w + (size_t)2 * CH;
      pgemm_kernel<0><<<dim3(4, 4, bc), 256, 0, stream>>>(
          Xh, Xl, BSC, LDC, cwh + (size_t)CH * CH, cwl + (size_t)CH * CH, 0, CH,
          Hh, Hl, nullptr, BSC, LDC, nullptr, nullptr, n, CH, CH, 8);
      rowdot_kernel<<<dim3(n, bc), 64, 0, stream>>>(Hh, Hl, att_dst + CH, att_src + CH, nullptr,
                                                    si, sj, nullptr, 2);
      softmax_kernel<<<dim3(n, bc), 256, 0, stream>>>(AAh, AAl, si, sj, nullptr, Ph, Pl, n, 0);
      pgemm_kernel<1><<<dim3(4, 4, bc), 256, 0, stream>>>(
          Ph, Pl, BS2, LD2, Hh, Hl, BSC, LDC,
          Xh, Xl, nullptr, BSC, LDC, conv_b + CH, nullptr, n, CH, n, 1 | 2 | 8);
      pgemm_kernel<0><<<dim3(4, 4, bc), 256, 0, stream>>>(
          Xh, Xl, BSC, LDC, gwh + (size_t)CH * CH, gwl + (size_t)CH * CH, 0, CH,
          Hh, Hl, nullptr, BSC, LDC, nullptr, dinv, n, CH, CH, 4 | 8);
      pgemm_kernel<1><<<dim3(4, 4, bc), 256, 0, stream>>>(
          AAh, AAl, BS2, LD2, Hh, Hl, BSC, LDC,
          XPh, XPl, nullptr, BSC, LDC, gcn_b + CH, dinv, n, CH, n, 1 | 4 | 8);
      rowdot_kernel<<<dim3(n, bc), 64, 0, stream>>>(XPh, XPl, aw + CH, nullptr, nullptr,
                                                    sj, nullptr, nullptr, 1);
      pool2_kernel<<<bc, 512, 0, stream>>>(
          XPh, XPl, Xh, Xl, AAh, AAl, sj, vvec + CH, c0 + 1, att_b + 1,
          le_W1 + CH, le_W2 + CH, le_W3 + CH, xcr, xcrh, xcrl, t1, t2, t3, sc, n, kk);
      fit_kernel<<<dim3(n, bc), 64, 0, stream>>>(AAh, AAl, t1, t2, t3, deg, le_b1 + 1, fit, n);
      topk_kernel<<<bc, 256, 0, stream>>>(fit, perm, vals, n, kk);
      readout_rank1_kernel<<<bc, 256, 0, stream>>>(vals, xcr, xs_c, kk);
    }

    // ================= layer 3 (rank-1 X; fused) =================
    {
      const int n = 164;
      pgemm_kernel<0><<<dim3(4, 1, 1), 256, 0, stream>>>(
          xcrh, xcrl, 0, 512, cwh + (size_t)2 * CH * CH, cwl + (size_t)2 * CH * CH, 0, CH,
          nullptr, nullptr, h3, 0, 512, nullptr, nullptr, bc, CH, CH, 16);
      gat3scal_kernel<<<bc, 64, 0, stream>>>(h3, att_dst + 2 * CH, att_src + 2 * CH, sc);
      gatw_kernel<<<dim3(n, bc), 256, 0, stream>>>(vals, sc, wv, n);
      xgat_kernel<<<dim3(n, bc), 256, 0, stream>>>(wv, h3, conv_b + 2 * CH, Xh, Xl);
      pool3_kernel<<<bc, 512, 0, stream>>>(
          Hh, Hl, Xh, Xl, sc, gcn_b + 2 * CH,
          le_W1 + 2 * CH, le_W2 + 2 * CH, le_W3 + 2 * CH, le_b1 + 2, xs_c, n);
    }
  }

  // ---- final MLP (full batch) ----
  splitbuf_kernel<<<NB, 256, 0, stream>>>(xs, XSh, XSl, 1024);
  pgemm_kernel<0><<<dim3(4, 4, 1), 256, 0, stream>>>(
      XSh, XSl, 0, 1024, l1h, l1l, 0, 1024,
      FHh, FHl, nullptr, 0, CH, lin1_b, nullptr, NB, CH, 2 * CH, 1 | 2 | 8);
  pgemm_kernel<0><<<dim3(4, 4, 1), 256, 0, stream>>>(
      FHh, FHl, 0, CH, l2h, l2l, 0, CH,
      nullptr, nullptr, out, 0, 511, lin2_b, nullptr, NB, 511, CH, 1 | 16);
}